// Round 4
// baseline (32645.273 us; speedup 1.0000x reference)
//
#include <hip/hip_runtime.h>

#define T_SEQ   32
#define N_NODES 10000
#define E_EDGES 160000
#define EF      (E_EDGES + N_NODES)
#define IN_CH   128
#define HID     64
#define HEADS   8
#define HC      512
#define GRU_H   256
#define G3      768

#define NB_GAT  512     // persistent GAT blocks (2/CU guaranteed: VGPR<=256, no LDS)
#define NB_GRU  256     // persistent GRU blocks (1/CU guaranteed: 80KB LDS)

typedef __attribute__((ext_vector_type(8))) short short8;
typedef __attribute__((ext_vector_type(4))) float f32x4;
typedef unsigned short ushort_t;

__device__ __forceinline__ float wave_reduce_sum(float v){
#pragma unroll
  for (int off = 32; off; off >>= 1) v += __shfl_xor(v, off, 64);
  return v;
}

__device__ __forceinline__ ushort_t f2bf(float v){
  unsigned u = __float_as_uint(v);
  unsigned r = u + 0x7FFFu + ((u >> 16) & 1u);
  return (ushort_t)(r >> 16);
}
__device__ __forceinline__ float bf2f(ushort_t b){
  return __uint_as_float(((unsigned)b) << 16);
}

// 16B global -> LDS DMA (gfx950). LDS dest must be wave-uniform base + lane*16.
__device__ __forceinline__ void async_cp16(const void* g, void* l){
  __builtin_amdgcn_global_load_lds((const __attribute__((address_space(1))) void*)g,
                                   (__attribute__((address_space(3))) void*)l, 16, 0, 0);
}

// f32 x8 -> bf16 hi/lo split, in-register (identical math to the old split_arr)
__device__ __forceinline__ void cvt8(const float* __restrict__ p, short8& h, short8& l){
  float4 v0 = *(const float4*)p;
  float4 v1 = *(const float4*)(p + 4);
  float vv[8] = {v0.x, v0.y, v0.z, v0.w, v1.x, v1.y, v1.z, v1.w};
#pragma unroll
  for (int i = 0; i < 8; i++){
    ushort_t hh = f2bf(vv[i]);
    h[i] = (short)hh;
    l[i] = (short)f2bf(vv[i] - bf2f(hh));
  }
}

// ---- capture-safe grid barrier (G16: device-scope atomics + fences) -------
// Monotonic ticket counter: barrier g completes when counter >= (g+1)*nb.
// No reset -> no reuse race; memset'd once per kernel_launch (in-graph).
__device__ __forceinline__ void grid_bar(unsigned* bar, unsigned nb){
  __syncthreads();
  if (threadIdx.x == 0){
    __threadfence();                               // publish this block's writes
    unsigned ticket = atomicAdd(bar, 1u);          // device-scope by default
    unsigned target = (ticket / nb + 1u) * nb;
    while (__hip_atomic_load(bar, __ATOMIC_ACQUIRE, __HIP_MEMORY_SCOPE_AGENT) < target){
      __builtin_amdgcn_s_sleep(1);
    }
    __threadfence();                               // reader-side invalidate
  }
  __syncthreads();
}

// ---------------- graph setup ----------------

__global__ __launch_bounds__(256)
void deg_loop_kernel(const int* __restrict__ edst, const float* __restrict__ eattr,
                     int* __restrict__ deg, float* __restrict__ lsum){
  int e = blockIdx.x * 256 + threadIdx.x;
  if (e < E_EDGES){
    int d = edst[e];
    atomicAdd(&deg[d], 1);
    atomicAdd(&lsum[d*3+0], eattr[e*3+0]);
    atomicAdd(&lsum[d*3+1], eattr[e*3+1]);
    atomicAdd(&lsum[d*3+2], eattr[e*3+2]);
  }
}

__global__ __launch_bounds__(256)
void loop_div_kernel(const int* __restrict__ deg, const float* __restrict__ lsum,
                     float* __restrict__ lattr){
  int n = blockIdx.x * 256 + threadIdx.x;
  if (n < N_NODES){
    float d = fmaxf((float)deg[n], 1.0f);
    lattr[n*3+0] = lsum[n*3+0] / d;
    lattr[n*3+1] = lsum[n*3+1] / d;
    lattr[n*3+2] = lsum[n*3+2] / d;
  }
}

__global__ __launch_bounds__(256)
void scan_rowptr_kernel(const int* __restrict__ deg, int* __restrict__ row_ptr){
  __shared__ int sums[256];
  __shared__ int base[256];
  int tid = threadIdx.x;
  const int CH = 40;
  int start = tid * CH;
  int s = 0;
  for (int k = 0; k < CH; k++){
    int n = start + k;
    if (n < N_NODES) s += deg[n];
  }
  sums[tid] = s;
  __syncthreads();
  if (tid == 0){
    int acc = 0;
    for (int i = 0; i < 256; i++){ base[i] = acc; acc += sums[i]; }
  }
  __syncthreads();
  int acc = base[tid];
  for (int k = 0; k < CH; k++){
    int n = start + k;
    if (n < N_NODES){ row_ptr[n] = acc; acc += deg[n]; }
    else if (n == N_NODES){ row_ptr[n] = acc; }
  }
}

__global__ __launch_bounds__(256)
void csr_fill_kernel(const int* __restrict__ edst, const int* __restrict__ row_ptr,
                     int* __restrict__ cursor, int* __restrict__ col){
  int e = blockIdx.x * 256 + threadIdx.x;
  if (e < E_EDGES){
    int d = edst[e];
    int pos = row_ptr[d] + atomicAdd(&cursor[d], 1);
    col[pos] = e;
  }
}

__global__ __launch_bounds__(256)
void build_emeta(const float* __restrict__ eattr, const float* __restrict__ lattr,
                 const int* __restrict__ esrc, float4* __restrict__ emeta){
  int e = blockIdx.x * 256 + threadIdx.x;
  if (e < E_EDGES){
    emeta[e] = make_float4(eattr[e*3], eattr[e*3+1], eattr[e*3+2], __int_as_float(esrc[e]));
  } else if (e < EF){
    int n = e - E_EDGES;
    emeta[e] = make_float4(lattr[n*3], lattr[n*3+1], lattr[n*3+2], __int_as_float(n));
  }
}

// ---------------- pre-split kernels (weights only) ----------------

__global__ __launch_bounds__(256)
void split_w_gat1(const float* __restrict__ wl, const float* __restrict__ wr,
                  ushort_t* __restrict__ hi, ushort_t* __restrict__ lo){
  int idx = blockIdx.x * 256 + threadIdx.x;
  if (idx >= 1024 * 128) return;
  int n = idx >> 7, k = idx & 127;
  float v = (n < 512) ? wl[k * 512 + n] : wr[k * 512 + (n - 512)];
  ushort_t h = f2bf(v);
  hi[idx] = h; lo[idx] = f2bf(v - bf2f(h));
}

__global__ __launch_bounds__(256)
void split_w_gat2(const float* __restrict__ wl, const float* __restrict__ wr,
                  ushort_t* __restrict__ hi, ushort_t* __restrict__ lo){
  int idx = blockIdx.x * 256 + threadIdx.x;
  if (idx >= 128 * 512) return;
  int n = idx >> 9, k = idx & 511;
  float v = (n < 64) ? wl[k * 64 + n] : wr[k * 64 + (n - 64)];
  ushort_t h = f2bf(v);
  hi[idx] = h; lo[idx] = f2bf(v - bf2f(h));
}

// GRU weight pack: Wpk[jt][kc][r][32] with r = g*64 + jj; weight row g*256+jt*64+jj,
// k = kc*32 + kk; k<64 from wih, else whh. hi/lo split.
__global__ __launch_bounds__(256)
void pack_w_gru(const float* __restrict__ wih, const float* __restrict__ whh,
                ushort_t* __restrict__ hi, ushort_t* __restrict__ lo){
  int idx = blockIdx.x * 256 + threadIdx.x;
  if (idx >= 4 * 10 * 192 * 32) return;
  int kk = idx & 31;
  int r  = (idx >> 5) % 192;
  int kc = (idx >> 5) / 192 % 10;
  int jt = idx / (32 * 192 * 10);
  int g = r >> 6, jj = r & 63;
  int wrow = g * 256 + jt * 64 + jj;
  int k = kc * 32 + kk;
  float v = (k < 64) ? wih[wrow * 64 + k] : whh[wrow * 256 + (k - 64)];
  ushort_t h = f2bf(v);
  hi[idx] = h; lo[idx] = f2bf(v - bf2f(h));
}

// =================== persistent GAT pipeline (one launch) ===================
// 512 blocks x 256 threads, no LDS. Per t: 4 phases, grid barrier between.
// Phase bodies are the round-2 kernels verbatim with blockIdx -> item index.

struct GatAllArgs {
  const float* x;                       // [T][N][128] f32
  const float4* emeta;
  const int* row_ptr; const int* col;
  const ushort_t *W1h, *W1l, *W2h, *W2l;
  const float *g1_we, *g1_att, *g1_b;
  const float *g2_we, *g2_att, *g2_b;
  float* xlr;                           // [N][1024] f32 (low region aliased as [N][128])
  ushort_t *h1h, *h1l;                  // [N][512] bf16 hi/lo
  ushort_t *embh, *embl;                // [T][N][64]
  unsigned* bar;
};

// ---- phase 1 body: x[t] @ W1 (bf16x3, in-register split), item q in [0,1252)
__device__ __forceinline__ void gemm1_body(int q, const float* __restrict__ X,
                                           const ushort_t* __restrict__ Bh,
                                           const ushort_t* __restrict__ Bl,
                                           float* __restrict__ C, int tid){
  const int M = N_NODES, K = IN_CH, N = 1024;
  int w = tid >> 6, lane = tid & 63;
  int m16 = lane & 15, quad = lane >> 4;
  int mb = q % 313, nb = q / 313;
  int n0 = (nb * 4 + w) * 64;
  int m0 = mb * 32;

  f32x4 acc[2][4];
#pragma unroll
  for (int i = 0; i < 2; i++)
#pragma unroll
    for (int j = 0; j < 4; j++) acc[i][j] = (f32x4){0,0,0,0};

  int ar0 = m0 + m16;      if (ar0 >= M) ar0 = M - 1;
  int ar1 = m0 + 16 + m16; if (ar1 >= M) ar1 = M - 1;
  const float* A0 = X + (size_t)ar0 * K + quad * 8;
  const float* A1 = X + (size_t)ar1 * K + quad * 8;

  for (int k0 = 0; k0 < K; k0 += 32){
    short8 a_h[2], a_l[2];
    cvt8(A0 + k0, a_h[0], a_l[0]);
    cvt8(A1 + k0, a_h[1], a_l[1]);
#pragma unroll
    for (int nt = 0; nt < 4; nt++){
      size_t boff = (size_t)(n0 + nt * 16 + m16) * K + k0 + quad * 8;
      short8 b_h = *(const short8*)(Bh + boff);
      short8 b_l = *(const short8*)(Bl + boff);
#pragma unroll
      for (int mt = 0; mt < 2; mt++){
        acc[mt][nt] = __builtin_amdgcn_mfma_f32_16x16x32_bf16(a_h[mt], b_h, acc[mt][nt],0,0,0);
        acc[mt][nt] = __builtin_amdgcn_mfma_f32_16x16x32_bf16(a_h[mt], b_l, acc[mt][nt],0,0,0);
        acc[mt][nt] = __builtin_amdgcn_mfma_f32_16x16x32_bf16(a_l[mt], b_h, acc[mt][nt],0,0,0);
      }
    }
  }
#pragma unroll
  for (int mt = 0; mt < 2; mt++){
    int row = m0 + mt * 16 + quad * 4;
#pragma unroll
    for (int nt = 0; nt < 4; nt++){
      int cc = n0 + nt * 16 + m16;
#pragma unroll
      for (int r4 = 0; r4 < 4; r4++){
        if (row + r4 < M) C[(size_t)(row + r4) * N + cc] = acc[mt][nt][r4];
      }
    }
  }
}

// ---- phase 3 body: h1 @ W2 (K=512, N=128); item covers 2 m-tiles, 2 waves each
__device__ __forceinline__ void gemm2_body(int q, const ushort_t* __restrict__ Ah,
                                           const ushort_t* __restrict__ Al,
                                           const ushort_t* __restrict__ Bh,
                                           const ushort_t* __restrict__ Bl,
                                           float* __restrict__ C, int tid){
  const int M = N_NODES, K = HC;
  int w = tid >> 6, lane = tid & 63;
  int m16 = lane & 15, quad = lane >> 4;
  int tile = q * 2 + (w >> 1);
  if (tile >= 313) return;
  int n0 = (w & 1) * 64;
  int m0 = tile * 32;

  f32x4 acc[2][4];
#pragma unroll
  for (int i = 0; i < 2; i++)
#pragma unroll
    for (int j = 0; j < 4; j++) acc[i][j] = (f32x4){0,0,0,0};

  int ar0 = m0 + m16;      if (ar0 >= M) ar0 = M - 1;
  int ar1 = m0 + 16 + m16; if (ar1 >= M) ar1 = M - 1;
  const ushort_t* Ah0 = Ah + (size_t)ar0 * K + quad * 8;
  const ushort_t* Al0 = Al + (size_t)ar0 * K + quad * 8;
  const ushort_t* Ah1 = Ah + (size_t)ar1 * K + quad * 8;
  const ushort_t* Al1 = Al + (size_t)ar1 * K + quad * 8;

  for (int k0 = 0; k0 < K; k0 += 32){
    short8 a_h[2], a_l[2];
    a_h[0] = *(const short8*)(Ah0 + k0); a_l[0] = *(const short8*)(Al0 + k0);
    a_h[1] = *(const short8*)(Ah1 + k0); a_l[1] = *(const short8*)(Al1 + k0);
#pragma unroll
    for (int nt = 0; nt < 4; nt++){
      size_t boff = (size_t)(n0 + nt * 16 + m16) * K + k0 + quad * 8;
      short8 b_h = *(const short8*)(Bh + boff);
      short8 b_l = *(const short8*)(Bl + boff);
#pragma unroll
      for (int mt = 0; mt < 2; mt++){
        acc[mt][nt] = __builtin_amdgcn_mfma_f32_16x16x32_bf16(a_h[mt], b_h, acc[mt][nt],0,0,0);
        acc[mt][nt] = __builtin_amdgcn_mfma_f32_16x16x32_bf16(a_h[mt], b_l, acc[mt][nt],0,0,0);
        acc[mt][nt] = __builtin_amdgcn_mfma_f32_16x16x32_bf16(a_l[mt], b_h, acc[mt][nt],0,0,0);
      }
    }
  }
#pragma unroll
  for (int mt = 0; mt < 2; mt++){
    int row = m0 + mt * 16 + quad * 4;
#pragma unroll
    for (int nt = 0; nt < 4; nt++){
      int cc = n0 + nt * 16 + m16;
#pragma unroll
      for (int r4 = 0; r4 < 4; r4++){
        if (row + r4 < M) C[(size_t)(row + r4) * 128 + cc] = acc[mt][nt][r4];
      }
    }
  }
}

// ---- phase 2 body: GAT layer 1 for node n (one wave)
__device__ __forceinline__ void gat1_half(float4 xl, float4 xr,
                                          float a0, float a1, float a2,
                                          float4 we0, float4 we1, float4 we2,
                                          float4 at, bool valid,
                                          float& den, float4& acc){
  float vx = xl.x + xr.x + a0*we0.x + a1*we1.x + a2*we2.x;
  float vy = xl.y + xr.y + a0*we0.y + a1*we1.y + a2*we2.y;
  float vz = xl.z + xr.z + a0*we0.z + a1*we1.z + a2*we2.z;
  float vw = xl.w + xr.w + a0*we0.w + a1*we1.w + a2*we2.w;
  vx = fmaxf(vx, 0.2f*vx); vy = fmaxf(vy, 0.2f*vy);
  vz = fmaxf(vz, 0.2f*vz); vw = fmaxf(vw, 0.2f*vw);
  float pm = vx*at.x + vy*at.y + vz*at.z + vw*at.w;
  pm += __shfl_xor(pm, 1, 64); pm += __shfl_xor(pm, 2, 64);
  pm += __shfl_xor(pm, 4, 64); pm += __shfl_xor(pm, 8, 64);
  float wgt = valid ? __expf(pm) : 0.f;
  den += wgt;
  acc.x += wgt * xl.x; acc.y += wgt * xl.y;
  acc.z += wgt * xl.z; acc.w += wgt * xl.w;
}

__device__ __forceinline__ void gat1_body(int n, int lane, const GatAllArgs& a){
  if (n >= N_NODES) return;
  const float* xlr = a.xlr;
  int ch0 = lane * 4;
  int ch1 = 256 + lane * 4;

  float4 att0 = *(const float4*)&a.g1_att[ch0];
  float4 att1 = *(const float4*)&a.g1_att[ch1];
  float4 we00 = *(const float4*)&a.g1_we[ch0],        we01 = *(const float4*)&a.g1_we[ch1];
  float4 we10 = *(const float4*)&a.g1_we[512 + ch0],  we11 = *(const float4*)&a.g1_we[512 + ch1];
  float4 we20 = *(const float4*)&a.g1_we[1024 + ch0], we21 = *(const float4*)&a.g1_we[1024 + ch1];
  const float* xrow_n = xlr + (size_t)n * 1024;
  float4 xr0 = *(const float4*)&xrow_n[512 + ch0];
  float4 xr1 = *(const float4*)&xrow_n[512 + ch1];

  float den0 = 0.f, den1 = 0.f;
  float4 acc0 = make_float4(0,0,0,0), acc1 = make_float4(0,0,0,0);
  int beg = a.row_ptr[n], end = a.row_ptr[n + 1];

  for (int p = beg - 1; p < end; p += 2){
    int c0 = (p >= beg) ? a.col[p] : (E_EDGES + n);   // p==beg-1 -> self loop
    bool v1 = (p + 1 < end);
    int c1 = v1 ? a.col[p + 1] : c0;
    float4 mt0 = a.emeta[c0];
    float4 mt1 = a.emeta[c1];
    const float* xp0 = xlr + (size_t)__float_as_int(mt0.w) * 1024;
    const float* xp1 = xlr + (size_t)__float_as_int(mt1.w) * 1024;
    float4 xa0 = *(const float4*)&xp0[ch0];
    float4 xa1 = *(const float4*)&xp0[ch1];
    float4 xb0 = *(const float4*)&xp1[ch0];
    float4 xb1 = *(const float4*)&xp1[ch1];
    gat1_half(xa0, xr0, mt0.x, mt0.y, mt0.z, we00, we10, we20, att0, true, den0, acc0);
    gat1_half(xa1, xr1, mt0.x, mt0.y, mt0.z, we01, we11, we21, att1, true, den1, acc1);
    gat1_half(xb0, xr0, mt1.x, mt1.y, mt1.z, we00, we10, we20, att0, v1, den0, acc0);
    gat1_half(xb1, xr1, mt1.x, mt1.y, mt1.z, we01, we11, we21, att1, v1, den1, acc1);
  }

  float4 b0 = *(const float4*)&a.g1_b[ch0];
  float4 b1 = *(const float4*)&a.g1_b[ch1];
  float id0 = 1.f / den0, id1 = 1.f / den1;
  float o[8];
  o[0] = acc0.x*id0 + b0.x; o[1] = acc0.y*id0 + b0.y;
  o[2] = acc0.z*id0 + b0.z; o[3] = acc0.w*id0 + b0.w;
  o[4] = acc1.x*id1 + b1.x; o[5] = acc1.y*id1 + b1.y;
  o[6] = acc1.z*id1 + b1.z; o[7] = acc1.w*id1 + b1.w;
  ushort4 h0, h1v, l0, l1v;
  ushort_t* hp0 = (ushort_t*)&h0; ushort_t* hp1 = (ushort_t*)&h1v;
  ushort_t* lp0 = (ushort_t*)&l0; ushort_t* lp1 = (ushort_t*)&l1v;
#pragma unroll
  for (int i = 0; i < 8; i++){
    float v = o[i];
    v = v > 0.f ? v : (__expf(v) - 1.f);
    ushort_t hh = f2bf(v);
    ushort_t ll = f2bf(v - bf2f(hh));
    if (i < 4){ hp0[i] = hh; lp0[i] = ll; } else { hp1[i-4] = hh; lp1[i-4] = ll; }
  }
  *(ushort4*)&a.h1h[(size_t)n * 512 + ch0] = h0;
  *(ushort4*)&a.h1h[(size_t)n * 512 + ch1] = h1v;
  *(ushort4*)&a.h1l[(size_t)n * 512 + ch0] = l0;
  *(ushort4*)&a.h1l[(size_t)n * 512 + ch1] = l1v;
}

// ---- phase 4 body: GAT layer 2 for node n (one wave)
__device__ __forceinline__ void gat2_body(int n, int lane, int t, const GatAllArgs& a){
  if (n >= N_NODES) return;
  const float* xlr = a.xlr;              // [N][128] region
  int g = lane >> 4;
  int c4 = (lane & 15) * 4;

  float4 attq = *(const float4*)&a.g2_att[c4];
  float4 we0q = *(const float4*)&a.g2_we[c4];
  float4 we1q = *(const float4*)&a.g2_we[64 + c4];
  float4 we2q = *(const float4*)&a.g2_we[128 + c4];
  float4 xr4  = *(const float4*)&xlr[(size_t)n * 128 + 64 + c4];

  float den = 0.f;
  float4 acc = make_float4(0,0,0,0);
  int beg = a.row_ptr[n], end = a.row_ptr[n + 1];

  for (int p0 = beg - 1; p0 < end; p0 += 4){
    int pp = p0 + g;
    bool valid = pp < end;
    int s = n; float a0 = 0.f, a1 = 0.f, a2 = 0.f;
    if (valid){
      float4 mt = (pp < beg) ? a.emeta[E_EDGES + n] : a.emeta[a.col[pp]];
      a0 = mt.x; a1 = mt.y; a2 = mt.z; s = __float_as_int(mt.w);
    }
    float4 xl4 = *(const float4*)&xlr[(size_t)s * 128 + c4];
    float vx = xl4.x + xr4.x + a0*we0q.x + a1*we1q.x + a2*we2q.x;
    float vy = xl4.y + xr4.y + a0*we0q.y + a1*we1q.y + a2*we2q.y;
    float vz = xl4.z + xr4.z + a0*we0q.z + a1*we1q.z + a2*we2q.z;
    float vw = xl4.w + xr4.w + a0*we0q.w + a1*we1q.w + a2*we2q.w;
    vx = fmaxf(vx, 0.2f*vx); vy = fmaxf(vy, 0.2f*vy);
    vz = fmaxf(vz, 0.2f*vz); vw = fmaxf(vw, 0.2f*vw);
    float pm = vx*attq.x + vy*attq.y + vz*attq.z + vw*attq.w;
    pm += __shfl_xor(pm, 1, 64); pm += __shfl_xor(pm, 2, 64);
    pm += __shfl_xor(pm, 4, 64); pm += __shfl_xor(pm, 8, 64);
    float wgt = valid ? __expf(pm) : 0.f;
    den += wgt;
    acc.x += wgt * xl4.x; acc.y += wgt * xl4.y;
    acc.z += wgt * xl4.z; acc.w += wgt * xl4.w;
  }
#pragma unroll
  for (int off = 16; off <= 32; off <<= 1){
    den   += __shfl_xor(den, off, 64);
    acc.x += __shfl_xor(acc.x, off, 64);
    acc.y += __shfl_xor(acc.y, off, 64);
    acc.z += __shfl_xor(acc.z, off, 64);
    acc.w += __shfl_xor(acc.w, off, 64);
  }
  if (g == 0){
    float4 bq = *(const float4*)&a.g2_b[c4];
    float id = 1.f / den;
    float o[4];
    o[0] = acc.x*id + bq.x; o[1] = acc.y*id + bq.y;
    o[2] = acc.z*id + bq.z; o[3] = acc.w*id + bq.w;
    ushort4 hv, lv;
    ushort_t* hp = (ushort_t*)&hv; ushort_t* lp = (ushort_t*)&lv;
#pragma unroll
    for (int i = 0; i < 4; i++){
      float v = o[i];
      v = v > 0.f ? v : (__expf(v) - 1.f);
      ushort_t hh = f2bf(v);
      hp[i] = hh; lp[i] = f2bf(v - bf2f(hh));
    }
    ushort_t* oh = a.embh + (size_t)t * N_NODES * HID;
    ushort_t* ol = a.embl + (size_t)t * N_NODES * HID;
    *(ushort4*)&oh[(size_t)n * 64 + c4] = hv;
    *(ushort4*)&ol[(size_t)n * 64 + c4] = lv;
  }
}

__global__ __launch_bounds__(256, 2)
void gat_all(GatAllArgs a){
  int tid = threadIdx.x;
  int lane = tid & 63, w = tid >> 6;
  for (int t = 0; t < T_SEQ; t++){
    const float* xt = a.x + (size_t)t * N_NODES * IN_CH;
    // phase 1: x[t] @ W1 -> xlr[N][1024]
    for (int q = blockIdx.x; q < 1252; q += NB_GAT)
      gemm1_body(q, xt, a.W1h, a.W1l, a.xlr, tid);
    grid_bar(a.bar, NB_GAT);
    // phase 2: GAT1 -> h1 (each wave one node)
    for (int q = blockIdx.x; q < 2500; q += NB_GAT)
      gat1_body(q * 4 + w, lane, a);
    grid_bar(a.bar, NB_GAT);
    // phase 3: h1 @ W2 -> xlr[N][128] (aliases xlr low region; gat1 done reading)
    for (int q = blockIdx.x; q < 157; q += NB_GAT)
      gemm2_body(q, a.h1h, a.h1l, a.W2h, a.W2l, a.xlr, tid);
    grid_bar(a.bar, NB_GAT);
    // phase 4: GAT2 -> emb[t]
    for (int q = blockIdx.x; q < 2500; q += NB_GAT)
      gat2_body(q * 4 + w, lane, t, a);
    if (t != T_SEQ - 1) grid_bar(a.bar, NB_GAT);  // xlr reused next t
  }
}

// =================== persistent GRU (one launch, all 32 steps) ==============
// 256 blocks (1/CU: 80KB LDS), spin grid barrier between steps.
// Item body = round-2 gru_step core: dbuf pipeline + involutive XOR swizzle
// applied to BOTH DMA source and LDS read (rule #21).

struct GruAllArgs {
  const ushort_t* embh; const ushort_t* embl;         // [T][N][64]
  const ushort_t* WpH[2]; const ushort_t* WpL[2];     // packed [4][10][192][32]
  const float*    BIH[2]; const float*    BHH[2];
  ushort_t* hb[8];                                    // ping-pong h buffers
  unsigned* bar;
};

#define GRU_STAGE(BB, AH, AL, ASTRIDE, ACOL, KC)                               \
  {                                                                            \
    _Pragma("unroll")                                                          \
    for (int pass = 0; pass < 2; pass++){                                      \
      int ch = pass * 256 + tid;          /* 0..511 : 128 rows x 4 chunks */   \
      int lch = ch ^ ((ch >> 3) & 7);     /* swizzled logical chunk */         \
      int row = lch >> 2, c = (lch & 3) * 8;                                   \
      int anode = m0 + row; if (anode >= N_NODES) anode = N_NODES - 1;         \
      async_cp16(AH + (size_t)anode * ASTRIDE + (ACOL) + c, &Ah_s[BB][ch * 8]);\
      async_cp16(AL + (size_t)anode * ASTRIDE + (ACOL) + c, &Al_s[BB][ch * 8]);\
    }                                                                          \
    const ushort_t* bh = WpH + ((size_t)jt * 10 + (KC)) * 6144;                \
    const ushort_t* bl = WpL + ((size_t)jt * 10 + (KC)) * 6144;                \
    _Pragma("unroll")                                                          \
    for (int pass = 0; pass < 3; pass++){                                      \
      int ch = pass * 256 + tid;          /* 0..767 : 192 rows x 4 chunks */   \
      int lch = ch ^ ((ch >> 3) & 7);                                          \
      async_cp16(bh + lch * 8, &Bh_s[BB][ch * 8]);                             \
      async_cp16(bl + lch * 8, &Bl_s[BB][ch * 8]);                             \
    }                                                                          \
  }

#define GRU_COMPUTE(BB, NTGT)                                                  \
  {                                                                            \
    short8 a_h[4], a_l[4];                                                     \
    _Pragma("unroll")                                                          \
    for (int mt = 0; mt < 4; mt++){                                            \
      int r = wm * 64 + mt * 16 + m16;                                         \
      int so = ((r * 4 + quad) ^ ((r >> 1) & 7)) * 8;                          \
      a_h[mt] = *(const short8*)&Ah_s[BB][so];                                 \
      a_l[mt] = *(const short8*)&Al_s[BB][so];                                 \
    }                                                                          \
    _Pragma("unroll")                                                          \
    for (int g = 0; g < 3; g++){                                               \
      int tgt = (g < 2) ? g : (NTGT);                                          \
      _Pragma("unroll")                                                        \
      for (int nt = 0; nt < 2; nt++){                                          \
        int r = g * 64 + wn * 32 + nt * 16 + m16;                              \
        int so = ((r * 4 + quad) ^ ((r >> 1) & 7)) * 8;                        \
        short8 b_h = *(const short8*)&Bh_s[BB][so];                            \
        short8 b_l = *(const short8*)&Bl_s[BB][so];                            \
        _Pragma("unroll")                                                      \
        for (int mt = 0; mt < 4; mt++){                                        \
          acc[tgt][mt][nt] = __builtin_amdgcn_mfma_f32_16x16x32_bf16(a_h[mt], b_h, acc[tgt][mt][nt],0,0,0); \
          acc[tgt][mt][nt] = __builtin_amdgcn_mfma_f32_16x16x32_bf16(a_h[mt], b_l, acc[tgt][mt][nt],0,0,0); \
          acc[tgt][mt][nt] = __builtin_amdgcn_mfma_f32_16x16x32_bf16(a_l[mt], b_h, acc[tgt][mt][nt],0,0,0); \
        }                                                                      \
      }                                                                        \
    }                                                                          \
  }

__global__ __launch_bounds__(256, 1)
void gru_all(GruAllArgs a){
  __shared__ __align__(16) short Ah_s[2][128 * 32];
  __shared__ __align__(16) short Al_s[2][128 * 32];
  __shared__ __align__(16) short Bh_s[2][192 * 32];
  __shared__ __align__(16) short Bl_s[2][192 * 32];

  int tid = threadIdx.x;
  int w = tid >> 6, lane = tid & 63;
  int wm = w >> 1, wn = w & 1;
  int m16 = lane & 15, quad = lane >> 4;

  for (int s = 0; s < T_SEQ; s++){
    int pin = (s & 1) ? 2 : 0;           // in = hb[dir*4+pin], out = hb[dir*4+(pin^2)]
    for (int q = blockIdx.x; q < 632; q += NB_GRU){
      int dir = (q >= 316) ? 1 : 0;
      int rem = q - dir * 316;
      int jt = rem & 3;                  // j-tile of 64
      int bx = rem >> 2;                 // node tile of 128 (0..78)
      int m0 = bx * 128;
      int j0 = jt * 64;
      int tsel = dir ? (T_SEQ - 1 - s) : s;
      const ushort_t* EtH  = a.embh + (size_t)tsel * N_NODES * HID;
      const ushort_t* EtL  = a.embl + (size_t)tsel * N_NODES * HID;
      const ushort_t* WpH  = a.WpH[dir];
      const ushort_t* WpL  = a.WpL[dir];
      const float*    BIH  = a.BIH[dir];
      const float*    BHH  = a.BHH[dir];
      const ushort_t* HinH = a.hb[dir*4 + pin];
      const ushort_t* HinL = a.hb[dir*4 + pin + 1];
      ushort_t* HoutH = a.hb[dir*4 + (pin^2)];
      ushort_t* HoutL = a.hb[dir*4 + (pin^2) + 1];

      f32x4 acc[4][4][2];                // [r,z,n_in,n_hid][mt][nt]
#pragma unroll
      for (int g = 0; g < 4; g++)
#pragma unroll
        for (int i = 0; i < 4; i++)
#pragma unroll
          for (int j = 0; j < 2; j++) acc[g][i][j] = (f32x4){0,0,0,0};

      // prologue: stage kc=0 (Et cols 0..31) into buf 0
      GRU_STAGE(0, EtH, EtL, 64, 0, 0)
      __syncthreads();
      GRU_STAGE(1, EtH, EtL, 64, 32, 1)
      GRU_COMPUTE(0, 2)
      __syncthreads();
      GRU_STAGE(0, HinH, HinL, 256, 0, 2)
      GRU_COMPUTE(1, 2)
      __syncthreads();
      for (int kc = 2; kc < 9; kc++){
        GRU_STAGE((kc + 1) & 1, HinH, HinL, 256, (kc - 1) * 32, kc + 1)
        GRU_COMPUTE(kc & 1, 3)
        __syncthreads();
      }
      GRU_COMPUTE(1, 3)

      // epilogue: gates -> h_out
#pragma unroll
      for (int mt = 0; mt < 4; mt++){
        int row = m0 + wm * 64 + mt * 16 + quad * 4;
#pragma unroll
        for (int nt = 0; nt < 2; nt++){
          int j = j0 + wn * 32 + nt * 16 + m16;
          float br  = BIH[j] + BHH[j];
          float bz  = BIH[GRU_H + j] + BHH[GRU_H + j];
          float bni = BIH[2*GRU_H + j];
          float bnh = BHH[2*GRU_H + j];
#pragma unroll
          for (int r4 = 0; r4 < 4; r4++){
            int node = row + r4;
            if (node < N_NODES){
              float rr = 1.f / (1.f + __expf(-(acc[0][mt][nt][r4] + br)));
              float zz = 1.f / (1.f + __expf(-(acc[1][mt][nt][r4] + bz)));
              float nn = tanhf(acc[2][mt][nt][r4] + bni + rr * (acc[3][mt][nt][r4] + bnh));
              size_t hidx = (size_t)node * GRU_H + j;
              float hold = bf2f(HinH[hidx]) + bf2f(HinL[hidx]);
              float hv = (1.f - zz) * nn + zz * hold;
              ushort_t hh = f2bf(hv);
              HoutH[hidx] = hh;
              HoutL[hidx] = f2bf(hv - bf2f(hh));
            }
          }
        }
      }
    }
    if (s != T_SEQ - 1) grid_bar(a.bar, NB_GRU);
  }
}

// ---------------- tail ----------------

__global__ __launch_bounds__(256)
void mean_kernel(const ushort_t* __restrict__ hfh, const ushort_t* __restrict__ hfl,
                 const ushort_t* __restrict__ hbh, const ushort_t* __restrict__ hbl,
                 float* __restrict__ g){
  int k = threadIdx.x;
  int n0 = blockIdx.x * 50;
  int n1 = n0 + 50; if (n1 > N_NODES) n1 = N_NODES;
  float sf = 0.f, sb = 0.f;
  for (int n = n0; n < n1; n++){
    size_t i = (size_t)n * GRU_H + k;
    sf += bf2f(hfh[i]) + bf2f(hfl[i]);
    sb += bf2f(hbh[i]) + bf2f(hbl[i]);
  }
  atomicAdd(&g[k], sf);
  atomicAdd(&g[GRU_H + k], sb);
}

__global__ __launch_bounds__(64)
void fc_kernel(const float* __restrict__ g, const float* __restrict__ W,
               const float* __restrict__ b, float* __restrict__ out){
  int j = blockIdx.x;
  int lane = threadIdx.x;
  float s = 0.f;
  for (int k = lane; k < 2 * GRU_H; k += 64) s += g[k] * W[j * (2 * GRU_H) + k];
  s = wave_reduce_sum(s);
  if (lane == 0) out[j] = b[j] + s * (1.0f / N_NODES);
}

// ---------------- launch ----------------

extern "C" void kernel_launch(void* const* d_in, const int* in_sizes, int n_in,
                              void* d_out, int out_size, void* d_ws, size_t ws_size,
                              hipStream_t stream){
  const float* x     = (const float*)d_in[0];
  const float* eattr = (const float*)d_in[1];
  const int*   esrc  = (const int*)  d_in[2];
  const int*   edst  = (const int*)  d_in[3];
  const float* g1_wl = (const float*)d_in[4];
  const float* g1_wr = (const float*)d_in[5];
  const float* g1_we = (const float*)d_in[6];
  const float* g1_att= (const float*)d_in[7];
  const float* g1_b  = (const float*)d_in[8];
  const float* g2_wl = (const float*)d_in[9];
  const float* g2_wr = (const float*)d_in[10];
  const float* g2_we = (const float*)d_in[11];
  const float* g2_att= (const float*)d_in[12];
  const float* g2_b  = (const float*)d_in[13];
  const float* wih_f = (const float*)d_in[14];
  const float* whh_f = (const float*)d_in[15];
  const float* bih_f = (const float*)d_in[16];
  const float* bhh_f = (const float*)d_in[17];
  const float* wih_b = (const float*)d_in[18];
  const float* whh_b = (const float*)d_in[19];
  const float* bih_b = (const float*)d_in[20];
  const float* bhh_b = (const float*)d_in[21];
  const float* fc_w  = (const float*)d_in[22];
  const float* fc_b  = (const float*)d_in[23];
  float* out = (float*)d_out;

  float* ws = (float*)d_ws;
  size_t o = 0;
  auto alloc = [&](size_t nfloats) -> float* {
    float* p = ws + o; o += (nfloats + 3) & ~(size_t)3; return p;
  };
  float* xlr1    = alloc((size_t)N_NODES * 1024);
  ushort_t* h1h  = (ushort_t*)alloc((size_t)N_NODES * 512 / 2 + 4);
  ushort_t* h1l  = (ushort_t*)alloc((size_t)N_NODES * 512 / 2 + 4);
  const size_t ETOT = (size_t)T_SEQ * N_NODES * HID;
  ushort_t* embh = (ushort_t*)alloc(ETOT / 2);
  ushort_t* embl = (ushort_t*)alloc(ETOT / 2);
  const size_t HTOT = (size_t)N_NODES * GRU_H;
  ushort_t* hbuf[8];
  for (int i = 0; i < 8; i++) hbuf[i] = (ushort_t*)alloc(HTOT / 2 + 4);
  float* lsum  = alloc((size_t)N_NODES * 3);
  float* lattr = alloc((size_t)N_NODES * 3);
  float* gmean = alloc(512);
  float4* emeta = (float4*)alloc((size_t)EF * 4);
  ushort_t* W1h = (ushort_t*)alloc(1024*128/2);
  ushort_t* W1l = (ushort_t*)alloc(1024*128/2);
  ushort_t* W2h = (ushort_t*)alloc(128*512/2);
  ushort_t* W2l = (ushort_t*)alloc(128*512/2);
  const size_t WPK = 4 * 10 * 192 * 32;     // 245760 shorts
  ushort_t* WpFh = (ushort_t*)alloc(WPK/2);
  ushort_t* WpFl = (ushort_t*)alloc(WPK/2);
  ushort_t* WpBh = (ushort_t*)alloc(WPK/2);
  ushort_t* WpBl = (ushort_t*)alloc(WPK/2);
  int* deg     = (int*)alloc(N_NODES + 4);
  int* row_ptr = (int*)alloc(N_NODES + 4);
  int* cursor  = (int*)alloc(N_NODES + 4);
  int* col     = (int*)alloc(E_EDGES + 4);
  unsigned* bar = (unsigned*)alloc(8);      // bar[0]=gat_all, bar[1]=gru_all

  hipMemsetAsync(deg,    0, N_NODES * sizeof(int), stream);
  hipMemsetAsync(cursor, 0, N_NODES * sizeof(int), stream);
  hipMemsetAsync(lsum,   0, (size_t)N_NODES * 3 * sizeof(float), stream);
  hipMemsetAsync(gmean,  0, 512 * sizeof(float), stream);
  hipMemsetAsync(bar,    0, 8 * sizeof(unsigned), stream);
  hipMemsetAsync(hbuf[0], 0, HTOT * sizeof(ushort_t), stream);
  hipMemsetAsync(hbuf[1], 0, HTOT * sizeof(ushort_t), stream);
  hipMemsetAsync(hbuf[4], 0, HTOT * sizeof(ushort_t), stream);
  hipMemsetAsync(hbuf[5], 0, HTOT * sizeof(ushort_t), stream);

  deg_loop_kernel<<<(E_EDGES + 255)/256, 256, 0, stream>>>(edst, eattr, deg, lsum);
  loop_div_kernel<<<(N_NODES + 255)/256, 256, 0, stream>>>(deg, lsum, lattr);
  scan_rowptr_kernel<<<1, 256, 0, stream>>>(deg, row_ptr);
  csr_fill_kernel<<<(E_EDGES + 255)/256, 256, 0, stream>>>(edst, row_ptr, cursor, col);
  build_emeta<<<(EF + 255)/256, 256, 0, stream>>>(eattr, lattr, esrc, emeta);
  split_w_gat1<<<(1024*128 + 255)/256, 256, 0, stream>>>(g1_wl, g1_wr, W1h, W1l);
  split_w_gat2<<<(128*512 + 255)/256, 256, 0, stream>>>(g2_wl, g2_wr, W2h, W2l);
  pack_w_gru<<<(int)((WPK + 255)/256), 256, 0, stream>>>(wih_f, whh_f, WpFh, WpFl);
  pack_w_gru<<<(int)((WPK + 255)/256), 256, 0, stream>>>(wih_b, whh_b, WpBh, WpBl);

  // persistent GAT: one launch for the whole 32-step pipeline
  {
    GatAllArgs ga;
    ga.x = x; ga.emeta = emeta; ga.row_ptr = row_ptr; ga.col = col;
    ga.W1h = W1h; ga.W1l = W1l; ga.W2h = W2h; ga.W2l = W2l;
    ga.g1_we = g1_we; ga.g1_att = g1_att; ga.g1_b = g1_b;
    ga.g2_we = g2_we; ga.g2_att = g2_att; ga.g2_b = g2_b;
    ga.xlr = xlr1; ga.h1h = h1h; ga.h1l = h1l;
    ga.embh = embh; ga.embl = embl;
    ga.bar = &bar[0];
    gat_all<<<NB_GAT, 256, 0, stream>>>(ga);
  }

  // persistent GRU: one launch for all 32 steps, both directions
  {
    GruAllArgs gaa;
    gaa.embh = embh; gaa.embl = embl;
    gaa.WpH[0] = WpFh; gaa.WpL[0] = WpFl; gaa.WpH[1] = WpBh; gaa.WpL[1] = WpBl;
    gaa.BIH[0] = bih_f; gaa.BHH[0] = bhh_f; gaa.BIH[1] = bih_b; gaa.BHH[1] = bhh_b;
    for (int i = 0; i < 8; i++) gaa.hb[i] = hbuf[i];
    gaa.bar = &bar[1];
    gru_all<<<NB_GRU, 256, 0, stream>>>(gaa);
  }

  mean_kernel<<<(N_NODES + 49)/50, 256, 0, stream>>>(hbuf[0], hbuf[1], hbuf[4], hbuf[5], gmean);
  fc_kernel<<<33, 64, 0, stream>>>(gmean, fc_w, fc_b, out);
}

// Round 5
// 13163.368 us; speedup vs baseline: 2.4800x; 2.4800x over previous
//
#include <hip/hip_runtime.h>

#define T_SEQ   32
#define N_NODES 10000
#define E_EDGES 160000
#define EF      (E_EDGES + N_NODES)
#define IN_CH   128
#define HID     64
#define HEADS   8
#define HC      512
#define GRU_H   256
#define G3      768

#define NB_GAT  512     // persistent GAT blocks (2/CU guaranteed: VGPR<=128, no LDS)
#define NB_GRU  256     // persistent GRU blocks (1/CU guaranteed: 80KB LDS)

typedef __attribute__((ext_vector_type(8))) short short8;
typedef __attribute__((ext_vector_type(4))) float f32x4;
typedef unsigned short ushort_t;

__device__ __forceinline__ float wave_reduce_sum(float v){
#pragma unroll
  for (int off = 32; off; off >>= 1) v += __shfl_xor(v, off, 64);
  return v;
}

__device__ __forceinline__ ushort_t f2bf(float v){
  unsigned u = __float_as_uint(v);
  unsigned r = u + 0x7FFFu + ((u >> 16) & 1u);
  return (ushort_t)(r >> 16);
}
__device__ __forceinline__ float bf2f(ushort_t b){
  return __uint_as_float(((unsigned)b) << 16);
}

// 16B global -> LDS DMA (gfx950). LDS dest must be wave-uniform base + lane*16.
__device__ __forceinline__ void async_cp16(const void* g, void* l){
  __builtin_amdgcn_global_load_lds((const __attribute__((address_space(1))) void*)g,
                                   (__attribute__((address_space(3))) void*)l, 16, 0, 0);
}

// f32 x8 -> bf16 hi/lo split, in-register
__device__ __forceinline__ void cvt8(const float* __restrict__ p, short8& h, short8& l){
  float4 v0 = *(const float4*)p;
  float4 v1 = *(const float4*)(p + 4);
  float vv[8] = {v0.x, v0.y, v0.z, v0.w, v1.x, v1.y, v1.z, v1.w};
#pragma unroll
  for (int i = 0; i < 8; i++){
    ushort_t hh = f2bf(vv[i]);
    h[i] = (short)hh;
    l[i] = (short)f2bf(vv[i] - bf2f(hh));
  }
}

// ---- capture-safe grid barrier, cache-friendly -----------------------------
// R4 lesson: ACQUIRE poll emits an L2 invalidate PER ITERATION -> co-resident
// workers' caches get nuked (FETCH 6.6GB, 4.5x slowdown). Fix: scope gives
// freshness (agent atomic load bypasses non-coherent L2); ordering only once:
// release on arrival (publish via L2 writeback), RELAXED poll (no invalidate),
// single ACQUIRE after exit (one invalidate so we read peers' data).
__device__ __forceinline__ void grid_bar(unsigned* bar, unsigned nb){
  __syncthreads();
  if (threadIdx.x == 0){
    unsigned ticket = __hip_atomic_fetch_add(bar, 1u, __ATOMIC_RELEASE,
                                             __HIP_MEMORY_SCOPE_AGENT);
    unsigned target = (ticket / nb + 1u) * nb;
    while (__hip_atomic_load(bar, __ATOMIC_RELAXED, __HIP_MEMORY_SCOPE_AGENT) < target){
      __builtin_amdgcn_s_sleep(32);     // ~0.85us backoff; poll is a plain read
    }
    (void)__hip_atomic_load(bar, __ATOMIC_ACQUIRE, __HIP_MEMORY_SCOPE_AGENT);
  }
  __syncthreads();
}

// ---------------- graph setup ----------------

__global__ __launch_bounds__(256)
void deg_loop_kernel(const int* __restrict__ edst, const float* __restrict__ eattr,
                     int* __restrict__ deg, float* __restrict__ lsum){
  int e = blockIdx.x * 256 + threadIdx.x;
  if (e < E_EDGES){
    int d = edst[e];
    atomicAdd(&deg[d], 1);
    atomicAdd(&lsum[d*3+0], eattr[e*3+0]);
    atomicAdd(&lsum[d*3+1], eattr[e*3+1]);
    atomicAdd(&lsum[d*3+2], eattr[e*3+2]);
  }
}

__global__ __launch_bounds__(256)
void loop_div_kernel(const int* __restrict__ deg, const float* __restrict__ lsum,
                     float* __restrict__ lattr){
  int n = blockIdx.x * 256 + threadIdx.x;
  if (n < N_NODES){
    float d = fmaxf((float)deg[n], 1.0f);
    lattr[n*3+0] = lsum[n*3+0] / d;
    lattr[n*3+1] = lsum[n*3+1] / d;
    lattr[n*3+2] = lsum[n*3+2] / d;
  }
}

__global__ __launch_bounds__(256)
void scan_rowptr_kernel(const int* __restrict__ deg, int* __restrict__ row_ptr){
  __shared__ int sums[256];
  __shared__ int base[256];
  int tid = threadIdx.x;
  const int CH = 40;
  int start = tid * CH;
  int s = 0;
  for (int k = 0; k < CH; k++){
    int n = start + k;
    if (n < N_NODES) s += deg[n];
  }
  sums[tid] = s;
  __syncthreads();
  if (tid == 0){
    int acc = 0;
    for (int i = 0; i < 256; i++){ base[i] = acc; acc += sums[i]; }
  }
  __syncthreads();
  int acc = base[tid];
  for (int k = 0; k < CH; k++){
    int n = start + k;
    if (n < N_NODES){ row_ptr[n] = acc; acc += deg[n]; }
    else if (n == N_NODES){ row_ptr[n] = acc; }
  }
}

__global__ __launch_bounds__(256)
void csr_fill_kernel(const int* __restrict__ edst, const int* __restrict__ row_ptr,
                     int* __restrict__ cursor, int* __restrict__ col){
  int e = blockIdx.x * 256 + threadIdx.x;
  if (e < E_EDGES){
    int d = edst[e];
    int pos = row_ptr[d] + atomicAdd(&cursor[d], 1);
    col[pos] = e;
  }
}

__global__ __launch_bounds__(256)
void build_emeta(const float* __restrict__ eattr, const float* __restrict__ lattr,
                 const int* __restrict__ esrc, float4* __restrict__ emeta){
  int e = blockIdx.x * 256 + threadIdx.x;
  if (e < E_EDGES){
    emeta[e] = make_float4(eattr[e*3], eattr[e*3+1], eattr[e*3+2], __int_as_float(esrc[e]));
  } else if (e < EF){
    int n = e - E_EDGES;
    emeta[e] = make_float4(lattr[n*3], lattr[n*3+1], lattr[n*3+2], __int_as_float(n));
  }
}

// ---------------- pre-split kernels (weights only) ----------------

__global__ __launch_bounds__(256)
void split_w_gat1(const float* __restrict__ wl, const float* __restrict__ wr,
                  ushort_t* __restrict__ hi, ushort_t* __restrict__ lo){
  int idx = blockIdx.x * 256 + threadIdx.x;
  if (idx >= 1024 * 128) return;
  int n = idx >> 7, k = idx & 127;
  float v = (n < 512) ? wl[k * 512 + n] : wr[k * 512 + (n - 512)];
  ushort_t h = f2bf(v);
  hi[idx] = h; lo[idx] = f2bf(v - bf2f(h));
}

__global__ __launch_bounds__(256)
void split_w_gat2(const float* __restrict__ wl, const float* __restrict__ wr,
                  ushort_t* __restrict__ hi, ushort_t* __restrict__ lo){
  int idx = blockIdx.x * 256 + threadIdx.x;
  if (idx >= 128 * 512) return;
  int n = idx >> 9, k = idx & 511;
  float v = (n < 64) ? wl[k * 64 + n] : wr[k * 64 + (n - 64)];
  ushort_t h = f2bf(v);
  hi[idx] = h; lo[idx] = f2bf(v - bf2f(h));
}

// GRU weight pack: Wpk[jt][kc][r][32] with r = g*64 + jj; weight row g*256+jt*64+jj,
// k = kc*32 + kk; k<64 from wih, else whh. hi/lo split.
__global__ __launch_bounds__(256)
void pack_w_gru(const float* __restrict__ wih, const float* __restrict__ whh,
                ushort_t* __restrict__ hi, ushort_t* __restrict__ lo){
  int idx = blockIdx.x * 256 + threadIdx.x;
  if (idx >= 4 * 10 * 192 * 32) return;
  int kk = idx & 31;
  int r  = (idx >> 5) % 192;
  int kc = (idx >> 5) / 192 % 10;
  int jt = idx / (32 * 192 * 10);
  int g = r >> 6, jj = r & 63;
  int wrow = g * 256 + jt * 64 + jj;
  int k = kc * 32 + kk;
  float v = (k < 64) ? wih[wrow * 64 + k] : whh[wrow * 256 + (k - 64)];
  ushort_t h = f2bf(v);
  hi[idx] = h; lo[idx] = f2bf(v - bf2f(h));
}

// =================== persistent GAT pipeline (one launch) ===================
// 512 blocks x 256 threads, no LDS. Double-buffered xlr; per t three phases:
//   [gat1(cur)] bar [gemm2 -> cur.low] bar [gat2(t,cur) || gemm1(t+1)->nxt] bar
// (gemm1(0) prologue). 96 barriers total; gat2's gathers co-scheduled with
// gemm1's MFMA.

struct GatAllArgs {
  const float* x;                       // [T][N][128] f32
  const float4* emeta;
  const int* row_ptr; const int* col;
  const ushort_t *W1h, *W1l, *W2h, *W2l;
  const float *g1_we, *g1_att, *g1_b;
  const float *g2_we, *g2_att, *g2_b;
  float *xlrA, *xlrB;                   // 2x [N][1024] f32 (low region = [N][128])
  ushort_t *h1h, *h1l;                  // [N][512] bf16 hi/lo
  ushort_t *embh, *embl;                // [T][N][64]
  unsigned* bar;
};

// ---- gemm1 body: x[t] @ W1 (bf16x3, in-register split), item q in [0,1252)
__device__ __forceinline__ void gemm1_body(int q, const float* __restrict__ X,
                                           const ushort_t* __restrict__ Bh,
                                           const ushort_t* __restrict__ Bl,
                                           float* __restrict__ C, int tid){
  const int M = N_NODES, K = IN_CH, N = 1024;
  int w = tid >> 6, lane = tid & 63;
  int m16 = lane & 15, quad = lane >> 4;
  int mb = q % 313, nb = q / 313;
  int n0 = (nb * 4 + w) * 64;
  int m0 = mb * 32;

  f32x4 acc[2][4];
#pragma unroll
  for (int i = 0; i < 2; i++)
#pragma unroll
    for (int j = 0; j < 4; j++) acc[i][j] = (f32x4){0,0,0,0};

  int ar0 = m0 + m16;      if (ar0 >= M) ar0 = M - 1;
  int ar1 = m0 + 16 + m16; if (ar1 >= M) ar1 = M - 1;
  const float* A0 = X + (size_t)ar0 * K + quad * 8;
  const float* A1 = X + (size_t)ar1 * K + quad * 8;

  for (int k0 = 0; k0 < K; k0 += 32){
    short8 a_h[2], a_l[2];
    cvt8(A0 + k0, a_h[0], a_l[0]);
    cvt8(A1 + k0, a_h[1], a_l[1]);
#pragma unroll
    for (int nt = 0; nt < 4; nt++){
      size_t boff = (size_t)(n0 + nt * 16 + m16) * K + k0 + quad * 8;
      short8 b_h = *(const short8*)(Bh + boff);
      short8 b_l = *(const short8*)(Bl + boff);
#pragma unroll
      for (int mt = 0; mt < 2; mt++){
        acc[mt][nt] = __builtin_amdgcn_mfma_f32_16x16x32_bf16(a_h[mt], b_h, acc[mt][nt],0,0,0);
        acc[mt][nt] = __builtin_amdgcn_mfma_f32_16x16x32_bf16(a_h[mt], b_l, acc[mt][nt],0,0,0);
        acc[mt][nt] = __builtin_amdgcn_mfma_f32_16x16x32_bf16(a_l[mt], b_h, acc[mt][nt],0,0,0);
      }
    }
  }
#pragma unroll
  for (int mt = 0; mt < 2; mt++){
    int row = m0 + mt * 16 + quad * 4;
#pragma unroll
    for (int nt = 0; nt < 4; nt++){
      int cc = n0 + nt * 16 + m16;
#pragma unroll
      for (int r4 = 0; r4 < 4; r4++){
        if (row + r4 < M) C[(size_t)(row + r4) * N + cc] = acc[mt][nt][r4];
      }
    }
  }
}

// ---- gemm2 body: h1 @ W2 (K=512, N=128); item covers 2 m-tiles, 2 waves each
__device__ __forceinline__ void gemm2_body(int q, const ushort_t* __restrict__ Ah,
                                           const ushort_t* __restrict__ Al,
                                           const ushort_t* __restrict__ Bh,
                                           const ushort_t* __restrict__ Bl,
                                           float* __restrict__ C, int tid){
  const int M = N_NODES, K = HC;
  int w = tid >> 6, lane = tid & 63;
  int m16 = lane & 15, quad = lane >> 4;
  int tile = q * 2 + (w >> 1);
  if (tile >= 313) return;
  int n0 = (w & 1) * 64;
  int m0 = tile * 32;

  f32x4 acc[2][4];
#pragma unroll
  for (int i = 0; i < 2; i++)
#pragma unroll
    for (int j = 0; j < 4; j++) acc[i][j] = (f32x4){0,0,0,0};

  int ar0 = m0 + m16;      if (ar0 >= M) ar0 = M - 1;
  int ar1 = m0 + 16 + m16; if (ar1 >= M) ar1 = M - 1;
  const ushort_t* Ah0 = Ah + (size_t)ar0 * K + quad * 8;
  const ushort_t* Al0 = Al + (size_t)ar0 * K + quad * 8;
  const ushort_t* Ah1 = Ah + (size_t)ar1 * K + quad * 8;
  const ushort_t* Al1 = Al + (size_t)ar1 * K + quad * 8;

  for (int k0 = 0; k0 < K; k0 += 32){
    short8 a_h[2], a_l[2];
    a_h[0] = *(const short8*)(Ah0 + k0); a_l[0] = *(const short8*)(Al0 + k0);
    a_h[1] = *(const short8*)(Ah1 + k0); a_l[1] = *(const short8*)(Al1 + k0);
#pragma unroll
    for (int nt = 0; nt < 4; nt++){
      size_t boff = (size_t)(n0 + nt * 16 + m16) * K + k0 + quad * 8;
      short8 b_h = *(const short8*)(Bh + boff);
      short8 b_l = *(const short8*)(Bl + boff);
#pragma unroll
      for (int mt = 0; mt < 2; mt++){
        acc[mt][nt] = __builtin_amdgcn_mfma_f32_16x16x32_bf16(a_h[mt], b_h, acc[mt][nt],0,0,0);
        acc[mt][nt] = __builtin_amdgcn_mfma_f32_16x16x32_bf16(a_h[mt], b_l, acc[mt][nt],0,0,0);
        acc[mt][nt] = __builtin_amdgcn_mfma_f32_16x16x32_bf16(a_l[mt], b_h, acc[mt][nt],0,0,0);
      }
    }
  }
#pragma unroll
  for (int mt = 0; mt < 2; mt++){
    int row = m0 + mt * 16 + quad * 4;
#pragma unroll
    for (int nt = 0; nt < 4; nt++){
      int cc = n0 + nt * 16 + m16;
#pragma unroll
      for (int r4 = 0; r4 < 4; r4++){
        if (row + r4 < M) C[(size_t)(row + r4) * 128 + cc] = acc[mt][nt][r4];
      }
    }
  }
}

// ---- gat1 body: GAT layer 1 for node n (one wave)
__device__ __forceinline__ void gat1_half(float4 xl, float4 xr,
                                          float a0, float a1, float a2,
                                          float4 we0, float4 we1, float4 we2,
                                          float4 at, bool valid,
                                          float& den, float4& acc){
  float vx = xl.x + xr.x + a0*we0.x + a1*we1.x + a2*we2.x;
  float vy = xl.y + xr.y + a0*we0.y + a1*we1.y + a2*we2.y;
  float vz = xl.z + xr.z + a0*we0.z + a1*we1.z + a2*we2.z;
  float vw = xl.w + xr.w + a0*we0.w + a1*we1.w + a2*we2.w;
  vx = fmaxf(vx, 0.2f*vx); vy = fmaxf(vy, 0.2f*vy);
  vz = fmaxf(vz, 0.2f*vz); vw = fmaxf(vw, 0.2f*vw);
  float pm = vx*at.x + vy*at.y + vz*at.z + vw*at.w;
  pm += __shfl_xor(pm, 1, 64); pm += __shfl_xor(pm, 2, 64);
  pm += __shfl_xor(pm, 4, 64); pm += __shfl_xor(pm, 8, 64);
  float wgt = valid ? __expf(pm) : 0.f;
  den += wgt;
  acc.x += wgt * xl.x; acc.y += wgt * xl.y;
  acc.z += wgt * xl.z; acc.w += wgt * xl.w;
}

__device__ __forceinline__ void gat1_body(int n, int lane, const float* __restrict__ xlr,
                                          const GatAllArgs& a){
  if (n >= N_NODES) return;
  int ch0 = lane * 4;
  int ch1 = 256 + lane * 4;

  float4 att0 = *(const float4*)&a.g1_att[ch0];
  float4 att1 = *(const float4*)&a.g1_att[ch1];
  float4 we00 = *(const float4*)&a.g1_we[ch0],        we01 = *(const float4*)&a.g1_we[ch1];
  float4 we10 = *(const float4*)&a.g1_we[512 + ch0],  we11 = *(const float4*)&a.g1_we[512 + ch1];
  float4 we20 = *(const float4*)&a.g1_we[1024 + ch0], we21 = *(const float4*)&a.g1_we[1024 + ch1];
  const float* xrow_n = xlr + (size_t)n * 1024;
  float4 xr0 = *(const float4*)&xrow_n[512 + ch0];
  float4 xr1 = *(const float4*)&xrow_n[512 + ch1];

  float den0 = 0.f, den1 = 0.f;
  float4 acc0 = make_float4(0,0,0,0), acc1 = make_float4(0,0,0,0);
  int beg = a.row_ptr[n], end = a.row_ptr[n + 1];

  for (int p = beg - 1; p < end; p += 2){
    int c0 = (p >= beg) ? a.col[p] : (E_EDGES + n);   // p==beg-1 -> self loop
    bool v1 = (p + 1 < end);
    int c1 = v1 ? a.col[p + 1] : c0;
    float4 mt0 = a.emeta[c0];
    float4 mt1 = a.emeta[c1];
    const float* xp0 = xlr + (size_t)__float_as_int(mt0.w) * 1024;
    const float* xp1 = xlr + (size_t)__float_as_int(mt1.w) * 1024;
    float4 xa0 = *(const float4*)&xp0[ch0];
    float4 xa1 = *(const float4*)&xp0[ch1];
    float4 xb0 = *(const float4*)&xp1[ch0];
    float4 xb1 = *(const float4*)&xp1[ch1];
    gat1_half(xa0, xr0, mt0.x, mt0.y, mt0.z, we00, we10, we20, att0, true, den0, acc0);
    gat1_half(xa1, xr1, mt0.x, mt0.y, mt0.z, we01, we11, we21, att1, true, den1, acc1);
    gat1_half(xb0, xr0, mt1.x, mt1.y, mt1.z, we00, we10, we20, att0, v1, den0, acc0);
    gat1_half(xb1, xr1, mt1.x, mt1.y, mt1.z, we01, we11, we21, att1, v1, den1, acc1);
  }

  float4 b0 = *(const float4*)&a.g1_b[ch0];
  float4 b1 = *(const float4*)&a.g1_b[ch1];
  float id0 = 1.f / den0, id1 = 1.f / den1;
  float o[8];
  o[0] = acc0.x*id0 + b0.x; o[1] = acc0.y*id0 + b0.y;
  o[2] = acc0.z*id0 + b0.z; o[3] = acc0.w*id0 + b0.w;
  o[4] = acc1.x*id1 + b1.x; o[5] = acc1.y*id1 + b1.y;
  o[6] = acc1.z*id1 + b1.z; o[7] = acc1.w*id1 + b1.w;
  ushort4 h0, h1v, l0, l1v;
  ushort_t* hp0 = (ushort_t*)&h0; ushort_t* hp1 = (ushort_t*)&h1v;
  ushort_t* lp0 = (ushort_t*)&l0; ushort_t* lp1 = (ushort_t*)&l1v;
#pragma unroll
  for (int i = 0; i < 8; i++){
    float v = o[i];
    v = v > 0.f ? v : (__expf(v) - 1.f);
    ushort_t hh = f2bf(v);
    ushort_t ll = f2bf(v - bf2f(hh));
    if (i < 4){ hp0[i] = hh; lp0[i] = ll; } else { hp1[i-4] = hh; lp1[i-4] = ll; }
  }
  *(ushort4*)&a.h1h[(size_t)n * 512 + ch0] = h0;
  *(ushort4*)&a.h1h[(size_t)n * 512 + ch1] = h1v;
  *(ushort4*)&a.h1l[(size_t)n * 512 + ch0] = l0;
  *(ushort4*)&a.h1l[(size_t)n * 512 + ch1] = l1v;
}

// ---- gat2 body: GAT layer 2 for node n (one wave)
__device__ __forceinline__ void gat2_body(int n, int lane, int t,
                                          const float* __restrict__ xlr,
                                          const GatAllArgs& a){
  if (n >= N_NODES) return;
  int g = lane >> 4;
  int c4 = (lane & 15) * 4;

  float4 attq = *(const float4*)&a.g2_att[c4];
  float4 we0q = *(const float4*)&a.g2_we[c4];
  float4 we1q = *(const float4*)&a.g2_we[64 + c4];
  float4 we2q = *(const float4*)&a.g2_we[128 + c4];
  float4 xr4  = *(const float4*)&xlr[(size_t)n * 128 + 64 + c4];

  float den = 0.f;
  float4 acc = make_float4(0,0,0,0);
  int beg = a.row_ptr[n], end = a.row_ptr[n + 1];

  for (int p0 = beg - 1; p0 < end; p0 += 4){
    int pp = p0 + g;
    bool valid = pp < end;
    int s = n; float a0 = 0.f, a1 = 0.f, a2 = 0.f;
    if (valid){
      float4 mt = (pp < beg) ? a.emeta[E_EDGES + n] : a.emeta[a.col[pp]];
      a0 = mt.x; a1 = mt.y; a2 = mt.z; s = __float_as_int(mt.w);
    }
    float4 xl4 = *(const float4*)&xlr[(size_t)s * 128 + c4];
    float vx = xl4.x + xr4.x + a0*we0q.x + a1*we1q.x + a2*we2q.x;
    float vy = xl4.y + xr4.y + a0*we0q.y + a1*we1q.y + a2*we2q.y;
    float vz = xl4.z + xr4.z + a0*we0q.z + a1*we1q.z + a2*we2q.z;
    float vw = xl4.w + xr4.w + a0*we0q.w + a1*we1q.w + a2*we2q.w;
    vx = fmaxf(vx, 0.2f*vx); vy = fmaxf(vy, 0.2f*vy);
    vz = fmaxf(vz, 0.2f*vz); vw = fmaxf(vw, 0.2f*vw);
    float pm = vx*attq.x + vy*attq.y + vz*attq.z + vw*attq.w;
    pm += __shfl_xor(pm, 1, 64); pm += __shfl_xor(pm, 2, 64);
    pm += __shfl_xor(pm, 4, 64); pm += __shfl_xor(pm, 8, 64);
    float wgt = valid ? __expf(pm) : 0.f;
    den += wgt;
    acc.x += wgt * xl4.x; acc.y += wgt * xl4.y;
    acc.z += wgt * xl4.z; acc.w += wgt * xl4.w;
  }
#pragma unroll
  for (int off = 16; off <= 32; off <<= 1){
    den   += __shfl_xor(den, off, 64);
    acc.x += __shfl_xor(acc.x, off, 64);
    acc.y += __shfl_xor(acc.y, off, 64);
    acc.z += __shfl_xor(acc.z, off, 64);
    acc.w += __shfl_xor(acc.w, off, 64);
  }
  if (g == 0){
    float4 bq = *(const float4*)&a.g2_b[c4];
    float id = 1.f / den;
    float o[4];
    o[0] = acc.x*id + bq.x; o[1] = acc.y*id + bq.y;
    o[2] = acc.z*id + bq.z; o[3] = acc.w*id + bq.w;
    ushort4 hv, lv;
    ushort_t* hp = (ushort_t*)&hv; ushort_t* lp = (ushort_t*)&lv;
#pragma unroll
    for (int i = 0; i < 4; i++){
      float v = o[i];
      v = v > 0.f ? v : (__expf(v) - 1.f);
      ushort_t hh = f2bf(v);
      hp[i] = hh; lp[i] = f2bf(v - bf2f(hh));
    }
    ushort_t* oh = a.embh + (size_t)t * N_NODES * HID;
    ushort_t* ol = a.embl + (size_t)t * N_NODES * HID;
    *(ushort4*)&oh[(size_t)n * 64 + c4] = hv;
    *(ushort4*)&ol[(size_t)n * 64 + c4] = lv;
  }
}

__global__ __launch_bounds__(256, 2)
void gat_all(GatAllArgs a){
  int tid = threadIdx.x;
  int lane = tid & 63, w = tid >> 6;
  float* xbuf0 = a.xlrA;
  float* xbuf1 = a.xlrB;
  // prologue: gemm1(0) -> xbuf0
  for (int q = blockIdx.x; q < 1252; q += NB_GAT)
    gemm1_body(q, a.x, a.W1h, a.W1l, xbuf0, tid);
  grid_bar(a.bar, NB_GAT);
  for (int t = 0; t < T_SEQ; t++){
    float* cur = (t & 1) ? xbuf1 : xbuf0;
    float* nxt = (t & 1) ? xbuf0 : xbuf1;
    // phase A: gat1 on cur -> h1
    for (int q = blockIdx.x; q < 2500; q += NB_GAT)
      gat1_body(q * 4 + w, lane, cur, a);
    grid_bar(a.bar, NB_GAT);
    // phase B: h1 @ W2 -> cur low region [N][128] (gat1 done reading cur)
    for (int q = blockIdx.x; q < 157; q += NB_GAT)
      gemm2_body(q, a.h1h, a.h1l, a.W2h, a.W2l, cur, tid);
    grid_bar(a.bar, NB_GAT);
    // phase C (merged): gat2(t) reads cur-low  ||  gemm1(t+1) -> nxt
    int goff = (t < T_SEQ - 1) ? 1252 : 0;
    int tot  = goff + 2500;
    const float* xt1 = a.x + (size_t)(t + 1) * N_NODES * IN_CH;
    for (int q = blockIdx.x; q < tot; q += NB_GAT){
      if (q < goff) gemm1_body(q, xt1, a.W1h, a.W1l, nxt, tid);
      else          gat2_body((q - goff) * 4 + w, lane, t, cur, a);
    }
    if (t < T_SEQ - 1) grid_bar(a.bar, NB_GAT);   // nxt must be complete before gat1
  }
}

// =================== persistent GRU (one launch, all 32 steps) ==============

struct GruAllArgs {
  const ushort_t* embh; const ushort_t* embl;         // [T][N][64]
  const ushort_t* WpH[2]; const ushort_t* WpL[2];     // packed [4][10][192][32]
  const float*    BIH[2]; const float*    BHH[2];
  ushort_t* hb[8];                                    // ping-pong h buffers
  unsigned* bar;
};

#define GRU_STAGE(BB, AH, AL, ASTRIDE, ACOL, KC)                               \
  {                                                                            \
    _Pragma("unroll")                                                          \
    for (int pass = 0; pass < 2; pass++){                                      \
      int ch = pass * 256 + tid;          /* 0..511 : 128 rows x 4 chunks */   \
      int lch = ch ^ ((ch >> 3) & 7);     /* swizzled logical chunk */         \
      int row = lch >> 2, c = (lch & 3) * 8;                                   \
      int anode = m0 + row; if (anode >= N_NODES) anode = N_NODES - 1;         \
      async_cp16(AH + (size_t)anode * ASTRIDE + (ACOL) + c, &Ah_s[BB][ch * 8]);\
      async_cp16(AL + (size_t)anode * ASTRIDE + (ACOL) + c, &Al_s[BB][ch * 8]);\
    }                                                                          \
    const ushort_t* bh = WpH + ((size_t)jt * 10 + (KC)) * 6144;                \
    const ushort_t* bl = WpL + ((size_t)jt * 10 + (KC)) * 6144;                \
    _Pragma("unroll")                                                          \
    for (int pass = 0; pass < 3; pass++){                                      \
      int ch = pass * 256 + tid;          /* 0..767 : 192 rows x 4 chunks */   \
      int lch = ch ^ ((ch >> 3) & 7);                                          \
      async_cp16(bh + lch * 8, &Bh_s[BB][ch * 8]);                             \
      async_cp16(bl + lch * 8, &Bl_s[BB][ch * 8]);                             \
    }                                                                          \
  }

#define GRU_COMPUTE(BB, NTGT)                                                  \
  {                                                                            \
    short8 a_h[4], a_l[4];                                                     \
    _Pragma("unroll")                                                          \
    for (int mt = 0; mt < 4; mt++){                                            \
      int r = wm * 64 + mt * 16 + m16;                                         \
      int so = ((r * 4 + quad) ^ ((r >> 1) & 7)) * 8;                          \
      a_h[mt] = *(const short8*)&Ah_s[BB][so];                                 \
      a_l[mt] = *(const short8*)&Al_s[BB][so];                                 \
    }                                                                          \
    _Pragma("unroll")                                                          \
    for (int g = 0; g < 3; g++){                                               \
      int tgt = (g < 2) ? g : (NTGT);                                          \
      _Pragma("unroll")                                                        \
      for (int nt = 0; nt < 2; nt++){                                          \
        int r = g * 64 + wn * 32 + nt * 16 + m16;                              \
        int so = ((r * 4 + quad) ^ ((r >> 1) & 7)) * 8;                        \
        short8 b_h = *(const short8*)&Bh_s[BB][so];                            \
        short8 b_l = *(const short8*)&Bl_s[BB][so];                            \
        _Pragma("unroll")                                                      \
        for (int mt = 0; mt < 4; mt++){                                        \
          acc[tgt][mt][nt] = __builtin_amdgcn_mfma_f32_16x16x32_bf16(a_h[mt], b_h, acc[tgt][mt][nt],0,0,0); \
          acc[tgt][mt][nt] = __builtin_amdgcn_mfma_f32_16x16x32_bf16(a_h[mt], b_l, acc[tgt][mt][nt],0,0,0); \
          acc[tgt][mt][nt] = __builtin_amdgcn_mfma_f32_16x16x32_bf16(a_l[mt], b_h, acc[tgt][mt][nt],0,0,0); \
        }                                                                      \
      }                                                                        \
    }                                                                          \
  }

__global__ __launch_bounds__(256, 1)
void gru_all(GruAllArgs a){
  __shared__ __align__(16) short Ah_s[2][128 * 32];
  __shared__ __align__(16) short Al_s[2][128 * 32];
  __shared__ __align__(16) short Bh_s[2][192 * 32];
  __shared__ __align__(16) short Bl_s[2][192 * 32];

  int tid = threadIdx.x;
  int w = tid >> 6, lane = tid & 63;
  int wm = w >> 1, wn = w & 1;
  int m16 = lane & 15, quad = lane >> 4;

  for (int s = 0; s < T_SEQ; s++){
    int pin = (s & 1) ? 2 : 0;           // in = hb[dir*4+pin], out = hb[dir*4+(pin^2)]
    for (int q = blockIdx.x; q < 632; q += NB_GRU){
      int dir = (q >= 316) ? 1 : 0;
      int rem = q - dir * 316;
      int jt = rem & 3;                  // j-tile of 64
      int bx = rem >> 2;                 // node tile of 128 (0..78)
      int m0 = bx * 128;
      int j0 = jt * 64;
      int tsel = dir ? (T_SEQ - 1 - s) : s;
      const ushort_t* EtH  = a.embh + (size_t)tsel * N_NODES * HID;
      const ushort_t* EtL  = a.embl + (size_t)tsel * N_NODES * HID;
      const ushort_t* WpH  = a.WpH[dir];
      const ushort_t* WpL  = a.WpL[dir];
      const float*    BIH  = a.BIH[dir];
      const float*    BHH  = a.BHH[dir];
      const ushort_t* HinH = a.hb[dir*4 + pin];
      const ushort_t* HinL = a.hb[dir*4 + pin + 1];
      ushort_t* HoutH = a.hb[dir*4 + (pin^2)];
      ushort_t* HoutL = a.hb[dir*4 + (pin^2) + 1];

      f32x4 acc[4][4][2];                // [r,z,n_in,n_hid][mt][nt]
#pragma unroll
      for (int g = 0; g < 4; g++)
#pragma unroll
        for (int i = 0; i < 4; i++)
#pragma unroll
          for (int j = 0; j < 2; j++) acc[g][i][j] = (f32x4){0,0,0,0};

      GRU_STAGE(0, EtH, EtL, 64, 0, 0)
      __syncthreads();
      GRU_STAGE(1, EtH, EtL, 64, 32, 1)
      GRU_COMPUTE(0, 2)
      __syncthreads();
      GRU_STAGE(0, HinH, HinL, 256, 0, 2)
      GRU_COMPUTE(1, 2)
      __syncthreads();
      for (int kc = 2; kc < 9; kc++){
        GRU_STAGE((kc + 1) & 1, HinH, HinL, 256, (kc - 1) * 32, kc + 1)
        GRU_COMPUTE(kc & 1, 3)
        __syncthreads();
      }
      GRU_COMPUTE(1, 3)

      // epilogue: gates -> h_out
#pragma unroll
      for (int mt = 0; mt < 4; mt++){
        int row = m0 + wm * 64 + mt * 16 + quad * 4;
#pragma unroll
        for (int nt = 0; nt < 2; nt++){
          int j = j0 + wn * 32 + nt * 16 + m16;
          float br  = BIH[j] + BHH[j];
          float bz  = BIH[GRU_H + j] + BHH[GRU_H + j];
          float bni = BIH[2*GRU_H + j];
          float bnh = BHH[2*GRU_H + j];
#pragma unroll
          for (int r4 = 0; r4 < 4; r4++){
            int node = row + r4;
            if (node < N_NODES){
              float rr = 1.f / (1.f + __expf(-(acc[0][mt][nt][r4] + br)));
              float zz = 1.f / (1.f + __expf(-(acc[1][mt][nt][r4] + bz)));
              float nn = tanhf(acc[2][mt][nt][r4] + bni + rr * (acc[3][mt][nt][r4] + bnh));
              size_t hidx = (size_t)node * GRU_H + j;
              float hold = bf2f(HinH[hidx]) + bf2f(HinL[hidx]);
              float hv = (1.f - zz) * nn + zz * hold;
              ushort_t hh = f2bf(hv);
              HoutH[hidx] = hh;
              HoutL[hidx] = f2bf(hv - bf2f(hh));
            }
          }
        }
      }
    }
    if (s != T_SEQ - 1) grid_bar(a.bar, NB_GRU);
  }
}

// ---------------- tail ----------------

__global__ __launch_bounds__(256)
void mean_kernel(const ushort_t* __restrict__ hfh, const ushort_t* __restrict__ hfl,
                 const ushort_t* __restrict__ hbh, const ushort_t* __restrict__ hbl,
                 float* __restrict__ g){
  int k = threadIdx.x;
  int n0 = blockIdx.x * 50;
  int n1 = n0 + 50; if (n1 > N_NODES) n1 = N_NODES;
  float sf = 0.f, sb = 0.f;
  for (int n = n0; n < n1; n++){
    size_t i = (size_t)n * GRU_H + k;
    sf += bf2f(hfh[i]) + bf2f(hfl[i]);
    sb += bf2f(hbh[i]) + bf2f(hbl[i]);
  }
  atomicAdd(&g[k], sf);
  atomicAdd(&g[GRU_H + k], sb);
}

__global__ __launch_bounds__(64)
void fc_kernel(const float* __restrict__ g, const float* __restrict__ W,
               const float* __restrict__ b, float* __restrict__ out){
  int j = blockIdx.x;
  int lane = threadIdx.x;
  float s = 0.f;
  for (int k = lane; k < 2 * GRU_H; k += 64) s += g[k] * W[j * (2 * GRU_H) + k];
  s = wave_reduce_sum(s);
  if (lane == 0) out[j] = b[j] + s * (1.0f / N_NODES);
}

// ---------------- launch ----------------

extern "C" void kernel_launch(void* const* d_in, const int* in_sizes, int n_in,
                              void* d_out, int out_size, void* d_ws, size_t ws_size,
                              hipStream_t stream){
  const float* x     = (const float*)d_in[0];
  const float* eattr = (const float*)d_in[1];
  const int*   esrc  = (const int*)  d_in[2];
  const int*   edst  = (const int*)  d_in[3];
  const float* g1_wl = (const float*)d_in[4];
  const float* g1_wr = (const float*)d_in[5];
  const float* g1_we = (const float*)d_in[6];
  const float* g1_att= (const float*)d_in[7];
  const float* g1_b  = (const float*)d_in[8];
  const float* g2_wl = (const float*)d_in[9];
  const float* g2_wr = (const float*)d_in[10];
  const float* g2_we = (const float*)d_in[11];
  const float* g2_att= (const float*)d_in[12];
  const float* g2_b  = (const float*)d_in[13];
  const float* wih_f = (const float*)d_in[14];
  const float* whh_f = (const float*)d_in[15];
  const float* bih_f = (const float*)d_in[16];
  const float* bhh_f = (const float*)d_in[17];
  const float* wih_b = (const float*)d_in[18];
  const float* whh_b = (const float*)d_in[19];
  const float* bih_b = (const float*)d_in[20];
  const float* bhh_b = (const float*)d_in[21];
  const float* fc_w  = (const float*)d_in[22];
  const float* fc_b  = (const float*)d_in[23];
  float* out = (float*)d_out;

  float* ws = (float*)d_ws;
  size_t o = 0;
  auto alloc = [&](size_t nfloats) -> float* {
    float* p = ws + o; o += (nfloats + 3) & ~(size_t)3; return p;
  };
  float* xlrA    = alloc((size_t)N_NODES * 1024);
  float* xlrB    = alloc((size_t)N_NODES * 1024);
  ushort_t* h1h  = (ushort_t*)alloc((size_t)N_NODES * 512 / 2 + 4);
  ushort_t* h1l  = (ushort_t*)alloc((size_t)N_NODES * 512 / 2 + 4);
  const size_t ETOT = (size_t)T_SEQ * N_NODES * HID;
  ushort_t* embh = (ushort_t*)alloc(ETOT / 2);
  ushort_t* embl = (ushort_t*)alloc(ETOT / 2);
  const size_t HTOT = (size_t)N_NODES * GRU_H;
  ushort_t* hbuf[8];
  for (int i = 0; i < 8; i++) hbuf[i] = (ushort_t*)alloc(HTOT / 2 + 4);
  float* lsum  = alloc((size_t)N_NODES * 3);
  float* lattr = alloc((size_t)N_NODES * 3);
  float* gmean = alloc(512);
  float4* emeta = (float4*)alloc((size_t)EF * 4);
  ushort_t* W1h = (ushort_t*)alloc(1024*128/2);
  ushort_t* W1l = (ushort_t*)alloc(1024*128/2);
  ushort_t* W2h = (ushort_t*)alloc(128*512/2);
  ushort_t* W2l = (ushort_t*)alloc(128*512/2);
  const size_t WPK = 4 * 10 * 192 * 32;     // 245760 shorts
  ushort_t* WpFh = (ushort_t*)alloc(WPK/2);
  ushort_t* WpFl = (ushort_t*)alloc(WPK/2);
  ushort_t* WpBh = (ushort_t*)alloc(WPK/2);
  ushort_t* WpBl = (ushort_t*)alloc(WPK/2);
  int* deg     = (int*)alloc(N_NODES + 4);
  int* row_ptr = (int*)alloc(N_NODES + 4);
  int* cursor  = (int*)alloc(N_NODES + 4);
  int* col     = (int*)alloc(E_EDGES + 4);
  unsigned* bar = (unsigned*)alloc(8);      // bar[0]=gat_all, bar[1]=gru_all

  hipMemsetAsync(deg,    0, N_NODES * sizeof(int), stream);
  hipMemsetAsync(cursor, 0, N_NODES * sizeof(int), stream);
  hipMemsetAsync(lsum,   0, (size_t)N_NODES * 3 * sizeof(float), stream);
  hipMemsetAsync(gmean,  0, 512 * sizeof(float), stream);
  hipMemsetAsync(bar,    0, 8 * sizeof(unsigned), stream);
  hipMemsetAsync(hbuf[0], 0, HTOT * sizeof(ushort_t), stream);
  hipMemsetAsync(hbuf[1], 0, HTOT * sizeof(ushort_t), stream);
  hipMemsetAsync(hbuf[4], 0, HTOT * sizeof(ushort_t), stream);
  hipMemsetAsync(hbuf[5], 0, HTOT * sizeof(ushort_t), stream);

  deg_loop_kernel<<<(E_EDGES + 255)/256, 256, 0, stream>>>(edst, eattr, deg, lsum);
  loop_div_kernel<<<(N_NODES + 255)/256, 256, 0, stream>>>(deg, lsum, lattr);
  scan_rowptr_kernel<<<1, 256, 0, stream>>>(deg, row_ptr);
  csr_fill_kernel<<<(E_EDGES + 255)/256, 256, 0, stream>>>(edst, row_ptr, cursor, col);
  build_emeta<<<(EF + 255)/256, 256, 0, stream>>>(eattr, lattr, esrc, emeta);
  split_w_gat1<<<(1024*128 + 255)/256, 256, 0, stream>>>(g1_wl, g1_wr, W1h, W1l);
  split_w_gat2<<<(128*512 + 255)/256, 256, 0, stream>>>(g2_wl, g2_wr, W2h, W2l);
  pack_w_gru<<<(int)((WPK + 255)/256), 256, 0, stream>>>(wih_f, whh_f, WpFh, WpFl);
  pack_w_gru<<<(int)((WPK + 255)/256), 256, 0, stream>>>(wih_b, whh_b, WpBh, WpBl);

  // persistent GAT: one launch for the whole 32-step pipeline
  {
    GatAllArgs ga;
    ga.x = x; ga.emeta = emeta; ga.row_ptr = row_ptr; ga.col = col;
    ga.W1h = W1h; ga.W1l = W1l; ga.W2h = W2h; ga.W2l = W2l;
    ga.g1_we = g1_we; ga.g1_att = g1_att; ga.g1_b = g1_b;
    ga.g2_we = g2_we; ga.g2_att = g2_att; ga.g2_b = g2_b;
    ga.xlrA = xlrA; ga.xlrB = xlrB; ga.h1h = h1h; ga.h1l = h1l;
    ga.embh = embh; ga.embl = embl;
    ga.bar = &bar[0];
    gat_all<<<NB_GAT, 256, 0, stream>>>(ga);
  }

  // persistent GRU: one launch for all 32 steps, both directions
  {
    GruAllArgs gaa;
    gaa.embh = embh; gaa.embl = embl;
    gaa.WpH[0] = WpFh; gaa.WpL[0] = WpFl; gaa.WpH[1] = WpBh; gaa.WpL[1] = WpBl;
    gaa.BIH[0] = bih_f; gaa.BHH[0] = bhh_f; gaa.BIH[1] = bih_b; gaa.BHH[1] = bhh_b;
    for (int i = 0; i < 8; i++) gaa.hb[i] = hbuf[i];
    gaa.bar = &bar[1];
    gru_all<<<NB_GRU, 256, 0, stream>>>(gaa);
  }

  mean_kernel<<<(N_NODES + 49)/50, 256, 0, stream>>>(hbuf[0], hbuf[1], hbuf[4], hbuf[5], gmean);
  fc_kernel<<<33, 64, 0, stream>>>(gmean, fc_w, fc_b, out);
}

// Round 6
// 8236.192 us; speedup vs baseline: 3.9636x; 1.5982x over previous
//
#include <hip/hip_runtime.h>

#define T_SEQ   32
#define N_NODES 10000
#define E_EDGES 160000
#define EF      (E_EDGES + N_NODES)
#define IN_CH   128
#define HID     64
#define HEADS   8
#define HC      512
#define GRU_H   256
#define G3      768

typedef __attribute__((ext_vector_type(8))) short short8;
typedef __attribute__((ext_vector_type(4))) float f32x4;
typedef unsigned short ushort_t;

__device__ __forceinline__ float wave_reduce_sum(float v){
#pragma unroll
  for (int off = 32; off; off >>= 1) v += __shfl_xor(v, off, 64);
  return v;
}

__device__ __forceinline__ ushort_t f2bf(float v){
  unsigned u = __float_as_uint(v);
  unsigned r = u + 0x7FFFu + ((u >> 16) & 1u);
  return (ushort_t)(r >> 16);
}
__device__ __forceinline__ float bf2f(ushort_t b){
  return __uint_as_float(((unsigned)b) << 16);
}

// ---------------- graph setup ----------------

__global__ __launch_bounds__(256)
void deg_loop_kernel(const int* __restrict__ edst, const float* __restrict__ eattr,
                     int* __restrict__ deg, float* __restrict__ lsum){
  int e = blockIdx.x * 256 + threadIdx.x;
  if (e < E_EDGES){
    int d = edst[e];
    atomicAdd(&deg[d], 1);
    atomicAdd(&lsum[d*3+0], eattr[e*3+0]);
    atomicAdd(&lsum[d*3+1], eattr[e*3+1]);
    atomicAdd(&lsum[d*3+2], eattr[e*3+2]);
  }
}

__global__ __launch_bounds__(256)
void loop_div_kernel(const int* __restrict__ deg, const float* __restrict__ lsum,
                     float* __restrict__ lattr){
  int n = blockIdx.x * 256 + threadIdx.x;
  if (n < N_NODES){
    float d = fmaxf((float)deg[n], 1.0f);
    lattr[n*3+0] = lsum[n*3+0] / d;
    lattr[n*3+1] = lsum[n*3+1] / d;
    lattr[n*3+2] = lsum[n*3+2] / d;
  }
}

__global__ __launch_bounds__(256)
void scan_rowptr_kernel(const int* __restrict__ deg, int* __restrict__ row_ptr){
  __shared__ int sums[256];
  __shared__ int base[256];
  int tid = threadIdx.x;
  const int CH = 40;
  int start = tid * CH;
  int s = 0;
  for (int k = 0; k < CH; k++){
    int n = start + k;
    if (n < N_NODES) s += deg[n];
  }
  sums[tid] = s;
  __syncthreads();
  if (tid == 0){
    int acc = 0;
    for (int i = 0; i < 256; i++){ base[i] = acc; acc += sums[i]; }
  }
  __syncthreads();
  int acc = base[tid];
  for (int k = 0; k < CH; k++){
    int n = start + k;
    if (n < N_NODES){ row_ptr[n] = acc; acc += deg[n]; }
    else if (n == N_NODES){ row_ptr[n] = acc; }
  }
}

__global__ __launch_bounds__(256)
void csr_fill_kernel(const int* __restrict__ edst, const int* __restrict__ row_ptr,
                     int* __restrict__ cursor, int* __restrict__ col){
  int e = blockIdx.x * 256 + threadIdx.x;
  if (e < E_EDGES){
    int d = edst[e];
    int pos = row_ptr[d] + atomicAdd(&cursor[d], 1);
    col[pos] = e;
  }
}

__global__ __launch_bounds__(256)
void build_emeta(const float* __restrict__ eattr, const float* __restrict__ lattr,
                 const int* __restrict__ esrc, float4* __restrict__ emeta){
  int e = blockIdx.x * 256 + threadIdx.x;
  if (e < E_EDGES){
    emeta[e] = make_float4(eattr[e*3], eattr[e*3+1], eattr[e*3+2], __int_as_float(esrc[e]));
  } else if (e < EF){
    int n = e - E_EDGES;
    emeta[e] = make_float4(lattr[n*3], lattr[n*3+1], lattr[n*3+2], __int_as_float(n));
  }
}

// ---------------- pre-split kernels ----------------

// vectorized: 4 floats / thread (G13)
__global__ __launch_bounds__(256)
void split_arr4(const float4* __restrict__ src, ushort4* __restrict__ hi,
                ushort4* __restrict__ lo, long n4){
  long idx = (long)blockIdx.x * 256 + threadIdx.x;
  if (idx < n4){
    float4 v = src[idx];
    float vv[4] = {v.x, v.y, v.z, v.w};
    ushort4 h, l;
    ushort_t* hp = (ushort_t*)&h; ushort_t* lp = (ushort_t*)&l;
#pragma unroll
    for (int i = 0; i < 4; i++){
      ushort_t hh = f2bf(vv[i]);
      hp[i] = hh; lp[i] = f2bf(vv[i] - bf2f(hh));
    }
    hi[idx] = h; lo[idx] = l;
  }
}

__global__ __launch_bounds__(256)
void split_w_gat1(const float* __restrict__ wl, const float* __restrict__ wr,
                  ushort_t* __restrict__ hi, ushort_t* __restrict__ lo){
  int idx = blockIdx.x * 256 + threadIdx.x;
  if (idx >= 1024 * 128) return;
  int n = idx >> 7, k = idx & 127;
  float v = (n < 512) ? wl[k * 512 + n] : wr[k * 512 + (n - 512)];
  ushort_t h = f2bf(v);
  hi[idx] = h; lo[idx] = f2bf(v - bf2f(h));
}

__global__ __launch_bounds__(256)
void split_w_gat2(const float* __restrict__ wl, const float* __restrict__ wr,
                  ushort_t* __restrict__ hi, ushort_t* __restrict__ lo){
  int idx = blockIdx.x * 256 + threadIdx.x;
  if (idx >= 128 * 512) return;
  int n = idx >> 9, k = idx & 511;
  float v = (n < 64) ? wl[k * 64 + n] : wr[k * 64 + (n - 64)];
  ushort_t h = f2bf(v);
  hi[idx] = h; lo[idx] = f2bf(v - bf2f(h));
}

// GRU weight pack: Wpk[jt][kc][r][32] with r = g*64 + jj; weight row g*256+jt*64+jj,
// k = kc*32 + kk; k<64 from wih, else whh. hi/lo split.
__global__ __launch_bounds__(256)
void pack_w_gru(const float* __restrict__ wih, const float* __restrict__ whh,
                ushort_t* __restrict__ hi, ushort_t* __restrict__ lo){
  int idx = blockIdx.x * 256 + threadIdx.x;
  if (idx >= 4 * 10 * 192 * 32) return;
  int kk = idx & 31;
  int r  = (idx >> 5) % 192;
  int kc = (idx >> 5) / 192 % 10;
  int jt = idx / (32 * 192 * 10);
  int g = r >> 6, jj = r & 63;
  int wrow = g * 256 + jt * 64 + jj;
  int k = kc * 32 + kk;
  float v = (k < 64) ? wih[wrow * 64 + k] : whh[wrow * 256 + (k - 64)];
  ushort_t h = f2bf(v);
  hi[idx] = h; lo[idx] = f2bf(v - bf2f(h));
}

// ------------- barrier-free bf16x3 GEMM (GAT path, weights tiny/L2-hot) ----

__global__ __launch_bounds__(256)
void gemm_nolds(const ushort_t* __restrict__ Ah, const ushort_t* __restrict__ Al,
                const ushort_t* __restrict__ Bh, const ushort_t* __restrict__ Bl,
                float* __restrict__ C, int M, int K, int N){
  int tid = threadIdx.x;
  int w = tid >> 6, lane = tid & 63;
  int m16 = lane & 15, quad = lane >> 4;
  int n0 = (blockIdx.y * 4 + w) * 64;
  if (n0 >= N) return;
  int m0 = blockIdx.x * 32;

  f32x4 acc[2][4];
#pragma unroll
  for (int i = 0; i < 2; i++)
#pragma unroll
    for (int j = 0; j < 4; j++) acc[i][j] = (f32x4){0,0,0,0};

  int ar0 = m0 + m16;      if (ar0 >= M) ar0 = M - 1;
  int ar1 = m0 + 16 + m16; if (ar1 >= M) ar1 = M - 1;
  const ushort_t* Ah0 = Ah + (size_t)ar0 * K + quad * 8;
  const ushort_t* Al0 = Al + (size_t)ar0 * K + quad * 8;
  const ushort_t* Ah1 = Ah + (size_t)ar1 * K + quad * 8;
  const ushort_t* Al1 = Al + (size_t)ar1 * K + quad * 8;

  for (int k0 = 0; k0 < K; k0 += 32){
    short8 a_h[2], a_l[2];
    a_h[0] = *(const short8*)(Ah0 + k0); a_l[0] = *(const short8*)(Al0 + k0);
    a_h[1] = *(const short8*)(Ah1 + k0); a_l[1] = *(const short8*)(Al1 + k0);
#pragma unroll
    for (int nt = 0; nt < 4; nt++){
      size_t boff = (size_t)(n0 + nt * 16 + m16) * K + k0 + quad * 8;
      short8 b_h = *(const short8*)(Bh + boff);
      short8 b_l = *(const short8*)(Bl + boff);
#pragma unroll
      for (int mt = 0; mt < 2; mt++){
        acc[mt][nt] = __builtin_amdgcn_mfma_f32_16x16x32_bf16(a_h[mt], b_h, acc[mt][nt],0,0,0);
        acc[mt][nt] = __builtin_amdgcn_mfma_f32_16x16x32_bf16(a_h[mt], b_l, acc[mt][nt],0,0,0);
        acc[mt][nt] = __builtin_amdgcn_mfma_f32_16x16x32_bf16(a_l[mt], b_h, acc[mt][nt],0,0,0);
      }
    }
  }
#pragma unroll
  for (int mt = 0; mt < 2; mt++){
    int row = m0 + mt * 16 + quad * 4;
#pragma unroll
    for (int nt = 0; nt < 4; nt++){
      int cc = n0 + nt * 16 + m16;
#pragma unroll
      for (int r4 = 0; r4 < 4; r4++){
        if (row + r4 < M) C[(size_t)(row + r4) * N + cc] = acc[mt][nt][r4];
      }
    }
  }
}

// ------------- no-LDS fused GRU step, both directions ----------------------
// gemm_nolds-style: weights are L2-hot (1MB/dir), read fragments directly from
// global; no LDS, no barriers, no DMA drains. Block = 64 nodes x 64 j-cols,
// 4 waves in 2x2 (wm rows, wn cols). __launch_bounds__(256,4) caps VGPR<=128
// -> 16 waves/CU (2x the r2 LDS version's occupancy). MFMA order identical to
// r2 -> bit-identical accumulators. first=1 (s==0): h_in==0, so the Hin
// K-chunks contribute 0 and are skipped; hold=0 (gh bias path kept via BHH).

struct GruArgs {
  const ushort_t *EtH[2], *EtL[2];     // [N][64]
  const ushort_t *WpH[2], *WpL[2];     // packed [4][10][192][32]
  const float    *BIH[2], *BHH[2];
  const ushort_t *HinH[2],*HinL[2];    // [N][256]
  ushort_t *HoutH[2], *HoutL[2];
  int first;
};

#define GRUN_STEP(KC, NTGT, AH0, AL0, AH1, AL1, KOFF)                          \
  {                                                                            \
    short8 a_h[2], a_l[2];                                                     \
    a_h[0] = *(const short8*)((AH0) + (KOFF));                                 \
    a_l[0] = *(const short8*)((AL0) + (KOFF));                                 \
    a_h[1] = *(const short8*)((AH1) + (KOFF));                                 \
    a_l[1] = *(const short8*)((AL1) + (KOFF));                                 \
    const ushort_t* bh = WBh + (size_t)(KC) * 6144;                            \
    const ushort_t* bl = WBl + (size_t)(KC) * 6144;                            \
    _Pragma("unroll")                                                          \
    for (int g = 0; g < 3; g++){                                               \
      int tgt = (g < 2) ? g : (NTGT);                                          \
      _Pragma("unroll")                                                        \
      for (int nt = 0; nt < 2; nt++){                                          \
        int r = g * 64 + wn * 32 + nt * 16 + m16;                              \
        short8 b_h = *(const short8*)(bh + r * 32 + quad * 8);                 \
        short8 b_l = *(const short8*)(bl + r * 32 + quad * 8);                 \
        _Pragma("unroll")                                                      \
        for (int mt = 0; mt < 2; mt++){                                        \
          acc[tgt][mt][nt] = __builtin_amdgcn_mfma_f32_16x16x32_bf16(a_h[mt], b_h, acc[tgt][mt][nt],0,0,0); \
          acc[tgt][mt][nt] = __builtin_amdgcn_mfma_f32_16x16x32_bf16(a_h[mt], b_l, acc[tgt][mt][nt],0,0,0); \
          acc[tgt][mt][nt] = __builtin_amdgcn_mfma_f32_16x16x32_bf16(a_l[mt], b_h, acc[tgt][mt][nt],0,0,0); \
        }                                                                      \
      }                                                                        \
    }                                                                          \
  }

__global__ __launch_bounds__(256, 4)
void gru_nolds(GruArgs ga){
  int dir = blockIdx.z;
  const ushort_t* EtH  = ga.EtH[dir];  const ushort_t* EtL  = ga.EtL[dir];
  const ushort_t* WpH  = ga.WpH[dir];  const ushort_t* WpL  = ga.WpL[dir];
  const float*    BIH  = ga.BIH[dir];  const float*    BHH  = ga.BHH[dir];
  const ushort_t* HinH = ga.HinH[dir]; const ushort_t* HinL = ga.HinL[dir];
  ushort_t* HoutH = ga.HoutH[dir];     ushort_t* HoutL = ga.HoutL[dir];

  int tid = threadIdx.x;
  int w = tid >> 6, lane = tid & 63;
  int wm = w >> 1, wn = w & 1;
  int m16 = lane & 15, quad = lane >> 4;
  int m0 = blockIdx.x * 64;
  int jt = blockIdx.y;               // j-tile of 64
  int j0 = jt * 64;

  f32x4 acc[4][2][2];                // [r,z,n_in,n_hid][mt][nt]
#pragma unroll
  for (int g = 0; g < 4; g++)
#pragma unroll
    for (int i = 0; i < 2; i++)
#pragma unroll
      for (int j = 0; j < 2; j++) acc[g][i][j] = (f32x4){0,0,0,0};

  int ar0 = m0 + wm * 32 + m16;      if (ar0 >= N_NODES) ar0 = N_NODES - 1;
  int ar1 = m0 + wm * 32 + 16 + m16; if (ar1 >= N_NODES) ar1 = N_NODES - 1;

  const ushort_t* EA0h = EtH + (size_t)ar0 * 64 + quad * 8;
  const ushort_t* EA0l = EtL + (size_t)ar0 * 64 + quad * 8;
  const ushort_t* EA1h = EtH + (size_t)ar1 * 64 + quad * 8;
  const ushort_t* EA1l = EtL + (size_t)ar1 * 64 + quad * 8;
  const ushort_t* HA0h = HinH + (size_t)ar0 * 256 + quad * 8;
  const ushort_t* HA0l = HinL + (size_t)ar0 * 256 + quad * 8;
  const ushort_t* HA1h = HinH + (size_t)ar1 * 256 + quad * 8;
  const ushort_t* HA1l = HinL + (size_t)ar1 * 256 + quad * 8;
  const ushort_t* WBh = WpH + (size_t)jt * 10 * 6144;
  const ushort_t* WBl = WpL + (size_t)jt * 10 * 6144;

  // K 0..63 : Et input, n-gate target = acc[2]
  GRUN_STEP(0, 2, EA0h, EA0l, EA1h, EA1l, 0)
  GRUN_STEP(1, 2, EA0h, EA0l, EA1h, EA1l, 32)
  // K 64..319 : Hin, n-gate target = acc[3] (skipped when h_in == 0)
  if (!ga.first){
    for (int kc = 2; kc < 10; kc++){
      GRUN_STEP(kc, 3, HA0h, HA0l, HA1h, HA1l, (kc - 2) * 32)
    }
  }

#pragma unroll
  for (int mt = 0; mt < 2; mt++){
    int row = m0 + wm * 32 + mt * 16 + quad * 4;
#pragma unroll
    for (int nt = 0; nt < 2; nt++){
      int j = j0 + wn * 32 + nt * 16 + m16;
      float br  = BIH[j] + BHH[j];
      float bz  = BIH[GRU_H + j] + BHH[GRU_H + j];
      float bni = BIH[2*GRU_H + j];
      float bnh = BHH[2*GRU_H + j];
#pragma unroll
      for (int r4 = 0; r4 < 4; r4++){
        int node = row + r4;
        if (node < N_NODES){
          float rr = 1.f / (1.f + __expf(-(acc[0][mt][nt][r4] + br)));
          float zz = 1.f / (1.f + __expf(-(acc[1][mt][nt][r4] + bz)));
          float nn = tanhf(acc[2][mt][nt][r4] + bni + rr * (acc[3][mt][nt][r4] + bnh));
          size_t hidx = (size_t)node * GRU_H + j;
          float hold = ga.first ? 0.f : (bf2f(HinH[hidx]) + bf2f(HinL[hidx]));
          float hv = (1.f - zz) * nn + zz * hold;
          ushort_t hh = f2bf(hv);
          HoutH[hidx] = hh;
          HoutL[hidx] = f2bf(hv - bf2f(hh));
        }
      }
    }
  }
}

// ---------------- fused GAT layer 1 ----------------
// 1 wave = 1 node; edges processed in pairs so two xl-row gathers are in
// flight simultaneously.

__device__ __forceinline__ void gat1_half(float4 xl, float4 xr,
                                          float a0, float a1, float a2,
                                          float4 we0, float4 we1, float4 we2,
                                          float4 at, bool valid,
                                          float& den, float4& acc){
  float vx = xl.x + xr.x + a0*we0.x + a1*we1.x + a2*we2.x;
  float vy = xl.y + xr.y + a0*we0.y + a1*we1.y + a2*we2.y;
  float vz = xl.z + xr.z + a0*we0.z + a1*we1.z + a2*we2.z;
  float vw = xl.w + xr.w + a0*we0.w + a1*we1.w + a2*we2.w;
  vx = fmaxf(vx, 0.2f*vx); vy = fmaxf(vy, 0.2f*vy);
  vz = fmaxf(vz, 0.2f*vz); vw = fmaxf(vw, 0.2f*vw);
  float pm = vx*at.x + vy*at.y + vz*at.z + vw*at.w;
  pm += __shfl_xor(pm, 1, 64); pm += __shfl_xor(pm, 2, 64);
  pm += __shfl_xor(pm, 4, 64); pm += __shfl_xor(pm, 8, 64);
  float wgt = valid ? __expf(pm) : 0.f;
  den += wgt;
  acc.x += wgt * xl.x; acc.y += wgt * xl.y;
  acc.z += wgt * xl.z; acc.w += wgt * xl.w;
}

__global__ __launch_bounds__(256)
void gat1_fused(const float* __restrict__ xlr, const float4* __restrict__ emeta,
                const int* __restrict__ row_ptr, const int* __restrict__ col,
                const float* __restrict__ we, const float* __restrict__ att,
                const float* __restrict__ bias,
                ushort_t* __restrict__ outh, ushort_t* __restrict__ outl){
  int n = (blockIdx.x * 256 + threadIdx.x) >> 6;
  int lane = threadIdx.x & 63;
  if (n >= N_NODES) return;
  int ch0 = lane * 4;
  int ch1 = 256 + lane * 4;

  float4 att0 = *(const float4*)&att[ch0];
  float4 att1 = *(const float4*)&att[ch1];
  float4 we00 = *(const float4*)&we[ch0],        we01 = *(const float4*)&we[ch1];
  float4 we10 = *(const float4*)&we[512 + ch0],  we11 = *(const float4*)&we[512 + ch1];
  float4 we20 = *(const float4*)&we[1024 + ch0], we21 = *(const float4*)&we[1024 + ch1];
  const float* xrow_n = xlr + (size_t)n * 1024;
  float4 xr0 = *(const float4*)&xrow_n[512 + ch0];
  float4 xr1 = *(const float4*)&xrow_n[512 + ch1];

  float den0 = 0.f, den1 = 0.f;
  float4 acc0 = make_float4(0,0,0,0), acc1 = make_float4(0,0,0,0);
  int beg = row_ptr[n], end = row_ptr[n + 1];

  for (int p = beg - 1; p < end; p += 2){
    int c0 = (p >= beg) ? col[p] : (E_EDGES + n);   // p==beg-1 -> self loop
    bool v1 = (p + 1 < end);
    int c1 = v1 ? col[p + 1] : c0;
    float4 mt0 = emeta[c0];
    float4 mt1 = emeta[c1];
    const float* xp0 = xlr + (size_t)__float_as_int(mt0.w) * 1024;
    const float* xp1 = xlr + (size_t)__float_as_int(mt1.w) * 1024;
    float4 xa0 = *(const float4*)&xp0[ch0];
    float4 xa1 = *(const float4*)&xp0[ch1];
    float4 xb0 = *(const float4*)&xp1[ch0];
    float4 xb1 = *(const float4*)&xp1[ch1];
    gat1_half(xa0, xr0, mt0.x, mt0.y, mt0.z, we00, we10, we20, att0, true, den0, acc0);
    gat1_half(xa1, xr1, mt0.x, mt0.y, mt0.z, we01, we11, we21, att1, true, den1, acc1);
    gat1_half(xb0, xr0, mt1.x, mt1.y, mt1.z, we00, we10, we20, att0, v1, den0, acc0);
    gat1_half(xb1, xr1, mt1.x, mt1.y, mt1.z, we01, we11, we21, att1, v1, den1, acc1);
  }

  float4 b0 = *(const float4*)&bias[ch0];
  float4 b1 = *(const float4*)&bias[ch1];
  float id0 = 1.f / den0, id1 = 1.f / den1;
  float o[8];
  o[0] = acc0.x*id0 + b0.x; o[1] = acc0.y*id0 + b0.y;
  o[2] = acc0.z*id0 + b0.z; o[3] = acc0.w*id0 + b0.w;
  o[4] = acc1.x*id1 + b1.x; o[5] = acc1.y*id1 + b1.y;
  o[6] = acc1.z*id1 + b1.z; o[7] = acc1.w*id1 + b1.w;
  ushort4 h0, h1v, l0, l1v;
  ushort_t* hp0 = (ushort_t*)&h0; ushort_t* hp1 = (ushort_t*)&h1v;
  ushort_t* lp0 = (ushort_t*)&l0; ushort_t* lp1 = (ushort_t*)&l1v;
#pragma unroll
  for (int i = 0; i < 8; i++){
    float v = o[i];
    v = v > 0.f ? v : (__expf(v) - 1.f);
    ushort_t hh = f2bf(v);
    ushort_t ll = f2bf(v - bf2f(hh));
    if (i < 4){ hp0[i] = hh; lp0[i] = ll; } else { hp1[i-4] = hh; lp1[i-4] = ll; }
  }
  *(ushort4*)&outh[(size_t)n * 512 + ch0] = h0;
  *(ushort4*)&outh[(size_t)n * 512 + ch1] = h1v;
  *(ushort4*)&outl[(size_t)n * 512 + ch0] = l0;
  *(ushort4*)&outl[(size_t)n * 512 + ch1] = l1v;
}

// ---------------- fused GAT layer 2 ----------------

__global__ __launch_bounds__(256)
void gat2_fused(const float* __restrict__ xlr, const float4* __restrict__ emeta,
                const int* __restrict__ row_ptr, const int* __restrict__ col,
                const float* __restrict__ we, const float* __restrict__ att,
                const float* __restrict__ bias,
                ushort_t* __restrict__ outh, ushort_t* __restrict__ outl){
  int n = (blockIdx.x * 256 + threadIdx.x) >> 6;
  int lane = threadIdx.x & 63;
  if (n >= N_NODES) return;
  int g = lane >> 4;
  int c4 = (lane & 15) * 4;

  float4 attq = *(const float4*)&att[c4];
  float4 we0q = *(const float4*)&we[c4];
  float4 we1q = *(const float4*)&we[64 + c4];
  float4 we2q = *(const float4*)&we[128 + c4];
  float4 xr4  = *(const float4*)&xlr[(size_t)n * 128 + 64 + c4];

  float den = 0.f;
  float4 acc = make_float4(0,0,0,0);
  int beg = row_ptr[n], end = row_ptr[n + 1];

  for (int p0 = beg - 1; p0 < end; p0 += 4){
    int pp = p0 + g;
    bool valid = pp < end;
    int s = n; float a0 = 0.f, a1 = 0.f, a2 = 0.f;
    if (valid){
      float4 mt = (pp < beg) ? emeta[E_EDGES + n] : emeta[col[pp]];
      a0 = mt.x; a1 = mt.y; a2 = mt.z; s = __float_as_int(mt.w);
    }
    float4 xl4 = *(const float4*)&xlr[(size_t)s * 128 + c4];
    float vx = xl4.x + xr4.x + a0*we0q.x + a1*we1q.x + a2*we2q.x;
    float vy = xl4.y + xr4.y + a0*we0q.y + a1*we1q.y + a2*we2q.y;
    float vz = xl4.z + xr4.z + a0*we0q.z + a1*we1q.z + a2*we2q.z;
    float vw = xl4.w + xr4.w + a0*we0q.w + a1*we1q.w + a2*we2q.w;
    vx = fmaxf(vx, 0.2f*vx); vy = fmaxf(vy, 0.2f*vy);
    vz = fmaxf(vz, 0.2f*vz); vw = fmaxf(vw, 0.2f*vw);
    float pm = vx*attq.x + vy*attq.y + vz*attq.z + vw*attq.w;
    pm += __shfl_xor(pm, 1, 64); pm += __shfl_xor(pm, 2, 64);
    pm += __shfl_xor(pm, 4, 64); pm += __shfl_xor(pm, 8, 64);
    float wgt = valid ? __expf(pm) : 0.f;
    den += wgt;
    acc.x += wgt * xl4.x; acc.y += wgt * xl4.y;
    acc.z += wgt * xl4.z; acc.w += wgt * xl4.w;
  }
#pragma unroll
  for (int off = 16; off <= 32; off <<= 1){
    den   += __shfl_xor(den, off, 64);
    acc.x += __shfl_xor(acc.x, off, 64);
    acc.y += __shfl_xor(acc.y, off, 64);
    acc.z += __shfl_xor(acc.z, off, 64);
    acc.w += __shfl_xor(acc.w, off, 64);
  }
  if (g == 0){
    float4 bq = *(const float4*)&bias[c4];
    float id = 1.f / den;
    float o[4];
    o[0] = acc.x*id + bq.x; o[1] = acc.y*id + bq.y;
    o[2] = acc.z*id + bq.z; o[3] = acc.w*id + bq.w;
    ushort4 hv, lv;
    ushort_t* hp = (ushort_t*)&hv; ushort_t* lp = (ushort_t*)&lv;
#pragma unroll
    for (int i = 0; i < 4; i++){
      float v = o[i];
      v = v > 0.f ? v : (__expf(v) - 1.f);
      ushort_t hh = f2bf(v);
      hp[i] = hh; lp[i] = f2bf(v - bf2f(hh));
    }
    *(ushort4*)&outh[(size_t)n * 64 + c4] = hv;
    *(ushort4*)&outl[(size_t)n * 64 + c4] = lv;
  }
}

// ---------------- tail ----------------

__global__ __launch_bounds__(256)
void mean_kernel(const ushort_t* __restrict__ hfh, const ushort_t* __restrict__ hfl,
                 const ushort_t* __restrict__ hbh, const ushort_t* __restrict__ hbl,
                 float* __restrict__ g){
  int k = threadIdx.x;
  int n0 = blockIdx.x * 50;
  int n1 = n0 + 50; if (n1 > N_NODES) n1 = N_NODES;
  float sf = 0.f, sb = 0.f;
  for (int n = n0; n < n1; n++){
    size_t i = (size_t)n * GRU_H + k;
    sf += bf2f(hfh[i]) + bf2f(hfl[i]);
    sb += bf2f(hbh[i]) + bf2f(hbl[i]);
  }
  atomicAdd(&g[k], sf);
  atomicAdd(&g[GRU_H + k], sb);
}

__global__ __launch_bounds__(64)
void fc_kernel(const float* __restrict__ g, const float* __restrict__ W,
               const float* __restrict__ b, float* __restrict__ out){
  int j = blockIdx.x;
  int lane = threadIdx.x;
  float s = 0.f;
  for (int k = lane; k < 2 * GRU_H; k += 64) s += g[k] * W[j * (2 * GRU_H) + k];
  s = wave_reduce_sum(s);
  if (lane == 0) out[j] = b[j] + s * (1.0f / N_NODES);
}

// ---------------- launch ----------------

extern "C" void kernel_launch(void* const* d_in, const int* in_sizes, int n_in,
                              void* d_out, int out_size, void* d_ws, size_t ws_size,
                              hipStream_t stream){
  const float* x     = (const float*)d_in[0];
  const float* eattr = (const float*)d_in[1];
  const int*   esrc  = (const int*)  d_in[2];
  const int*   edst  = (const int*)  d_in[3];
  const float* g1_wl = (const float*)d_in[4];
  const float* g1_wr = (const float*)d_in[5];
  const float* g1_we = (const float*)d_in[6];
  const float* g1_att= (const float*)d_in[7];
  const float* g1_b  = (const float*)d_in[8];
  const float* g2_wl = (const float*)d_in[9];
  const float* g2_wr = (const float*)d_in[10];
  const float* g2_we = (const float*)d_in[11];
  const float* g2_att= (const float*)d_in[12];
  const float* g2_b  = (const float*)d_in[13];
  const float* wih_f = (const float*)d_in[14];
  const float* whh_f = (const float*)d_in[15];
  const float* bih_f = (const float*)d_in[16];
  const float* bhh_f = (const float*)d_in[17];
  const float* wih_b = (const float*)d_in[18];
  const float* whh_b = (const float*)d_in[19];
  const float* bih_b = (const float*)d_in[20];
  const float* bhh_b = (const float*)d_in[21];
  const float* fc_w  = (const float*)d_in[22];
  const float* fc_b  = (const float*)d_in[23];
  float* out = (float*)d_out;

  float* ws = (float*)d_ws;
  size_t o = 0;
  auto alloc = [&](size_t nfloats) -> float* {
    float* p = ws + o; o += (nfloats + 3) & ~(size_t)3; return p;
  };
  const size_t XTOT = (size_t)T_SEQ * N_NODES * IN_CH;
  ushort_t* xh   = (ushort_t*)alloc(XTOT / 2);
  ushort_t* xlo  = (ushort_t*)alloc(XTOT / 2);
  float* xlr1    = alloc((size_t)N_NODES * 1024);
  ushort_t* h1h  = (ushort_t*)alloc((size_t)N_NODES * 512 / 2 + 4);
  ushort_t* h1l  = (ushort_t*)alloc((size_t)N_NODES * 512 / 2 + 4);
  const size_t ETOT = (size_t)T_SEQ * N_NODES * HID;
  ushort_t* embh = (ushort_t*)alloc(ETOT / 2);
  ushort_t* embl = (ushort_t*)alloc(ETOT / 2);
  const size_t HTOT = (size_t)N_NODES * GRU_H;
  ushort_t* hbuf[8];
  for (int i = 0; i < 8; i++) hbuf[i] = (ushort_t*)alloc(HTOT / 2 + 4);
  float* lsum  = alloc((size_t)N_NODES * 3);
  float* lattr = alloc((size_t)N_NODES * 3);
  float* gmean = alloc(512);
  float4* emeta = (float4*)alloc((size_t)EF * 4);
  ushort_t* W1h = (ushort_t*)alloc(1024*128/2);
  ushort_t* W1l = (ushort_t*)alloc(1024*128/2);
  ushort_t* W2h = (ushort_t*)alloc(128*512/2);
  ushort_t* W2l = (ushort_t*)alloc(128*512/2);
  const size_t WPK = 4 * 10 * 192 * 32;     // 245760 shorts
  ushort_t* WpFh = (ushort_t*)alloc(WPK/2);
  ushort_t* WpFl = (ushort_t*)alloc(WPK/2);
  ushort_t* WpBh = (ushort_t*)alloc(WPK/2);
  ushort_t* WpBl = (ushort_t*)alloc(WPK/2);
  int* deg     = (int*)alloc(N_NODES + 4);
  int* row_ptr = (int*)alloc(N_NODES + 4);
  int* cursor  = (int*)alloc(N_NODES + 4);
  int* col     = (int*)alloc(E_EDGES + 4);
  float* xlr2 = xlr1;

  hipMemsetAsync(deg,    0, N_NODES * sizeof(int), stream);
  hipMemsetAsync(cursor, 0, N_NODES * sizeof(int), stream);
  hipMemsetAsync(lsum,   0, (size_t)N_NODES * 3 * sizeof(float), stream);
  hipMemsetAsync(gmean,  0, 512 * sizeof(float), stream);
  // NOTE: no hbuf memsets — gru_nolds first=1 handles h0 == 0 exactly
  // (saves 4 x ~94us fillBuffer dispatches seen in r1/r2 profiles).

  deg_loop_kernel<<<(E_EDGES + 255)/256, 256, 0, stream>>>(edst, eattr, deg, lsum);
  loop_div_kernel<<<(N_NODES + 255)/256, 256, 0, stream>>>(deg, lsum, lattr);
  scan_rowptr_kernel<<<1, 256, 0, stream>>>(deg, row_ptr);
  csr_fill_kernel<<<(E_EDGES + 255)/256, 256, 0, stream>>>(edst, row_ptr, cursor, col);
  build_emeta<<<(EF + 255)/256, 256, 0, stream>>>(eattr, lattr, esrc, emeta);
  split_arr4<<<(int)(XTOT / 4 / 256), 256, 0, stream>>>(
      (const float4*)x, (ushort4*)xh, (ushort4*)xlo, (long)(XTOT / 4));
  split_w_gat1<<<(1024*128 + 255)/256, 256, 0, stream>>>(g1_wl, g1_wr, W1h, W1l);
  split_w_gat2<<<(128*512 + 255)/256, 256, 0, stream>>>(g2_wl, g2_wr, W2h, W2l);
  pack_w_gru<<<(int)((WPK + 255)/256), 256, 0, stream>>>(wih_f, whh_f, WpFh, WpFl);
  pack_w_gru<<<(int)((WPK + 255)/256), 256, 0, stream>>>(wih_b, whh_b, WpBh, WpBl);

  const int MB32  = (N_NODES + 31) / 32;    // 313
  const int MB64  = (N_NODES + 63) / 64;    // 157
  const int NODE_BLOCKS = (N_NODES + 3) / 4;
  for (int t = 0; t < T_SEQ; t++){
    const ushort_t* xth = xh  + (size_t)t * N_NODES * IN_CH;
    const ushort_t* xtl = xlo + (size_t)t * N_NODES * IN_CH;
    gemm_nolds<<<dim3(MB32, 4), 256, 0, stream>>>(xth, xtl, W1h, W1l, xlr1,
                                                  N_NODES, IN_CH, 1024);
    gat1_fused<<<NODE_BLOCKS, 256, 0, stream>>>(
        xlr1, emeta, row_ptr, col, g1_we, g1_att, g1_b, h1h, h1l);
    // N=128 -> only 2 waves needed; 128-thread blocks avoid dead waves
    gemm_nolds<<<dim3(MB32, 1), 128, 0, stream>>>(h1h, h1l, W2h, W2l, xlr2,
                                                  N_NODES, HC, 128);
    gat2_fused<<<NODE_BLOCKS, 256, 0, stream>>>(
        xlr2, emeta, row_ptr, col, g2_we, g2_att, g2_b,
        embh + (size_t)t * N_NODES * HID, embl + (size_t)t * N_NODES * HID);
  }

  // GRU: both directions per launch; fwd ping-pong hbuf[0,1]<->[2,3], bwd [4,5]<->[6,7]
  {
    int fin = 0, bin = 4;
    for (int s = 0; s < T_SEQ; s++){
      int fo = fin ^ 2, bo = bin ^ 2;
      GruArgs ga;
      ga.EtH[0] = embh + (size_t)s * N_NODES * HID;
      ga.EtL[0] = embl + (size_t)s * N_NODES * HID;
      ga.EtH[1] = embh + (size_t)(T_SEQ - 1 - s) * N_NODES * HID;
      ga.EtL[1] = embl + (size_t)(T_SEQ - 1 - s) * N_NODES * HID;
      ga.WpH[0] = WpFh; ga.WpL[0] = WpFl; ga.WpH[1] = WpBh; ga.WpL[1] = WpBl;
      ga.BIH[0] = bih_f; ga.BHH[0] = bhh_f; ga.BIH[1] = bih_b; ga.BHH[1] = bhh_b;
      ga.HinH[0] = hbuf[fin];   ga.HinL[0] = hbuf[fin+1];
      ga.HinH[1] = hbuf[bin];   ga.HinL[1] = hbuf[bin+1];
      ga.HoutH[0] = hbuf[fo];   ga.HoutL[0] = hbuf[fo+1];
      ga.HoutH[1] = hbuf[bo];   ga.HoutL[1] = hbuf[bo+1];
      ga.first = (s == 0) ? 1 : 0;
      gru_nolds<<<dim3(MB64, 4, 2), 256, 0, stream>>>(ga);
      fin = fo; bin = bo;
    }
  }

  mean_kernel<<<(N_NODES + 49)/50, 256, 0, stream>>>(hbuf[0], hbuf[1], hbuf[4], hbuf[5], gmean);
  fc_kernel<<<33, 64, 0, stream>>>(gmean, fc_w, fc_b, out);
}

// Round 7
// 8023.258 us; speedup vs baseline: 4.0688x; 1.0265x over previous
//
#include <hip/hip_runtime.h>

#define T_SEQ   32
#define N_NODES 10000
#define E_EDGES 160000
#define EF      (E_EDGES + N_NODES)
#define IN_CH   128
#define HID     64
#define HEADS   8
#define HC      512
#define GRU_H   256
#define G3      768

typedef __attribute__((ext_vector_type(8))) short short8;
typedef __attribute__((ext_vector_type(4))) float f32x4;
typedef unsigned short ushort_t;

__device__ __forceinline__ float wave_reduce_sum(float v){
#pragma unroll
  for (int off = 32; off; off >>= 1) v += __shfl_xor(v, off, 64);
  return v;
}

__device__ __forceinline__ ushort_t f2bf(float v){
  unsigned u = __float_as_uint(v);
  unsigned r = u + 0x7FFFu + ((u >> 16) & 1u);
  return (ushort_t)(r >> 16);
}
__device__ __forceinline__ float bf2f(ushort_t b){
  return __uint_as_float(((unsigned)b) << 16);
}

// 16B global -> LDS DMA (gfx950). LDS dest must be wave-uniform base + lane*16.
__device__ __forceinline__ void async_cp16(const void* g, void* l){
  __builtin_amdgcn_global_load_lds((const __attribute__((address_space(1))) void*)g,
                                   (__attribute__((address_space(3))) void*)l, 16, 0, 0);
}

// ---------------- graph setup ----------------

__global__ __launch_bounds__(256)
void deg_loop_kernel(const int* __restrict__ edst, const float* __restrict__ eattr,
                     int* __restrict__ deg, float* __restrict__ lsum){
  int e = blockIdx.x * 256 + threadIdx.x;
  if (e < E_EDGES){
    int d = edst[e];
    atomicAdd(&deg[d], 1);
    atomicAdd(&lsum[d*3+0], eattr[e*3+0]);
    atomicAdd(&lsum[d*3+1], eattr[e*3+1]);
    atomicAdd(&lsum[d*3+2], eattr[e*3+2]);
  }
}

__global__ __launch_bounds__(256)
void loop_div_kernel(const int* __restrict__ deg, const float* __restrict__ lsum,
                     float* __restrict__ lattr){
  int n = blockIdx.x * 256 + threadIdx.x;
  if (n < N_NODES){
    float d = fmaxf((float)deg[n], 1.0f);
    lattr[n*3+0] = lsum[n*3+0] / d;
    lattr[n*3+1] = lsum[n*3+1] / d;
    lattr[n*3+2] = lsum[n*3+2] / d;
  }
}

__global__ __launch_bounds__(256)
void scan_rowptr_kernel(const int* __restrict__ deg, int* __restrict__ row_ptr){
  __shared__ int sums[256];
  __shared__ int base[256];
  int tid = threadIdx.x;
  const int CH = 40;
  int start = tid * CH;
  int s = 0;
  for (int k = 0; k < CH; k++){
    int n = start + k;
    if (n < N_NODES) s += deg[n];
  }
  sums[tid] = s;
  __syncthreads();
  if (tid == 0){
    int acc = 0;
    for (int i = 0; i < 256; i++){ base[i] = acc; acc += sums[i]; }
  }
  __syncthreads();
  int acc = base[tid];
  for (int k = 0; k < CH; k++){
    int n = start + k;
    if (n < N_NODES){ row_ptr[n] = acc; acc += deg[n]; }
    else if (n == N_NODES){ row_ptr[n] = acc; }
  }
}

__global__ __launch_bounds__(256)
void csr_fill_kernel(const int* __restrict__ edst, const int* __restrict__ row_ptr,
                     int* __restrict__ cursor, int* __restrict__ col){
  int e = blockIdx.x * 256 + threadIdx.x;
  if (e < E_EDGES){
    int d = edst[e];
    int pos = row_ptr[d] + atomicAdd(&cursor[d], 1);
    col[pos] = e;
  }
}

__global__ __launch_bounds__(256)
void build_emeta(const float* __restrict__ eattr, const float* __restrict__ lattr,
                 const int* __restrict__ esrc, float4* __restrict__ emeta){
  int e = blockIdx.x * 256 + threadIdx.x;
  if (e < E_EDGES){
    emeta[e] = make_float4(eattr[e*3], eattr[e*3+1], eattr[e*3+2], __int_as_float(esrc[e]));
  } else if (e < EF){
    int n = e - E_EDGES;
    emeta[e] = make_float4(lattr[n*3], lattr[n*3+1], lattr[n*3+2], __int_as_float(n));
  }
}

// ---------------- pre-split kernels ----------------

// vectorized: 4 floats / thread (G13)
__global__ __launch_bounds__(256)
void split_arr4(const float4* __restrict__ src, ushort4* __restrict__ hi,
                ushort4* __restrict__ lo, long n4){
  long idx = (long)blockIdx.x * 256 + threadIdx.x;
  if (idx < n4){
    float4 v = src[idx];
    float vv[4] = {v.x, v.y, v.z, v.w};
    ushort4 h, l;
    ushort_t* hp = (ushort_t*)&h; ushort_t* lp = (ushort_t*)&l;
#pragma unroll
    for (int i = 0; i < 4; i++){
      ushort_t hh = f2bf(vv[i]);
      hp[i] = hh; lp[i] = f2bf(vv[i] - bf2f(hh));
    }
    hi[idx] = h; lo[idx] = l;
  }
}

__global__ __launch_bounds__(256)
void split_w_gat1(const float* __restrict__ wl, const float* __restrict__ wr,
                  ushort_t* __restrict__ hi, ushort_t* __restrict__ lo){
  int idx = blockIdx.x * 256 + threadIdx.x;
  if (idx >= 1024 * 128) return;
  int n = idx >> 7, k = idx & 127;
  float v = (n < 512) ? wl[k * 512 + n] : wr[k * 512 + (n - 512)];
  ushort_t h = f2bf(v);
  hi[idx] = h; lo[idx] = f2bf(v - bf2f(h));
}

__global__ __launch_bounds__(256)
void split_w_gat2(const float* __restrict__ wl, const float* __restrict__ wr,
                  ushort_t* __restrict__ hi, ushort_t* __restrict__ lo){
  int idx = blockIdx.x * 256 + threadIdx.x;
  if (idx >= 128 * 512) return;
  int n = idx >> 9, k = idx & 511;
  float v = (n < 64) ? wl[k * 64 + n] : wr[k * 64 + (n - 64)];
  ushort_t h = f2bf(v);
  hi[idx] = h; lo[idx] = f2bf(v - bf2f(h));
}

// GRU weight pack: Wpk[jt][kc][r][32] with r = g*64 + jj; weight row g*256+jt*64+jj,
// k = kc*32 + kk; k<64 from wih, else whh. hi/lo split.
__global__ __launch_bounds__(256)
void pack_w_gru(const float* __restrict__ wih, const float* __restrict__ whh,
                ushort_t* __restrict__ hi, ushort_t* __restrict__ lo){
  int idx = blockIdx.x * 256 + threadIdx.x;
  if (idx >= 4 * 10 * 192 * 32) return;
  int kk = idx & 31;
  int r  = (idx >> 5) % 192;
  int kc = (idx >> 5) / 192 % 10;
  int jt = idx / (32 * 192 * 10);
  int g = r >> 6, jj = r & 63;
  int wrow = g * 256 + jt * 64 + jj;
  int k = kc * 32 + kk;
  float v = (k < 64) ? wih[wrow * 64 + k] : whh[wrow * 256 + (k - 64)];
  ushort_t h = f2bf(v);
  hi[idx] = h; lo[idx] = f2bf(v - bf2f(h));
}

// ------------- barrier-free bf16x3 GEMM (GAT path, weights tiny/L2-hot) ----

__global__ __launch_bounds__(256)
void gemm_nolds(const ushort_t* __restrict__ Ah, const ushort_t* __restrict__ Al,
                const ushort_t* __restrict__ Bh, const ushort_t* __restrict__ Bl,
                float* __restrict__ C, int M, int K, int N){
  int tid = threadIdx.x;
  int w = tid >> 6, lane = tid & 63;
  int m16 = lane & 15, quad = lane >> 4;
  int n0 = (blockIdx.y * 4 + w) * 64;
  if (n0 >= N) return;
  int m0 = blockIdx.x * 32;

  f32x4 acc[2][4];
#pragma unroll
  for (int i = 0; i < 2; i++)
#pragma unroll
    for (int j = 0; j < 4; j++) acc[i][j] = (f32x4){0,0,0,0};

  int ar0 = m0 + m16;      if (ar0 >= M) ar0 = M - 1;
  int ar1 = m0 + 16 + m16; if (ar1 >= M) ar1 = M - 1;
  const ushort_t* Ah0 = Ah + (size_t)ar0 * K + quad * 8;
  const ushort_t* Al0 = Al + (size_t)ar0 * K + quad * 8;
  const ushort_t* Ah1 = Ah + (size_t)ar1 * K + quad * 8;
  const ushort_t* Al1 = Al + (size_t)ar1 * K + quad * 8;

  for (int k0 = 0; k0 < K; k0 += 32){
    short8 a_h[2], a_l[2];
    a_h[0] = *(const short8*)(Ah0 + k0); a_l[0] = *(const short8*)(Al0 + k0);
    a_h[1] = *(const short8*)(Ah1 + k0); a_l[1] = *(const short8*)(Al1 + k0);
#pragma unroll
    for (int nt = 0; nt < 4; nt++){
      size_t boff = (size_t)(n0 + nt * 16 + m16) * K + k0 + quad * 8;
      short8 b_h = *(const short8*)(Bh + boff);
      short8 b_l = *(const short8*)(Bl + boff);
#pragma unroll
      for (int mt = 0; mt < 2; mt++){
        acc[mt][nt] = __builtin_amdgcn_mfma_f32_16x16x32_bf16(a_h[mt], b_h, acc[mt][nt],0,0,0);
        acc[mt][nt] = __builtin_amdgcn_mfma_f32_16x16x32_bf16(a_h[mt], b_l, acc[mt][nt],0,0,0);
        acc[mt][nt] = __builtin_amdgcn_mfma_f32_16x16x32_bf16(a_l[mt], b_h, acc[mt][nt],0,0,0);
      }
    }
  }
#pragma unroll
  for (int mt = 0; mt < 2; mt++){
    int row = m0 + mt * 16 + quad * 4;
#pragma unroll
    for (int nt = 0; nt < 4; nt++){
      int cc = n0 + nt * 16 + m16;
#pragma unroll
      for (int r4 = 0; r4 < 4; r4++){
        if (row + r4 < M) C[(size_t)(row + r4) * N + cc] = acc[mt][nt][r4];
      }
    }
  }
}

// ------------- LDS-staged fused GRU step, both directions (r2 body) --------
// Block: 128 nodes x 64 GRU cols (x 3 gates); 4 waves in 2x2; K chunks of 32.
// Double-buffered: issue next-chunk DMAs before computing the current chunk.
// LDS linear (global_load_lds requires dest = base + lane*16); bank conflicts
// fixed by an involutive XOR on the 16B-chunk index applied to BOTH the DMA
// source and the fragment read (rule #21): chunk' = chunk ^ ((chunk>>3)&7).
// first=1 (s==0): h_in == 0 exactly -> skip all Hin staging/compute, hold=0.
// This replaces the 4 x ~94us hbuf memset fills seen in r1/r2 profiles.

struct GruArgs {
  const ushort_t *EtH[2], *EtL[2];     // [N][64]
  const ushort_t *WpH[2], *WpL[2];     // packed [4][10][192][32]
  const float    *BIH[2], *BHH[2];
  const ushort_t *HinH[2],*HinL[2];    // [N][256]
  ushort_t *HoutH[2], *HoutL[2];
  int first;
};

#define GRU_STAGE(BB, AH, AL, ASTRIDE, ACOL, KC)                               \
  {                                                                            \
    _Pragma("unroll")                                                          \
    for (int pass = 0; pass < 2; pass++){                                      \
      int ch = pass * 256 + tid;          /* 0..511 : 128 rows x 4 chunks */   \
      int lch = ch ^ ((ch >> 3) & 7);     /* swizzled logical chunk */         \
      int row = lch >> 2, c = (lch & 3) * 8;                                   \
      int anode = m0 + row; if (anode >= N_NODES) anode = N_NODES - 1;         \
      async_cp16(AH + (size_t)anode * ASTRIDE + (ACOL) + c, &Ah_s[BB][ch * 8]);\
      async_cp16(AL + (size_t)anode * ASTRIDE + (ACOL) + c, &Al_s[BB][ch * 8]);\
    }                                                                          \
    const ushort_t* bh = WpH + ((size_t)jt * 10 + (KC)) * 6144;                \
    const ushort_t* bl = WpL + ((size_t)jt * 10 + (KC)) * 6144;                \
    _Pragma("unroll")                                                          \
    for (int pass = 0; pass < 3; pass++){                                      \
      int ch = pass * 256 + tid;          /* 0..767 : 192 rows x 4 chunks */   \
      int lch = ch ^ ((ch >> 3) & 7);                                          \
      async_cp16(bh + lch * 8, &Bh_s[BB][ch * 8]);                             \
      async_cp16(bl + lch * 8, &Bl_s[BB][ch * 8]);                             \
    }                                                                          \
  }

#define GRU_COMPUTE(BB, NTGT)                                                  \
  {                                                                            \
    short8 a_h[4], a_l[4];                                                     \
    _Pragma("unroll")                                                          \
    for (int mt = 0; mt < 4; mt++){                                            \
      int r = wm * 64 + mt * 16 + m16;                                         \
      int so = ((r * 4 + quad) ^ ((r >> 1) & 7)) * 8;                          \
      a_h[mt] = *(const short8*)&Ah_s[BB][so];                                 \
      a_l[mt] = *(const short8*)&Al_s[BB][so];                                 \
    }                                                                          \
    _Pragma("unroll")                                                          \
    for (int g = 0; g < 3; g++){                                               \
      int tgt = (g < 2) ? g : (NTGT);                                          \
      _Pragma("unroll")                                                        \
      for (int nt = 0; nt < 2; nt++){                                          \
        int r = g * 64 + wn * 32 + nt * 16 + m16;                              \
        int so = ((r * 4 + quad) ^ ((r >> 1) & 7)) * 8;                        \
        short8 b_h = *(const short8*)&Bh_s[BB][so];                            \
        short8 b_l = *(const short8*)&Bl_s[BB][so];                            \
        _Pragma("unroll")                                                      \
        for (int mt = 0; mt < 4; mt++){                                        \
          acc[tgt][mt][nt] = __builtin_amdgcn_mfma_f32_16x16x32_bf16(a_h[mt], b_h, acc[tgt][mt][nt],0,0,0); \
          acc[tgt][mt][nt] = __builtin_amdgcn_mfma_f32_16x16x32_bf16(a_h[mt], b_l, acc[tgt][mt][nt],0,0,0); \
          acc[tgt][mt][nt] = __builtin_amdgcn_mfma_f32_16x16x32_bf16(a_l[mt], b_h, acc[tgt][mt][nt],0,0,0); \
        }                                                                      \
      }                                                                        \
    }                                                                          \
  }

__global__ __launch_bounds__(256, 2)
void gru_step(GruArgs ga){
  int dir = blockIdx.z;
  const ushort_t* EtH  = ga.EtH[dir];  const ushort_t* EtL  = ga.EtL[dir];
  const ushort_t* WpH  = ga.WpH[dir];  const ushort_t* WpL  = ga.WpL[dir];
  const float*    BIH  = ga.BIH[dir];  const float*    BHH  = ga.BHH[dir];
  const ushort_t* HinH = ga.HinH[dir]; const ushort_t* HinL = ga.HinL[dir];
  ushort_t* HoutH = ga.HoutH[dir];     ushort_t* HoutL = ga.HoutL[dir];

  __shared__ __align__(16) short Ah_s[2][128 * 32];
  __shared__ __align__(16) short Al_s[2][128 * 32];
  __shared__ __align__(16) short Bh_s[2][192 * 32];
  __shared__ __align__(16) short Bl_s[2][192 * 32];

  int tid = threadIdx.x;
  int w = tid >> 6, lane = tid & 63;
  int wm = w >> 1, wn = w & 1;
  int m16 = lane & 15, quad = lane >> 4;
  int m0 = blockIdx.x * 128;
  int jt = blockIdx.y;               // j-tile of 64
  int j0 = jt * 64;

  f32x4 acc[4][4][2];                // [r,z,n_in,n_hid][mt][nt]
#pragma unroll
  for (int g = 0; g < 4; g++)
#pragma unroll
    for (int i = 0; i < 4; i++)
#pragma unroll
      for (int j = 0; j < 2; j++) acc[g][i][j] = (f32x4){0,0,0,0};

  // prologue: stage kc=0 (Et cols 0..31) into buf 0
  GRU_STAGE(0, EtH, EtL, 64, 0, 0)
  __syncthreads();
  // kc=0: stage kc=1 (Et cols 32..63) -> buf1; compute buf0, n-gate -> acc[2]
  GRU_STAGE(1, EtH, EtL, 64, 32, 1)
  GRU_COMPUTE(0, 2)
  __syncthreads();
  if (!ga.first){
    // kc=1: stage kc=2 (Hin cols 0..31) -> buf0; compute buf1 -> acc[2]
    GRU_STAGE(0, HinH, HinL, 256, 0, 2)
    GRU_COMPUTE(1, 2)
    __syncthreads();
    // kc=2..8: stage kc+1 -> buf (kc+1)&1; compute buf kc&1 -> acc[3]
    for (int kc = 2; kc < 9; kc++){
      GRU_STAGE((kc + 1) & 1, HinH, HinL, 256, (kc - 1) * 32, kc + 1)
      GRU_COMPUTE(kc & 1, 3)
      __syncthreads();
    }
    GRU_COMPUTE(1, 3)
  } else {
    // s == 0: h_in == 0; only the Et chunks contribute
    GRU_COMPUTE(1, 2)
  }

#pragma unroll
  for (int mt = 0; mt < 4; mt++){
    int row = m0 + wm * 64 + mt * 16 + quad * 4;
#pragma unroll
    for (int nt = 0; nt < 2; nt++){
      int j = j0 + wn * 32 + nt * 16 + m16;
      float br  = BIH[j] + BHH[j];
      float bz  = BIH[GRU_H + j] + BHH[GRU_H + j];
      float bni = BIH[2*GRU_H + j];
      float bnh = BHH[2*GRU_H + j];
#pragma unroll
      for (int r4 = 0; r4 < 4; r4++){
        int node = row + r4;
        if (node < N_NODES){
          float rr = 1.f / (1.f + __expf(-(acc[0][mt][nt][r4] + br)));
          float zz = 1.f / (1.f + __expf(-(acc[1][mt][nt][r4] + bz)));
          float nn = tanhf(acc[2][mt][nt][r4] + bni + rr * (acc[3][mt][nt][r4] + bnh));
          size_t hidx = (size_t)node * GRU_H + j;
          float hold = ga.first ? 0.f : (bf2f(HinH[hidx]) + bf2f(HinL[hidx]));
          float hv = (1.f - zz) * nn + zz * hold;
          ushort_t hh = f2bf(hv);
          HoutH[hidx] = hh;
          HoutL[hidx] = f2bf(hv - bf2f(hh));
        }
      }
    }
  }
}

// ---------------- fused GAT layer 1 ----------------
// 1 wave = 1 node; edges processed in pairs so two xl-row gathers are in
// flight simultaneously.

__device__ __forceinline__ void gat1_half(float4 xl, float4 xr,
                                          float a0, float a1, float a2,
                                          float4 we0, float4 we1, float4 we2,
                                          float4 at, bool valid,
                                          float& den, float4& acc){
  float vx = xl.x + xr.x + a0*we0.x + a1*we1.x + a2*we2.x;
  float vy = xl.y + xr.y + a0*we0.y + a1*we1.y + a2*we2.y;
  float vz = xl.z + xr.z + a0*we0.z + a1*we1.z + a2*we2.z;
  float vw = xl.w + xr.w + a0*we0.w + a1*we1.w + a2*we2.w;
  vx = fmaxf(vx, 0.2f*vx); vy = fmaxf(vy, 0.2f*vy);
  vz = fmaxf(vz, 0.2f*vz); vw = fmaxf(vw, 0.2f*vw);
  float pm = vx*at.x + vy*at.y + vz*at.z + vw*at.w;
  pm += __shfl_xor(pm, 1, 64); pm += __shfl_xor(pm, 2, 64);
  pm += __shfl_xor(pm, 4, 64); pm += __shfl_xor(pm, 8, 64);
  float wgt = valid ? __expf(pm) : 0.f;
  den += wgt;
  acc.x += wgt * xl.x; acc.y += wgt * xl.y;
  acc.z += wgt * xl.z; acc.w += wgt * xl.w;
}

__global__ __launch_bounds__(256)
void gat1_fused(const float* __restrict__ xlr, const float4* __restrict__ emeta,
                const int* __restrict__ row_ptr, const int* __restrict__ col,
                const float* __restrict__ we, const float* __restrict__ att,
                const float* __restrict__ bias,
                ushort_t* __restrict__ outh, ushort_t* __restrict__ outl){
  int n = (blockIdx.x * 256 + threadIdx.x) >> 6;
  int lane = threadIdx.x & 63;
  if (n >= N_NODES) return;
  int ch0 = lane * 4;
  int ch1 = 256 + lane * 4;

  float4 att0 = *(const float4*)&att[ch0];
  float4 att1 = *(const float4*)&att[ch1];
  float4 we00 = *(const float4*)&we[ch0],        we01 = *(const float4*)&we[ch1];
  float4 we10 = *(const float4*)&we[512 + ch0],  we11 = *(const float4*)&we[512 + ch1];
  float4 we20 = *(const float4*)&we[1024 + ch0], we21 = *(const float4*)&we[1024 + ch1];
  const float* xrow_n = xlr + (size_t)n * 1024;
  float4 xr0 = *(const float4*)&xrow_n[512 + ch0];
  float4 xr1 = *(const float4*)&xrow_n[512 + ch1];

  float den0 = 0.f, den1 = 0.f;
  float4 acc0 = make_float4(0,0,0,0), acc1 = make_float4(0,0,0,0);
  int beg = row_ptr[n], end = row_ptr[n + 1];

  for (int p = beg - 1; p < end; p += 2){
    int c0 = (p >= beg) ? col[p] : (E_EDGES + n);   // p==beg-1 -> self loop
    bool v1 = (p + 1 < end);
    int c1 = v1 ? col[p + 1] : c0;
    float4 mt0 = emeta[c0];
    float4 mt1 = emeta[c1];
    const float* xp0 = xlr + (size_t)__float_as_int(mt0.w) * 1024;
    const float* xp1 = xlr + (size_t)__float_as_int(mt1.w) * 1024;
    float4 xa0 = *(const float4*)&xp0[ch0];
    float4 xa1 = *(const float4*)&xp0[ch1];
    float4 xb0 = *(const float4*)&xp1[ch0];
    float4 xb1 = *(const float4*)&xp1[ch1];
    gat1_half(xa0, xr0, mt0.x, mt0.y, mt0.z, we00, we10, we20, att0, true, den0, acc0);
    gat1_half(xa1, xr1, mt0.x, mt0.y, mt0.z, we01, we11, we21, att1, true, den1, acc1);
    gat1_half(xb0, xr0, mt1.x, mt1.y, mt1.z, we00, we10, we20, att0, v1, den0, acc0);
    gat1_half(xb1, xr1, mt1.x, mt1.y, mt1.z, we01, we11, we21, att1, v1, den1, acc1);
  }

  float4 b0 = *(const float4*)&bias[ch0];
  float4 b1 = *(const float4*)&bias[ch1];
  float id0 = 1.f / den0, id1 = 1.f / den1;
  float o[8];
  o[0] = acc0.x*id0 + b0.x; o[1] = acc0.y*id0 + b0.y;
  o[2] = acc0.z*id0 + b0.z; o[3] = acc0.w*id0 + b0.w;
  o[4] = acc1.x*id1 + b1.x; o[5] = acc1.y*id1 + b1.y;
  o[6] = acc1.z*id1 + b1.z; o[7] = acc1.w*id1 + b1.w;
  ushort4 h0, h1v, l0, l1v;
  ushort_t* hp0 = (ushort_t*)&h0; ushort_t* hp1 = (ushort_t*)&h1v;
  ushort_t* lp0 = (ushort_t*)&l0; ushort_t* lp1 = (ushort_t*)&l1v;
#pragma unroll
  for (int i = 0; i < 8; i++){
    float v = o[i];
    v = v > 0.f ? v : (__expf(v) - 1.f);
    ushort_t hh = f2bf(v);
    ushort_t ll = f2bf(v - bf2f(hh));
    if (i < 4){ hp0[i] = hh; lp0[i] = ll; } else { hp1[i-4] = hh; lp1[i-4] = ll; }
  }
  *(ushort4*)&outh[(size_t)n * 512 + ch0] = h0;
  *(ushort4*)&outh[(size_t)n * 512 + ch1] = h1v;
  *(ushort4*)&outl[(size_t)n * 512 + ch0] = l0;
  *(ushort4*)&outl[(size_t)n * 512 + ch1] = l1v;
}

// ---------------- fused GAT layer 2 ----------------

__global__ __launch_bounds__(256)
void gat2_fused(const float* __restrict__ xlr, const float4* __restrict__ emeta,
                const int* __restrict__ row_ptr, const int* __restrict__ col,
                const float* __restrict__ we, const float* __restrict__ att,
                const float* __restrict__ bias,
                ushort_t* __restrict__ outh, ushort_t* __restrict__ outl){
  int n = (blockIdx.x * 256 + threadIdx.x) >> 6;
  int lane = threadIdx.x & 63;
  if (n >= N_NODES) return;
  int g = lane >> 4;
  int c4 = (lane & 15) * 4;

  float4 attq = *(const float4*)&att[c4];
  float4 we0q = *(const float4*)&we[c4];
  float4 we1q = *(const float4*)&we[64 + c4];
  float4 we2q = *(const float4*)&we[128 + c4];
  float4 xr4  = *(const float4*)&xlr[(size_t)n * 128 + 64 + c4];

  float den = 0.f;
  float4 acc = make_float4(0,0,0,0);
  int beg = row_ptr[n], end = row_ptr[n + 1];

  for (int p0 = beg - 1; p0 < end; p0 += 4){
    int pp = p0 + g;
    bool valid = pp < end;
    int s = n; float a0 = 0.f, a1 = 0.f, a2 = 0.f;
    if (valid){
      float4 mt = (pp < beg) ? emeta[E_EDGES + n] : emeta[col[pp]];
      a0 = mt.x; a1 = mt.y; a2 = mt.z; s = __float_as_int(mt.w);
    }
    float4 xl4 = *(const float4*)&xlr[(size_t)s * 128 + c4];
    float vx = xl4.x + xr4.x + a0*we0q.x + a1*we1q.x + a2*we2q.x;
    float vy = xl4.y + xr4.y + a0*we0q.y + a1*we1q.y + a2*we2q.y;
    float vz = xl4.z + xr4.z + a0*we0q.z + a1*we1q.z + a2*we2q.z;
    float vw = xl4.w + xr4.w + a0*we0q.w + a1*we1q.w + a2*we2q.w;
    vx = fmaxf(vx, 0.2f*vx); vy = fmaxf(vy, 0.2f*vy);
    vz = fmaxf(vz, 0.2f*vz); vw = fmaxf(vw, 0.2f*vw);
    float pm = vx*attq.x + vy*attq.y + vz*attq.z + vw*attq.w;
    pm += __shfl_xor(pm, 1, 64); pm += __shfl_xor(pm, 2, 64);
    pm += __shfl_xor(pm, 4, 64); pm += __shfl_xor(pm, 8, 64);
    float wgt = valid ? __expf(pm) : 0.f;
    den += wgt;
    acc.x += wgt * xl4.x; acc.y += wgt * xl4.y;
    acc.z += wgt * xl4.z; acc.w += wgt * xl4.w;
  }
#pragma unroll
  for (int off = 16; off <= 32; off <<= 1){
    den   += __shfl_xor(den, off, 64);
    acc.x += __shfl_xor(acc.x, off, 64);
    acc.y += __shfl_xor(acc.y, off, 64);
    acc.z += __shfl_xor(acc.z, off, 64);
    acc.w += __shfl_xor(acc.w, off, 64);
  }
  if (g == 0){
    float4 bq = *(const float4*)&bias[c4];
    float id = 1.f / den;
    float o[4];
    o[0] = acc.x*id + bq.x; o[1] = acc.y*id + bq.y;
    o[2] = acc.z*id + bq.z; o[3] = acc.w*id + bq.w;
    ushort4 hv, lv;
    ushort_t* hp = (ushort_t*)&hv; ushort_t* lp = (ushort_t*)&lv;
#pragma unroll
    for (int i = 0; i < 4; i++){
      float v = o[i];
      v = v > 0.f ? v : (__expf(v) - 1.f);
      ushort_t hh = f2bf(v);
      hp[i] = hh; lp[i] = f2bf(v - bf2f(hh));
    }
    *(ushort4*)&outh[(size_t)n * 64 + c4] = hv;
    *(ushort4*)&outl[(size_t)n * 64 + c4] = lv;
  }
}

// ---------------- tail ----------------

__global__ __launch_bounds__(256)
void mean_kernel(const ushort_t* __restrict__ hfh, const ushort_t* __restrict__ hfl,
                 const ushort_t* __restrict__ hbh, const ushort_t* __restrict__ hbl,
                 float* __restrict__ g){
  int k = threadIdx.x;
  int n0 = blockIdx.x * 50;
  int n1 = n0 + 50; if (n1 > N_NODES) n1 = N_NODES;
  float sf = 0.f, sb = 0.f;
  for (int n = n0; n < n1; n++){
    size_t i = (size_t)n * GRU_H + k;
    sf += bf2f(hfh[i]) + bf2f(hfl[i]);
    sb += bf2f(hbh[i]) + bf2f(hbl[i]);
  }
  atomicAdd(&g[k], sf);
  atomicAdd(&g[GRU_H + k], sb);
}

__global__ __launch_bounds__(64)
void fc_kernel(const float* __restrict__ g, const float* __restrict__ W,
               const float* __restrict__ b, float* __restrict__ out){
  int j = blockIdx.x;
  int lane = threadIdx.x;
  float s = 0.f;
  for (int k = lane; k < 2 * GRU_H; k += 64) s += g[k] * W[j * (2 * GRU_H) + k];
  s = wave_reduce_sum(s);
  if (lane == 0) out[j] = b[j] + s * (1.0f / N_NODES);
}

// ---------------- launch ----------------

extern "C" void kernel_launch(void* const* d_in, const int* in_sizes, int n_in,
                              void* d_out, int out_size, void* d_ws, size_t ws_size,
                              hipStream_t stream){
  const float* x     = (const float*)d_in[0];
  const float* eattr = (const float*)d_in[1];
  const int*   esrc  = (const int*)  d_in[2];
  const int*   edst  = (const int*)  d_in[3];
  const float* g1_wl = (const float*)d_in[4];
  const float* g1_wr = (const float*)d_in[5];
  const float* g1_we = (const float*)d_in[6];
  const float* g1_att= (const float*)d_in[7];
  const float* g1_b  = (const float*)d_in[8];
  const float* g2_wl = (const float*)d_in[9];
  const float* g2_wr = (const float*)d_in[10];
  const float* g2_we = (const float*)d_in[11];
  const float* g2_att= (const float*)d_in[12];
  const float* g2_b  = (const float*)d_in[13];
  const float* wih_f = (const float*)d_in[14];
  const float* whh_f = (const float*)d_in[15];
  const float* bih_f = (const float*)d_in[16];
  const float* bhh_f = (const float*)d_in[17];
  const float* wih_b = (const float*)d_in[18];
  const float* whh_b = (const float*)d_in[19];
  const float* bih_b = (const float*)d_in[20];
  const float* bhh_b = (const float*)d_in[21];
  const float* fc_w  = (const float*)d_in[22];
  const float* fc_b  = (const float*)d_in[23];
  float* out = (float*)d_out;

  float* ws = (float*)d_ws;
  size_t o = 0;
  auto alloc = [&](size_t nfloats) -> float* {
    float* p = ws + o; o += (nfloats + 3) & ~(size_t)3; return p;
  };
  const size_t XTOT = (size_t)T_SEQ * N_NODES * IN_CH;
  ushort_t* xh   = (ushort_t*)alloc(XTOT / 2);
  ushort_t* xlo  = (ushort_t*)alloc(XTOT / 2);
  float* xlr1    = alloc((size_t)N_NODES * 1024);
  ushort_t* h1h  = (ushort_t*)alloc((size_t)N_NODES * 512 / 2 + 4);
  ushort_t* h1l  = (ushort_t*)alloc((size_t)N_NODES * 512 / 2 + 4);
  const size_t ETOT = (size_t)T_SEQ * N_NODES * HID;
  ushort_t* embh = (ushort_t*)alloc(ETOT / 2);
  ushort_t* embl = (ushort_t*)alloc(ETOT / 2);
  const size_t HTOT = (size_t)N_NODES * GRU_H;
  ushort_t* hbuf[8];
  for (int i = 0; i < 8; i++) hbuf[i] = (ushort_t*)alloc(HTOT / 2 + 4);
  float* lsum  = alloc((size_t)N_NODES * 3);
  float* lattr = alloc((size_t)N_NODES * 3);
  float* gmean = alloc(512);
  float4* emeta = (float4*)alloc((size_t)EF * 4);
  ushort_t* W1h = (ushort_t*)alloc(1024*128/2);
  ushort_t* W1l = (ushort_t*)alloc(1024*128/2);
  ushort_t* W2h = (ushort_t*)alloc(128*512/2);
  ushort_t* W2l = (ushort_t*)alloc(128*512/2);
  const size_t WPK = 4 * 10 * 192 * 32;     // 245760 shorts
  ushort_t* WpFh = (ushort_t*)alloc(WPK/2);
  ushort_t* WpFl = (ushort_t*)alloc(WPK/2);
  ushort_t* WpBh = (ushort_t*)alloc(WPK/2);
  ushort_t* WpBl = (ushort_t*)alloc(WPK/2);
  int* deg     = (int*)alloc(N_NODES + 4);
  int* row_ptr = (int*)alloc(N_NODES + 4);
  int* cursor  = (int*)alloc(N_NODES + 4);
  int* col     = (int*)alloc(E_EDGES + 4);
  float* xlr2 = xlr1;

  hipMemsetAsync(deg,    0, N_NODES * sizeof(int), stream);
  hipMemsetAsync(cursor, 0, N_NODES * sizeof(int), stream);
  hipMemsetAsync(lsum,   0, (size_t)N_NODES * 3 * sizeof(float), stream);
  hipMemsetAsync(gmean,  0, 512 * sizeof(float), stream);
  // no hbuf memsets — gru_step first=1 handles h0 == 0 exactly

  deg_loop_kernel<<<(E_EDGES + 255)/256, 256, 0, stream>>>(edst, eattr, deg, lsum);
  loop_div_kernel<<<(N_NODES + 255)/256, 256, 0, stream>>>(deg, lsum, lattr);
  scan_rowptr_kernel<<<1, 256, 0, stream>>>(deg, row_ptr);
  csr_fill_kernel<<<(E_EDGES + 255)/256, 256, 0, stream>>>(edst, row_ptr, cursor, col);
  build_emeta<<<(EF + 255)/256, 256, 0, stream>>>(eattr, lattr, esrc, emeta);
  split_arr4<<<(int)(XTOT / 4 / 256), 256, 0, stream>>>(
      (const float4*)x, (ushort4*)xh, (ushort4*)xlo, (long)(XTOT / 4));
  split_w_gat1<<<(1024*128 + 255)/256, 256, 0, stream>>>(g1_wl, g1_wr, W1h, W1l);
  split_w_gat2<<<(128*512 + 255)/256, 256, 0, stream>>>(g2_wl, g2_wr, W2h, W2l);
  pack_w_gru<<<(int)((WPK + 255)/256), 256, 0, stream>>>(wih_f, whh_f, WpFh, WpFl);
  pack_w_gru<<<(int)((WPK + 255)/256), 256, 0, stream>>>(wih_b, whh_b, WpBh, WpBl);

  const int MB32  = (N_NODES + 31) / 32;    // 313
  const int MB128 = (N_NODES + 127) / 128;  // 79
  const int NODE_BLOCKS = (N_NODES + 3) / 4;
  for (int t = 0; t < T_SEQ; t++){
    const ushort_t* xth = xh  + (size_t)t * N_NODES * IN_CH;
    const ushort_t* xtl = xlo + (size_t)t * N_NODES * IN_CH;
    gemm_nolds<<<dim3(MB32, 4), 256, 0, stream>>>(xth, xtl, W1h, W1l, xlr1,
                                                  N_NODES, IN_CH, 1024);
    gat1_fused<<<NODE_BLOCKS, 256, 0, stream>>>(
        xlr1, emeta, row_ptr, col, g1_we, g1_att, g1_b, h1h, h1l);
    // N=128 -> only 2 waves needed; 128-thread blocks avoid dead waves
    gemm_nolds<<<dim3(MB32, 1), 128, 0, stream>>>(h1h, h1l, W2h, W2l, xlr2,
                                                  N_NODES, HC, 128);
    gat2_fused<<<NODE_BLOCKS, 256, 0, stream>>>(
        xlr2, emeta, row_ptr, col, g2_we, g2_att, g2_b,
        embh + (size_t)t * N_NODES * HID, embl + (size_t)t * N_NODES * HID);
  }

  // GRU: both directions per launch; fwd ping-pong hbuf[0,1]<->[2,3], bwd [4,5]<->[6,7]
  {
    int fin = 0, bin = 4;
    for (int s = 0; s < T_SEQ; s++){
      int fo = fin ^ 2, bo = bin ^ 2;
      GruArgs ga;
      ga.EtH[0] = embh + (size_t)s * N_NODES * HID;
      ga.EtL[0] = embl + (size_t)s * N_NODES * HID;
      ga.EtH[1] = embh + (size_t)(T_SEQ - 1 - s) * N_NODES * HID;
      ga.EtL[1] = embl + (size_t)(T_SEQ - 1 - s) * N_NODES * HID;
      ga.WpH[0] = WpFh; ga.WpL[0] = WpFl; ga.WpH[1] = WpBh; ga.WpL[1] = WpBl;
      ga.BIH[0] = bih_f; ga.BHH[0] = bhh_f; ga.BIH[1] = bih_b; ga.BHH[1] = bhh_b;
      ga.HinH[0] = hbuf[fin];   ga.HinL[0] = hbuf[fin+1];
      ga.HinH[1] = hbuf[bin];   ga.HinL[1] = hbuf[bin+1];
      ga.HoutH[0] = hbuf[fo];   ga.HoutL[0] = hbuf[fo+1];
      ga.HoutH[1] = hbuf[bo];   ga.HoutL[1] = hbuf[bo+1];
      ga.first = (s == 0) ? 1 : 0;
      gru_step<<<dim3(MB128, 4, 2), 256, 0, stream>>>(ga);
      fin = fo; bin = bo;
    }
  }

  mean_kernel<<<(N_NODES + 49)/50, 256, 0, stream>>>(hbuf[0], hbuf[1], hbuf[4], hbuf[5], gmean);
  fc_kernel<<<33, 64, 0, stream>>>(gmean, fc_w, fc_b, out);
}

// Round 8
// 7431.441 us; speedup vs baseline: 4.3929x; 1.0796x over previous
//
#include <hip/hip_runtime.h>

#define T_SEQ   32
#define N_NODES 10000
#define E_EDGES 160000
#define EF      (E_EDGES + N_NODES)
#define IN_CH   128
#define HID     64
#define HEADS   8
#define HC      512
#define GRU_H   256
#define G3      768

typedef __attribute__((ext_vector_type(8))) short short8;
typedef __attribute__((ext_vector_type(4))) float f32x4;
typedef unsigned short ushort_t;

__device__ __forceinline__ float wave_reduce_sum(float v){
#pragma unroll
  for (int off = 32; off; off >>= 1) v += __shfl_xor(v, off, 64);
  return v;
}

__device__ __forceinline__ ushort_t f2bf(float v){
  unsigned u = __float_as_uint(v);
  unsigned r = u + 0x7FFFu + ((u >> 16) & 1u);
  return (ushort_t)(r >> 16);
}
__device__ __forceinline__ float bf2f(ushort_t b){
  return __uint_as_float(((unsigned)b) << 16);
}

// 16B global -> LDS DMA (gfx950). LDS dest must be wave-uniform base + lane*16.
__device__ __forceinline__ void async_cp16(const void* g, void* l){
  __builtin_amdgcn_global_load_lds((const __attribute__((address_space(1))) void*)g,
                                   (__attribute__((address_space(3))) void*)l, 16, 0, 0);
}

// ---------------- graph setup ----------------

__global__ __launch_bounds__(256)
void deg_loop_kernel(const int* __restrict__ edst, const float* __restrict__ eattr,
                     int* __restrict__ deg, float* __restrict__ lsum){
  int e = blockIdx.x * 256 + threadIdx.x;
  if (e < E_EDGES){
    int d = edst[e];
    atomicAdd(&deg[d], 1);
    atomicAdd(&lsum[d*3+0], eattr[e*3+0]);
    atomicAdd(&lsum[d*3+1], eattr[e*3+1]);
    atomicAdd(&lsum[d*3+2], eattr[e*3+2]);
  }
}

__global__ __launch_bounds__(256)
void loop_div_kernel(const int* __restrict__ deg, const float* __restrict__ lsum,
                     float* __restrict__ lattr){
  int n = blockIdx.x * 256 + threadIdx.x;
  if (n < N_NODES){
    float d = fmaxf((float)deg[n], 1.0f);
    lattr[n*3+0] = lsum[n*3+0] / d;
    lattr[n*3+1] = lsum[n*3+1] / d;
    lattr[n*3+2] = lsum[n*3+2] / d;
  }
}

__global__ __launch_bounds__(256)
void scan_rowptr_kernel(const int* __restrict__ deg, int* __restrict__ row_ptr){
  __shared__ int sums[256];
  __shared__ int base[256];
  int tid = threadIdx.x;
  const int CH = 40;
  int start = tid * CH;
  int s = 0;
  for (int k = 0; k < CH; k++){
    int n = start + k;
    if (n < N_NODES) s += deg[n];
  }
  sums[tid] = s;
  __syncthreads();
  if (tid == 0){
    int acc = 0;
    for (int i = 0; i < 256; i++){ base[i] = acc; acc += sums[i]; }
  }
  __syncthreads();
  int acc = base[tid];
  for (int k = 0; k < CH; k++){
    int n = start + k;
    if (n < N_NODES){ row_ptr[n] = acc; acc += deg[n]; }
    else if (n == N_NODES){ row_ptr[n] = acc; }
  }
}

__global__ __launch_bounds__(256)
void csr_fill_kernel(const int* __restrict__ edst, const int* __restrict__ row_ptr,
                     int* __restrict__ cursor, int* __restrict__ col){
  int e = blockIdx.x * 256 + threadIdx.x;
  if (e < E_EDGES){
    int d = edst[e];
    int pos = row_ptr[d] + atomicAdd(&cursor[d], 1);
    col[pos] = e;
  }
}

__global__ __launch_bounds__(256)
void build_emeta(const float* __restrict__ eattr, const float* __restrict__ lattr,
                 const int* __restrict__ esrc, float4* __restrict__ emeta){
  int e = blockIdx.x * 256 + threadIdx.x;
  if (e < E_EDGES){
    emeta[e] = make_float4(eattr[e*3], eattr[e*3+1], eattr[e*3+2], __int_as_float(esrc[e]));
  } else if (e < EF){
    int n = e - E_EDGES;
    emeta[e] = make_float4(lattr[n*3], lattr[n*3+1], lattr[n*3+2], __int_as_float(n));
  }
}

// ---------------- pre-split kernels ----------------

// vectorized: 4 floats / thread (G13)
__global__ __launch_bounds__(256)
void split_arr4(const float4* __restrict__ src, ushort4* __restrict__ hi,
                ushort4* __restrict__ lo, long n4){
  long idx = (long)blockIdx.x * 256 + threadIdx.x;
  if (idx < n4){
    float4 v = src[idx];
    float vv[4] = {v.x, v.y, v.z, v.w};
    ushort4 h, l;
    ushort_t* hp = (ushort_t*)&h; ushort_t* lp = (ushort_t*)&l;
#pragma unroll
    for (int i = 0; i < 4; i++){
      ushort_t hh = f2bf(vv[i]);
      hp[i] = hh; lp[i] = f2bf(vv[i] - bf2f(hh));
    }
    hi[idx] = h; lo[idx] = l;
  }
}

__global__ __launch_bounds__(256)
void split_w_gat1(const float* __restrict__ wl, const float* __restrict__ wr,
                  ushort_t* __restrict__ hi, ushort_t* __restrict__ lo){
  int idx = blockIdx.x * 256 + threadIdx.x;
  if (idx >= 1024 * 128) return;
  int n = idx >> 7, k = idx & 127;
  float v = (n < 512) ? wl[k * 512 + n] : wr[k * 512 + (n - 512)];
  ushort_t h = f2bf(v);
  hi[idx] = h; lo[idx] = f2bf(v - bf2f(h));
}

__global__ __launch_bounds__(256)
void split_w_gat2(const float* __restrict__ wl, const float* __restrict__ wr,
                  ushort_t* __restrict__ hi, ushort_t* __restrict__ lo){
  int idx = blockIdx.x * 256 + threadIdx.x;
  if (idx >= 128 * 512) return;
  int n = idx >> 9, k = idx & 511;
  float v = (n < 64) ? wl[k * 64 + n] : wr[k * 64 + (n - 64)];
  ushort_t h = f2bf(v);
  hi[idx] = h; lo[idx] = f2bf(v - bf2f(h));
}

// GRU weight pack: Wpk[jt][kc][r][32] with r = g*64 + jj; weight row g*256+jt*64+jj,
// k = kc*32 + kk; k<64 from wih, else whh. hi/lo split.
__global__ __launch_bounds__(256)
void pack_w_gru(const float* __restrict__ wih, const float* __restrict__ whh,
                ushort_t* __restrict__ hi, ushort_t* __restrict__ lo){
  int idx = blockIdx.x * 256 + threadIdx.x;
  if (idx >= 4 * 10 * 192 * 32) return;
  int kk = idx & 31;
  int r  = (idx >> 5) % 192;
  int kc = (idx >> 5) / 192 % 10;
  int jt = idx / (32 * 192 * 10);
  int g = r >> 6, jj = r & 63;
  int wrow = g * 256 + jt * 64 + jj;
  int k = kc * 32 + kk;
  float v = (k < 64) ? wih[wrow * 64 + k] : whh[wrow * 256 + (k - 64)];
  ushort_t h = f2bf(v);
  hi[idx] = h; lo[idx] = f2bf(v - bf2f(h));
}

// ------------- barrier-free bf16x3 GEMM (GAT path, weights tiny/L2-hot) ----

__global__ __launch_bounds__(256)
void gemm_nolds(const ushort_t* __restrict__ Ah, const ushort_t* __restrict__ Al,
                const ushort_t* __restrict__ Bh, const ushort_t* __restrict__ Bl,
                float* __restrict__ C, int M, int K, int N){
  int tid = threadIdx.x;
  int w = tid >> 6, lane = tid & 63;
  int m16 = lane & 15, quad = lane >> 4;
  int n0 = (blockIdx.y * 4 + w) * 64;
  if (n0 >= N) return;
  int m0 = blockIdx.x * 32;

  f32x4 acc[2][4];
#pragma unroll
  for (int i = 0; i < 2; i++)
#pragma unroll
    for (int j = 0; j < 4; j++) acc[i][j] = (f32x4){0,0,0,0};

  int ar0 = m0 + m16;      if (ar0 >= M) ar0 = M - 1;
  int ar1 = m0 + 16 + m16; if (ar1 >= M) ar1 = M - 1;
  const ushort_t* Ah0 = Ah + (size_t)ar0 * K + quad * 8;
  const ushort_t* Al0 = Al + (size_t)ar0 * K + quad * 8;
  const ushort_t* Ah1 = Ah + (size_t)ar1 * K + quad * 8;
  const ushort_t* Al1 = Al + (size_t)ar1 * K + quad * 8;

  for (int k0 = 0; k0 < K; k0 += 32){
    short8 a_h[2], a_l[2];
    a_h[0] = *(const short8*)(Ah0 + k0); a_l[0] = *(const short8*)(Al0 + k0);
    a_h[1] = *(const short8*)(Ah1 + k0); a_l[1] = *(const short8*)(Al1 + k0);
#pragma unroll
    for (int nt = 0; nt < 4; nt++){
      size_t boff = (size_t)(n0 + nt * 16 + m16) * K + k0 + quad * 8;
      short8 b_h = *(const short8*)(Bh + boff);
      short8 b_l = *(const short8*)(Bl + boff);
#pragma unroll
      for (int mt = 0; mt < 2; mt++){
        acc[mt][nt] = __builtin_amdgcn_mfma_f32_16x16x32_bf16(a_h[mt], b_h, acc[mt][nt],0,0,0);
        acc[mt][nt] = __builtin_amdgcn_mfma_f32_16x16x32_bf16(a_h[mt], b_l, acc[mt][nt],0,0,0);
        acc[mt][nt] = __builtin_amdgcn_mfma_f32_16x16x32_bf16(a_l[mt], b_h, acc[mt][nt],0,0,0);
      }
    }
  }
#pragma unroll
  for (int mt = 0; mt < 2; mt++){
    int row = m0 + mt * 16 + quad * 4;
#pragma unroll
    for (int nt = 0; nt < 4; nt++){
      int cc = n0 + nt * 16 + m16;
#pragma unroll
      for (int r4 = 0; r4 < 4; r4++){
        if (row + r4 < M) C[(size_t)(row + r4) * N + cc] = acc[mt][nt][r4];
      }
    }
  }
}

// gemm1 with XCD-chunked swizzle (T1): 1252 blocks 1D. The 4 nb-blocks sharing
// one 32-row A-panel are adjacent in work index -> same XCD chunk -> A fetched
// from HBM once per panel instead of 4x (r7 PMC: concurrent cross-XCD misses
// don't combine). Bijective r=4 variant (1252 % 8 == 4).
__global__ __launch_bounds__(256)
void gemm1_swz(const ushort_t* __restrict__ Ah, const ushort_t* __restrict__ Al,
               const ushort_t* __restrict__ Bh, const ushort_t* __restrict__ Bl,
               float* __restrict__ C){
  const int M = N_NODES, K = IN_CH, N = 1024;
  int bid = blockIdx.x;
  int xcd = bid & 7, lk = bid >> 3;
  int wsw = (xcd < 4 ? xcd * 157 : 628 + (xcd - 4) * 156) + lk;
  int mb = wsw >> 2, nbq = wsw & 3;

  int tid = threadIdx.x;
  int w = tid >> 6, lane = tid & 63;
  int m16 = lane & 15, quad = lane >> 4;
  int n0 = (nbq * 4 + w) * 64;
  int m0 = mb * 32;

  f32x4 acc[2][4];
#pragma unroll
  for (int i = 0; i < 2; i++)
#pragma unroll
    for (int j = 0; j < 4; j++) acc[i][j] = (f32x4){0,0,0,0};

  int ar0 = m0 + m16;      if (ar0 >= M) ar0 = M - 1;
  int ar1 = m0 + 16 + m16; if (ar1 >= M) ar1 = M - 1;
  const ushort_t* Ah0 = Ah + (size_t)ar0 * K + quad * 8;
  const ushort_t* Al0 = Al + (size_t)ar0 * K + quad * 8;
  const ushort_t* Ah1 = Ah + (size_t)ar1 * K + quad * 8;
  const ushort_t* Al1 = Al + (size_t)ar1 * K + quad * 8;

  for (int k0 = 0; k0 < K; k0 += 32){
    short8 a_h[2], a_l[2];
    a_h[0] = *(const short8*)(Ah0 + k0); a_l[0] = *(const short8*)(Al0 + k0);
    a_h[1] = *(const short8*)(Ah1 + k0); a_l[1] = *(const short8*)(Al1 + k0);
#pragma unroll
    for (int nt = 0; nt < 4; nt++){
      size_t boff = (size_t)(n0 + nt * 16 + m16) * K + k0 + quad * 8;
      short8 b_h = *(const short8*)(Bh + boff);
      short8 b_l = *(const short8*)(Bl + boff);
#pragma unroll
      for (int mt = 0; mt < 2; mt++){
        acc[mt][nt] = __builtin_amdgcn_mfma_f32_16x16x32_bf16(a_h[mt], b_h, acc[mt][nt],0,0,0);
        acc[mt][nt] = __builtin_amdgcn_mfma_f32_16x16x32_bf16(a_h[mt], b_l, acc[mt][nt],0,0,0);
        acc[mt][nt] = __builtin_amdgcn_mfma_f32_16x16x32_bf16(a_l[mt], b_h, acc[mt][nt],0,0,0);
      }
    }
  }
#pragma unroll
  for (int mt = 0; mt < 2; mt++){
    int row = m0 + mt * 16 + quad * 4;
#pragma unroll
    for (int nt = 0; nt < 4; nt++){
      int cc = n0 + nt * 16 + m16;
#pragma unroll
      for (int r4 = 0; r4 < 4; r4++){
        if (row + r4 < M) C[(size_t)(row + r4) * N + cc] = acc[mt][nt][r4];
      }
    }
  }
}

// ------------- LDS-staged fused GRU step, both directions ------------------
// r2 body + first-flag. NEW (r8): 1D grid of 632 with XCD-chunked swizzle so
// all 8 blocks (4 jt x 2 dir) of one 128-node tile land on the SAME XCD ->
// Et/Hin fetched from HBM once per tile, 7 L2 hits (r7 PMC: FETCH was ~4x
// algorithmic because the 4 jt blocks ran concurrently on 4 different XCDs
// and their in-flight misses don't combine). 632 % 8 == 0 -> simple bijection
// w = (bid&7)*79 + (bid>>3); decode m0_tile = w>>3, jt = (w&7)>>1, dir = w&1.

struct GruArgs {
  const ushort_t *EtH[2], *EtL[2];     // [N][64]
  const ushort_t *WpH[2], *WpL[2];     // packed [4][10][192][32]
  const float    *BIH[2], *BHH[2];
  const ushort_t *HinH[2],*HinL[2];    // [N][256]
  ushort_t *HoutH[2], *HoutL[2];
  int first;
};

#define GRU_STAGE(BB, AH, AL, ASTRIDE, ACOL, KC)                               \
  {                                                                            \
    _Pragma("unroll")                                                          \
    for (int pass = 0; pass < 2; pass++){                                      \
      int ch = pass * 256 + tid;          /* 0..511 : 128 rows x 4 chunks */   \
      int lch = ch ^ ((ch >> 3) & 7);     /* swizzled logical chunk */         \
      int row = lch >> 2, c = (lch & 3) * 8;                                   \
      int anode = m0 + row; if (anode >= N_NODES) anode = N_NODES - 1;         \
      async_cp16(AH + (size_t)anode * ASTRIDE + (ACOL) + c, &Ah_s[BB][ch * 8]);\
      async_cp16(AL + (size_t)anode * ASTRIDE + (ACOL) + c, &Al_s[BB][ch * 8]);\
    }                                                                          \
    const ushort_t* bh = WpH + ((size_t)jt * 10 + (KC)) * 6144;                \
    const ushort_t* bl = WpL + ((size_t)jt * 10 + (KC)) * 6144;                \
    _Pragma("unroll")                                                          \
    for (int pass = 0; pass < 3; pass++){                                      \
      int ch = pass * 256 + tid;          /* 0..767 : 192 rows x 4 chunks */   \
      int lch = ch ^ ((ch >> 3) & 7);                                          \
      async_cp16(bh + lch * 8, &Bh_s[BB][ch * 8]);                             \
      async_cp16(bl + lch * 8, &Bl_s[BB][ch * 8]);                             \
    }                                                                          \
  }

#define GRU_COMPUTE(BB, NTGT)                                                  \
  {                                                                            \
    short8 a_h[4], a_l[4];                                                     \
    _Pragma("unroll")                                                          \
    for (int mt = 0; mt < 4; mt++){                                            \
      int r = wm * 64 + mt * 16 + m16;                                         \
      int so = ((r * 4 + quad) ^ ((r >> 1) & 7)) * 8;                          \
      a_h[mt] = *(const short8*)&Ah_s[BB][so];                                 \
      a_l[mt] = *(const short8*)&Al_s[BB][so];                                 \
    }                                                                          \
    _Pragma("unroll")                                                          \
    for (int g = 0; g < 3; g++){                                               \
      int tgt = (g < 2) ? g : (NTGT);                                          \
      _Pragma("unroll")                                                        \
      for (int nt = 0; nt < 2; nt++){                                          \
        int r = g * 64 + wn * 32 + nt * 16 + m16;                              \
        int so = ((r * 4 + quad) ^ ((r >> 1) & 7)) * 8;                        \
        short8 b_h = *(const short8*)&Bh_s[BB][so];                            \
        short8 b_l = *(const short8*)&Bl_s[BB][so];                            \
        _Pragma("unroll")                                                      \
        for (int mt = 0; mt < 4; mt++){                                        \
          acc[tgt][mt][nt] = __builtin_amdgcn_mfma_f32_16x16x32_bf16(a_h[mt], b_h, acc[tgt][mt][nt],0,0,0); \
          acc[tgt][mt][nt] = __builtin_amdgcn_mfma_f32_16x16x32_bf16(a_h[mt], b_l, acc[tgt][mt][nt],0,0,0); \
          acc[tgt][mt][nt] = __builtin_amdgcn_mfma_f32_16x16x32_bf16(a_l[mt], b_h, acc[tgt][mt][nt],0,0,0); \
        }                                                                      \
      }                                                                        \
    }                                                                          \
  }

__global__ __launch_bounds__(256, 2)
void gru_step(GruArgs ga){
  int bid = blockIdx.x;
  int wsw = (bid & 7) * 79 + (bid >> 3);
  int m0 = (wsw >> 3) * 128;
  int sub = wsw & 7;
  int jt = sub >> 1;                 // j-tile of 64
  int dir = sub & 1;

  const ushort_t* EtH  = ga.EtH[dir];  const ushort_t* EtL  = ga.EtL[dir];
  const ushort_t* WpH  = ga.WpH[dir];  const ushort_t* WpL  = ga.WpL[dir];
  const float*    BIH  = ga.BIH[dir];  const float*    BHH  = ga.BHH[dir];
  const ushort_t* HinH = ga.HinH[dir]; const ushort_t* HinL = ga.HinL[dir];
  ushort_t* HoutH = ga.HoutH[dir];     ushort_t* HoutL = ga.HoutL[dir];

  __shared__ __align__(16) short Ah_s[2][128 * 32];
  __shared__ __align__(16) short Al_s[2][128 * 32];
  __shared__ __align__(16) short Bh_s[2][192 * 32];
  __shared__ __align__(16) short Bl_s[2][192 * 32];

  int tid = threadIdx.x;
  int w = tid >> 6, lane = tid & 63;
  int wm = w >> 1, wn = w & 1;
  int m16 = lane & 15, quad = lane >> 4;
  int j0 = jt * 64;

  f32x4 acc[4][4][2];                // [r,z,n_in,n_hid][mt][nt]
#pragma unroll
  for (int g = 0; g < 4; g++)
#pragma unroll
    for (int i = 0; i < 4; i++)
#pragma unroll
      for (int j = 0; j < 2; j++) acc[g][i][j] = (f32x4){0,0,0,0};

  // prologue: stage kc=0 (Et cols 0..31) into buf 0
  GRU_STAGE(0, EtH, EtL, 64, 0, 0)
  __syncthreads();
  // kc=0: stage kc=1 (Et cols 32..63) -> buf1; compute buf0, n-gate -> acc[2]
  GRU_STAGE(1, EtH, EtL, 64, 32, 1)
  GRU_COMPUTE(0, 2)
  __syncthreads();
  if (!ga.first){
    // kc=1: stage kc=2 (Hin cols 0..31) -> buf0; compute buf1 -> acc[2]
    GRU_STAGE(0, HinH, HinL, 256, 0, 2)
    GRU_COMPUTE(1, 2)
    __syncthreads();
    // kc=2..8: stage kc+1 -> buf (kc+1)&1; compute buf kc&1 -> acc[3]
    for (int kc = 2; kc < 9; kc++){
      GRU_STAGE((kc + 1) & 1, HinH, HinL, 256, (kc - 1) * 32, kc + 1)
      GRU_COMPUTE(kc & 1, 3)
      __syncthreads();
    }
    GRU_COMPUTE(1, 3)
  } else {
    // s == 0: h_in == 0; only the Et chunks contribute
    GRU_COMPUTE(1, 2)
  }

#pragma unroll
  for (int mt = 0; mt < 4; mt++){
    int row = m0 + wm * 64 + mt * 16 + quad * 4;
#pragma unroll
    for (int nt = 0; nt < 2; nt++){
      int j = j0 + wn * 32 + nt * 16 + m16;
      float br  = BIH[j] + BHH[j];
      float bz  = BIH[GRU_H + j] + BHH[GRU_H + j];
      float bni = BIH[2*GRU_H + j];
      float bnh = BHH[2*GRU_H + j];
#pragma unroll
      for (int r4 = 0; r4 < 4; r4++){
        int node = row + r4;
        if (node < N_NODES){
          float rr = 1.f / (1.f + __expf(-(acc[0][mt][nt][r4] + br)));
          float zz = 1.f / (1.f + __expf(-(acc[1][mt][nt][r4] + bz)));
          float nn = tanhf(acc[2][mt][nt][r4] + bni + rr * (acc[3][mt][nt][r4] + bnh));
          size_t hidx = (size_t)node * GRU_H + j;
          float hold = ga.first ? 0.f : (bf2f(HinH[hidx]) + bf2f(HinL[hidx]));
          float hv = (1.f - zz) * nn + zz * hold;
          ushort_t hh = f2bf(hv);
          HoutH[hidx] = hh;
          HoutL[hidx] = f2bf(hv - bf2f(hh));
        }
      }
    }
  }
}

// ---------------- fused GAT layer 1 ----------------
// 1 wave = 1 node; edges processed in pairs so two xl-row gathers are in
// flight simultaneously.

__device__ __forceinline__ void gat1_half(float4 xl, float4 xr,
                                          float a0, float a1, float a2,
                                          float4 we0, float4 we1, float4 we2,
                                          float4 at, bool valid,
                                          float& den, float4& acc){
  float vx = xl.x + xr.x + a0*we0.x + a1*we1.x + a2*we2.x;
  float vy = xl.y + xr.y + a0*we0.y + a1*we1.y + a2*we2.y;
  float vz = xl.z + xr.z + a0*we0.z + a1*we1.z + a2*we2.z;
  float vw = xl.w + xr.w + a0*we0.w + a1*we1.w + a2*we2.w;
  vx = fmaxf(vx, 0.2f*vx); vy = fmaxf(vy, 0.2f*vy);
  vz = fmaxf(vz, 0.2f*vz); vw = fmaxf(vw, 0.2f*vw);
  float pm = vx*at.x + vy*at.y + vz*at.z + vw*at.w;
  pm += __shfl_xor(pm, 1, 64); pm += __shfl_xor(pm, 2, 64);
  pm += __shfl_xor(pm, 4, 64); pm += __shfl_xor(pm, 8, 64);
  float wgt = valid ? __expf(pm) : 0.f;
  den += wgt;
  acc.x += wgt * xl.x; acc.y += wgt * xl.y;
  acc.z += wgt * xl.z; acc.w += wgt * xl.w;
}

__global__ __launch_bounds__(256)
void gat1_fused(const float* __restrict__ xlr, const float4* __restrict__ emeta,
                const int* __restrict__ row_ptr, const int* __restrict__ col,
                const float* __restrict__ we, const float* __restrict__ att,
                const float* __restrict__ bias,
                ushort_t* __restrict__ outh, ushort_t* __restrict__ outl){
  int n = (blockIdx.x * 256 + threadIdx.x) >> 6;
  int lane = threadIdx.x & 63;
  if (n >= N_NODES) return;
  int ch0 = lane * 4;
  int ch1 = 256 + lane * 4;

  float4 att0 = *(const float4*)&att[ch0];
  float4 att1 = *(const float4*)&att[ch1];
  float4 we00 = *(const float4*)&we[ch0],        we01 = *(const float4*)&we[ch1];
  float4 we10 = *(const float4*)&we[512 + ch0],  we11 = *(const float4*)&we[512 + ch1];
  float4 we20 = *(const float4*)&we[1024 + ch0], we21 = *(const float4*)&we[1024 + ch1];
  const float* xrow_n = xlr + (size_t)n * 1024;
  float4 xr0 = *(const float4*)&xrow_n[512 + ch0];
  float4 xr1 = *(const float4*)&xrow_n[512 + ch1];

  float den0 = 0.f, den1 = 0.f;
  float4 acc0 = make_float4(0,0,0,0), acc1 = make_float4(0,0,0,0);
  int beg = row_ptr[n], end = row_ptr[n + 1];

  for (int p = beg - 1; p < end; p += 2){
    int c0 = (p >= beg) ? col[p] : (E_EDGES + n);   // p==beg-1 -> self loop
    bool v1 = (p + 1 < end);
    int c1 = v1 ? col[p + 1] : c0;
    float4 mt0 = emeta[c0];
    float4 mt1 = emeta[c1];
    const float* xp0 = xlr + (size_t)__float_as_int(mt0.w) * 1024;
    const float* xp1 = xlr + (size_t)__float_as_int(mt1.w) * 1024;
    float4 xa0 = *(const float4*)&xp0[ch0];
    float4 xa1 = *(const float4*)&xp0[ch1];
    float4 xb0 = *(const float4*)&xp1[ch0];
    float4 xb1 = *(const float4*)&xp1[ch1];
    gat1_half(xa0, xr0, mt0.x, mt0.y, mt0.z, we00, we10, we20, att0, true, den0, acc0);
    gat1_half(xa1, xr1, mt0.x, mt0.y, mt0.z, we01, we11, we21, att1, true, den1, acc1);
    gat1_half(xb0, xr0, mt1.x, mt1.y, mt1.z, we00, we10, we20, att0, v1, den0, acc0);
    gat1_half(xb1, xr1, mt1.x, mt1.y, mt1.z, we01, we11, we21, att1, v1, den1, acc1);
  }

  float4 b0 = *(const float4*)&bias[ch0];
  float4 b1 = *(const float4*)&bias[ch1];
  float id0 = 1.f / den0, id1 = 1.f / den1;
  float o[8];
  o[0] = acc0.x*id0 + b0.x; o[1] = acc0.y*id0 + b0.y;
  o[2] = acc0.z*id0 + b0.z; o[3] = acc0.w*id0 + b0.w;
  o[4] = acc1.x*id1 + b1.x; o[5] = acc1.y*id1 + b1.y;
  o[6] = acc1.z*id1 + b1.z; o[7] = acc1.w*id1 + b1.w;
  ushort4 h0, h1v, l0, l1v;
  ushort_t* hp0 = (ushort_t*)&h0; ushort_t* hp1 = (ushort_t*)&h1v;
  ushort_t* lp0 = (ushort_t*)&l0; ushort_t* lp1 = (ushort_t*)&l1v;
#pragma unroll
  for (int i = 0; i < 8; i++){
    float v = o[i];
    v = v > 0.f ? v : (__expf(v) - 1.f);
    ushort_t hh = f2bf(v);
    ushort_t ll = f2bf(v - bf2f(hh));
    if (i < 4){ hp0[i] = hh; lp0[i] = ll; } else { hp1[i-4] = hh; lp1[i-4] = ll; }
  }
  *(ushort4*)&outh[(size_t)n * 512 + ch0] = h0;
  *(ushort4*)&outh[(size_t)n * 512 + ch1] = h1v;
  *(ushort4*)&outl[(size_t)n * 512 + ch0] = l0;
  *(ushort4*)&outl[(size_t)n * 512 + ch1] = l1v;
}

// ---------------- fused GAT layer 2 ----------------

__global__ __launch_bounds__(256)
void gat2_fused(const float* __restrict__ xlr, const float4* __restrict__ emeta,
                const int* __restrict__ row_ptr, const int* __restrict__ col,
                const float* __restrict__ we, const float* __restrict__ att,
                const float* __restrict__ bias,
                ushort_t* __restrict__ outh, ushort_t* __restrict__ outl){
  int n = (blockIdx.x * 256 + threadIdx.x) >> 6;
  int lane = threadIdx.x & 63;
  if (n >= N_NODES) return;
  int g = lane >> 4;
  int c4 = (lane & 15) * 4;

  float4 attq = *(const float4*)&att[c4];
  float4 we0q = *(const float4*)&we[c4];
  float4 we1q = *(const float4*)&we[64 + c4];
  float4 we2q = *(const float4*)&we[128 + c4];
  float4 xr4  = *(const float4*)&xlr[(size_t)n * 128 + 64 + c4];

  float den = 0.f;
  float4 acc = make_float4(0,0,0,0);
  int beg = row_ptr[n], end = row_ptr[n + 1];

  for (int p0 = beg - 1; p0 < end; p0 += 4){
    int pp = p0 + g;
    bool valid = pp < end;
    int s = n; float a0 = 0.f, a1 = 0.f, a2 = 0.f;
    if (valid){
      float4 mt = (pp < beg) ? emeta[E_EDGES + n] : emeta[col[pp]];
      a0 = mt.x; a1 = mt.y; a2 = mt.z; s = __float_as_int(mt.w);
    }
    float4 xl4 = *(const float4*)&xlr[(size_t)s * 128 + c4];
    float vx = xl4.x + xr4.x + a0*we0q.x + a1*we1q.x + a2*we2q.x;
    float vy = xl4.y + xr4.y + a0*we0q.y + a1*we1q.y + a2*we2q.y;
    float vz = xl4.z + xr4.z + a0*we0q.z + a1*we1q.z + a2*we2q.z;
    float vw = xl4.w + xr4.w + a0*we0q.w + a1*we1q.w + a2*we2q.w;
    vx = fmaxf(vx, 0.2f*vx); vy = fmaxf(vy, 0.2f*vy);
    vz = fmaxf(vz, 0.2f*vz); vw = fmaxf(vw, 0.2f*vw);
    float pm = vx*attq.x + vy*attq.y + vz*attq.z + vw*attq.w;
    pm += __shfl_xor(pm, 1, 64); pm += __shfl_xor(pm, 2, 64);
    pm += __shfl_xor(pm, 4, 64); pm += __shfl_xor(pm, 8, 64);
    float wgt = valid ? __expf(pm) : 0.f;
    den += wgt;
    acc.x += wgt * xl4.x; acc.y += wgt * xl4.y;
    acc.z += wgt * xl4.z; acc.w += wgt * xl4.w;
  }
#pragma unroll
  for (int off = 16; off <= 32; off <<= 1){
    den   += __shfl_xor(den, off, 64);
    acc.x += __shfl_xor(acc.x, off, 64);
    acc.y += __shfl_xor(acc.y, off, 64);
    acc.z += __shfl_xor(acc.z, off, 64);
    acc.w += __shfl_xor(acc.w, off, 64);
  }
  if (g == 0){
    float4 bq = *(const float4*)&bias[c4];
    float id = 1.f / den;
    float o[4];
    o[0] = acc.x*id + bq.x; o[1] = acc.y*id + bq.y;
    o[2] = acc.z*id + bq.z; o[3] = acc.w*id + bq.w;
    ushort4 hv, lv;
    ushort_t* hp = (ushort_t*)&hv; ushort_t* lp = (ushort_t*)&lv;
#pragma unroll
    for (int i = 0; i < 4; i++){
      float v = o[i];
      v = v > 0.f ? v : (__expf(v) - 1.f);
      ushort_t hh = f2bf(v);
      hp[i] = hh; lp[i] = f2bf(v - bf2f(hh));
    }
    *(ushort4*)&outh[(size_t)n * 64 + c4] = hv;
    *(ushort4*)&outl[(size_t)n * 64 + c4] = lv;
  }
}

// ---------------- tail ----------------

__global__ __launch_bounds__(256)
void mean_kernel(const ushort_t* __restrict__ hfh, const ushort_t* __restrict__ hfl,
                 const ushort_t* __restrict__ hbh, const ushort_t* __restrict__ hbl,
                 float* __restrict__ g){
  int k = threadIdx.x;
  int n0 = blockIdx.x * 50;
  int n1 = n0 + 50; if (n1 > N_NODES) n1 = N_NODES;
  float sf = 0.f, sb = 0.f;
  for (int n = n0; n < n1; n++){
    size_t i = (size_t)n * GRU_H + k;
    sf += bf2f(hfh[i]) + bf2f(hfl[i]);
    sb += bf2f(hbh[i]) + bf2f(hbl[i]);
  }
  atomicAdd(&g[k], sf);
  atomicAdd(&g[GRU_H + k], sb);
}

__global__ __launch_bounds__(64)
void fc_kernel(const float* __restrict__ g, const float* __restrict__ W,
               const float* __restrict__ b, float* __restrict__ out){
  int j = blockIdx.x;
  int lane = threadIdx.x;
  float s = 0.f;
  for (int k = lane; k < 2 * GRU_H; k += 64) s += g[k] * W[j * (2 * GRU_H) + k];
  s = wave_reduce_sum(s);
  if (lane == 0) out[j] = b[j] + s * (1.0f / N_NODES);
}

// ---------------- launch ----------------

extern "C" void kernel_launch(void* const* d_in, const int* in_sizes, int n_in,
                              void* d_out, int out_size, void* d_ws, size_t ws_size,
                              hipStream_t stream){
  const float* x     = (const float*)d_in[0];
  const float* eattr = (const float*)d_in[1];
  const int*   esrc  = (const int*)  d_in[2];
  const int*   edst  = (const int*)  d_in[3];
  const float* g1_wl = (const float*)d_in[4];
  const float* g1_wr = (const float*)d_in[5];
  const float* g1_we = (const float*)d_in[6];
  const float* g1_att= (const float*)d_in[7];
  const float* g1_b  = (const float*)d_in[8];
  const float* g2_wl = (const float*)d_in[9];
  const float* g2_wr = (const float*)d_in[10];
  const float* g2_we = (const float*)d_in[11];
  const float* g2_att= (const float*)d_in[12];
  const float* g2_b  = (const float*)d_in[13];
  const float* wih_f = (const float*)d_in[14];
  const float* whh_f = (const float*)d_in[15];
  const float* bih_f = (const float*)d_in[16];
  const float* bhh_f = (const float*)d_in[17];
  const float* wih_b = (const float*)d_in[18];
  const float* whh_b = (const float*)d_in[19];
  const float* bih_b = (const float*)d_in[20];
  const float* bhh_b = (const float*)d_in[21];
  const float* fc_w  = (const float*)d_in[22];
  const float* fc_b  = (const float*)d_in[23];
  float* out = (float*)d_out;

  float* ws = (float*)d_ws;
  size_t o = 0;
  auto alloc = [&](size_t nfloats) -> float* {
    float* p = ws + o; o += (nfloats + 3) & ~(size_t)3; return p;
  };
  const size_t XTOT = (size_t)T_SEQ * N_NODES * IN_CH;
  ushort_t* xh   = (ushort_t*)alloc(XTOT / 2);
  ushort_t* xlo  = (ushort_t*)alloc(XTOT / 2);
  float* xlr1    = alloc((size_t)N_NODES * 1024);
  ushort_t* h1h  = (ushort_t*)alloc((size_t)N_NODES * 512 / 2 + 4);
  ushort_t* h1l  = (ushort_t*)alloc((size_t)N_NODES * 512 / 2 + 4);
  const size_t ETOT = (size_t)T_SEQ * N_NODES * HID;
  ushort_t* embh = (ushort_t*)alloc(ETOT / 2);
  ushort_t* embl = (ushort_t*)alloc(ETOT / 2);
  const size_t HTOT = (size_t)N_NODES * GRU_H;
  ushort_t* hbuf[8];
  for (int i = 0; i < 8; i++) hbuf[i] = (ushort_t*)alloc(HTOT / 2 + 4);
  float* lsum  = alloc((size_t)N_NODES * 3);
  float* lattr = alloc((size_t)N_NODES * 3);
  float* gmean = alloc(512);
  float4* emeta = (float4*)alloc((size_t)EF * 4);
  ushort_t* W1h = (ushort_t*)alloc(1024*128/2);
  ushort_t* W1l = (ushort_t*)alloc(1024*128/2);
  ushort_t* W2h = (ushort_t*)alloc(128*512/2);
  ushort_t* W2l = (ushort_t*)alloc(128*512/2);
  const size_t WPK = 4 * 10 * 192 * 32;     // 245760 shorts
  ushort_t* WpFh = (ushort_t*)alloc(WPK/2);
  ushort_t* WpFl = (ushort_t*)alloc(WPK/2);
  ushort_t* WpBh = (ushort_t*)alloc(WPK/2);
  ushort_t* WpBl = (ushort_t*)alloc(WPK/2);
  int* deg     = (int*)alloc(N_NODES + 4);
  int* row_ptr = (int*)alloc(N_NODES + 4);
  int* cursor  = (int*)alloc(N_NODES + 4);
  int* col     = (int*)alloc(E_EDGES + 4);
  float* xlr2 = xlr1;

  hipMemsetAsync(deg,    0, N_NODES * sizeof(int), stream);
  hipMemsetAsync(cursor, 0, N_NODES * sizeof(int), stream);
  hipMemsetAsync(lsum,   0, (size_t)N_NODES * 3 * sizeof(float), stream);
  hipMemsetAsync(gmean,  0, 512 * sizeof(float), stream);
  // no hbuf memsets — gru_step first=1 handles h0 == 0 exactly

  deg_loop_kernel<<<(E_EDGES + 255)/256, 256, 0, stream>>>(edst, eattr, deg, lsum);
  loop_div_kernel<<<(N_NODES + 255)/256, 256, 0, stream>>>(deg, lsum, lattr);
  scan_rowptr_kernel<<<1, 256, 0, stream>>>(deg, row_ptr);
  csr_fill_kernel<<<(E_EDGES + 255)/256, 256, 0, stream>>>(edst, row_ptr, cursor, col);
  build_emeta<<<(EF + 255)/256, 256, 0, stream>>>(eattr, lattr, esrc, emeta);
  split_arr4<<<(int)(XTOT / 4 / 256), 256, 0, stream>>>(
      (const float4*)x, (ushort4*)xh, (ushort4*)xlo, (long)(XTOT / 4));
  split_w_gat1<<<(1024*128 + 255)/256, 256, 0, stream>>>(g1_wl, g1_wr, W1h, W1l);
  split_w_gat2<<<(128*512 + 255)/256, 256, 0, stream>>>(g2_wl, g2_wr, W2h, W2l);
  pack_w_gru<<<(int)((WPK + 255)/256), 256, 0, stream>>>(wih_f, whh_f, WpFh, WpFl);
  pack_w_gru<<<(int)((WPK + 255)/256), 256, 0, stream>>>(wih_b, whh_b, WpBh, WpBl);

  const int MB32  = (N_NODES + 31) / 32;    // 313
  const int NODE_BLOCKS = (N_NODES + 3) / 4;
  for (int t = 0; t < T_SEQ; t++){
    const ushort_t* xth = xh  + (size_t)t * N_NODES * IN_CH;
    const ushort_t* xtl = xlo + (size_t)t * N_NODES * IN_CH;
    gemm1_swz<<<1252, 256, 0, stream>>>(xth, xtl, W1h, W1l, xlr1);
    gat1_fused<<<NODE_BLOCKS, 256, 0, stream>>>(
        xlr1, emeta, row_ptr, col, g1_we, g1_att, g1_b, h1h, h1l);
    // N=128 -> only 2 waves needed; 128-thread blocks avoid dead waves
    gemm_nolds<<<dim3(MB32, 1), 128, 0, stream>>>(h1h, h1l, W2h, W2l, xlr2,
                                                  N_NODES, HC, 128);
    gat2_fused<<<NODE_BLOCKS, 256, 0, stream>>>(
        xlr2, emeta, row_ptr, col, g2_we, g2_att, g2_b,
        embh + (size_t)t * N_NODES * HID, embl + (size_t)t * N_NODES * HID);
  }

  // GRU: both directions per launch; fwd ping-pong hbuf[0,1]<->[2,3], bwd [4,5]<->[6,7]
  {
    int fin = 0, bin = 4;
    for (int s = 0; s < T_SEQ; s++){
      int fo = fin ^ 2, bo = bin ^ 2;
      GruArgs ga;
      ga.EtH[0] = embh + (size_t)s * N_NODES * HID;
      ga.EtL[0] = embl + (size_t)s * N_NODES * HID;
      ga.EtH[1] = embh + (size_t)(T_SEQ - 1 - s) * N_NODES * HID;
      ga.EtL[1] = embl + (size_t)(T_SEQ - 1 - s) * N_NODES * HID;
      ga.WpH[0] = WpFh; ga.WpL[0] = WpFl; ga.WpH[1] = WpBh; ga.WpL[1] = WpBl;
      ga.BIH[0] = bih_f; ga.BHH[0] = bhh_f; ga.BIH[1] = bih_b; ga.BHH[1] = bhh_b;
      ga.HinH[0] = hbuf[fin];   ga.HinL[0] = hbuf[fin+1];
      ga.HinH[1] = hbuf[bin];   ga.HinL[1] = hbuf[bin+1];
      ga.HoutH[0] = hbuf[fo];   ga.HoutL[0] = hbuf[fo+1];
      ga.HoutH[1] = hbuf[bo];   ga.HoutL[1] = hbuf[bo+1];
      ga.first = (s == 0) ? 1 : 0;
      gru_step<<<632, 256, 0, stream>>>(ga);
      fin = fo; bin = bo;
    }
  }

  mean_kernel<<<(N_NODES + 49)/50, 256, 0, stream>>>(hbuf[0], hbuf[1], hbuf[4], hbuf[5], gmean);
  fc_kernel<<<33, 64, 0, stream>>>(gmean, fc_w, fc_b, out);
}

// Round 9
// 6294.581 us; speedup vs baseline: 5.1863x; 1.1806x over previous
//
#include <hip/hip_runtime.h>

#define T_SEQ   32
#define N_NODES 10000
#define E_EDGES 160000
#define EF      (E_EDGES + N_NODES)
#define IN_CH   128
#define HID     64
#define HEADS   8
#define HC      512
#define GRU_H   256
#define G3      768

typedef __attribute__((ext_vector_type(8))) short short8;
typedef __attribute__((ext_vector_type(4))) float f32x4;
typedef unsigned short ushort_t;

__device__ __forceinline__ float wave_reduce_sum(float v){
#pragma unroll
  for (int off = 32; off; off >>= 1) v += __shfl_xor(v, off, 64);
  return v;
}

__device__ __forceinline__ ushort_t f2bf(float v){
  unsigned u = __float_as_uint(v);
  unsigned r = u + 0x7FFFu + ((u >> 16) & 1u);
  return (ushort_t)(r >> 16);
}
__device__ __forceinline__ float bf2f(ushort_t b){
  return __uint_as_float(((unsigned)b) << 16);
}

// 16B global -> LDS DMA (gfx950). LDS dest must be wave-uniform base + lane*16.
__device__ __forceinline__ void async_cp16(const void* g, void* l){
  __builtin_amdgcn_global_load_lds((const __attribute__((address_space(1))) void*)g,
                                   (__attribute__((address_space(3))) void*)l, 16, 0, 0);
}

// ---------------- graph setup ----------------

__global__ __launch_bounds__(256)
void deg_loop_kernel(const int* __restrict__ edst, const float* __restrict__ eattr,
                     int* __restrict__ deg, float* __restrict__ lsum){
  int e = blockIdx.x * 256 + threadIdx.x;
  if (e < E_EDGES){
    int d = edst[e];
    atomicAdd(&deg[d], 1);
    atomicAdd(&lsum[d*3+0], eattr[e*3+0]);
    atomicAdd(&lsum[d*3+1], eattr[e*3+1]);
    atomicAdd(&lsum[d*3+2], eattr[e*3+2]);
  }
}

__global__ __launch_bounds__(256)
void loop_div_kernel(const int* __restrict__ deg, const float* __restrict__ lsum,
                     float* __restrict__ lattr){
  int n = blockIdx.x * 256 + threadIdx.x;
  if (n < N_NODES){
    float d = fmaxf((float)deg[n], 1.0f);
    lattr[n*3+0] = lsum[n*3+0] / d;
    lattr[n*3+1] = lsum[n*3+1] / d;
    lattr[n*3+2] = lsum[n*3+2] / d;
  }
}

__global__ __launch_bounds__(256)
void scan_rowptr_kernel(const int* __restrict__ deg, int* __restrict__ row_ptr){
  __shared__ int sums[256];
  __shared__ int base[256];
  int tid = threadIdx.x;
  const int CH = 40;
  int start = tid * CH;
  int s = 0;
  for (int k = 0; k < CH; k++){
    int n = start + k;
    if (n < N_NODES) s += deg[n];
  }
  sums[tid] = s;
  __syncthreads();
  if (tid == 0){
    int acc = 0;
    for (int i = 0; i < 256; i++){ base[i] = acc; acc += sums[i]; }
  }
  __syncthreads();
  int acc = base[tid];
  for (int k = 0; k < CH; k++){
    int n = start + k;
    if (n < N_NODES){ row_ptr[n] = acc; acc += deg[n]; }
    else if (n == N_NODES){ row_ptr[n] = acc; }
  }
}

__global__ __launch_bounds__(256)
void csr_fill_kernel(const int* __restrict__ edst, const int* __restrict__ row_ptr,
                     int* __restrict__ cursor, int* __restrict__ col){
  int e = blockIdx.x * 256 + threadIdx.x;
  if (e < E_EDGES){
    int d = edst[e];
    int pos = row_ptr[d] + atomicAdd(&cursor[d], 1);
    col[pos] = e;
  }
}

__global__ __launch_bounds__(256)
void build_emeta(const float* __restrict__ eattr, const float* __restrict__ lattr,
                 const int* __restrict__ esrc, float4* __restrict__ emeta){
  int e = blockIdx.x * 256 + threadIdx.x;
  if (e < E_EDGES){
    emeta[e] = make_float4(eattr[e*3], eattr[e*3+1], eattr[e*3+2], __int_as_float(esrc[e]));
  } else if (e < EF){
    int n = e - E_EDGES;
    emeta[e] = make_float4(lattr[n*3], lattr[n*3+1], lattr[n*3+2], __int_as_float(n));
  }
}

// ---------------- pre-split kernels ----------------

__global__ __launch_bounds__(256)
void split_arr4(const float4* __restrict__ src, ushort4* __restrict__ hi,
                ushort4* __restrict__ lo, long n4){
  long idx = (long)blockIdx.x * 256 + threadIdx.x;
  if (idx < n4){
    float4 v = src[idx];
    float vv[4] = {v.x, v.y, v.z, v.w};
    ushort4 h, l;
    ushort_t* hp = (ushort_t*)&h; ushort_t* lp = (ushort_t*)&l;
#pragma unroll
    for (int i = 0; i < 4; i++){
      ushort_t hh = f2bf(vv[i]);
      hp[i] = hh; lp[i] = f2bf(vv[i] - bf2f(hh));
    }
    hi[idx] = h; lo[idx] = l;
  }
}

__global__ __launch_bounds__(256)
void split_w_gat1(const float* __restrict__ wl, const float* __restrict__ wr,
                  ushort_t* __restrict__ hi, ushort_t* __restrict__ lo){
  int idx = blockIdx.x * 256 + threadIdx.x;
  if (idx >= 1024 * 128) return;
  int n = idx >> 7, k = idx & 127;
  float v = (n < 512) ? wl[k * 512 + n] : wr[k * 512 + (n - 512)];
  ushort_t h = f2bf(v);
  hi[idx] = h; lo[idx] = f2bf(v - bf2f(h));
}

__global__ __launch_bounds__(256)
void split_w_gat2(const float* __restrict__ wl, const float* __restrict__ wr,
                  ushort_t* __restrict__ hi, ushort_t* __restrict__ lo){
  int idx = blockIdx.x * 256 + threadIdx.x;
  if (idx >= 128 * 512) return;
  int n = idx >> 9, k = idx & 511;
  float v = (n < 64) ? wl[k * 64 + n] : wr[k * 64 + (n - 64)];
  ushort_t h = f2bf(v);
  hi[idx] = h; lo[idx] = f2bf(v - bf2f(h));
}

__global__ __launch_bounds__(256)
void pack_w_gru(const float* __restrict__ wih, const float* __restrict__ whh,
                ushort_t* __restrict__ hi, ushort_t* __restrict__ lo){
  int idx = blockIdx.x * 256 + threadIdx.x;
  if (idx >= 4 * 10 * 192 * 32) return;
  int kk = idx & 31;
  int r  = (idx >> 5) % 192;
  int kc = (idx >> 5) / 192 % 10;
  int jt = idx / (32 * 192 * 10);
  int g = r >> 6, jj = r & 63;
  int wrow = g * 256 + jt * 64 + jj;
  int k = kc * 32 + kk;
  float v = (k < 64) ? wih[wrow * 64 + k] : whh[wrow * 256 + (k - 64)];
  ushort_t h = f2bf(v);
  hi[idx] = h; lo[idx] = f2bf(v - bf2f(h));
}

// ------------- batched bf16x3 GEMM1 (x @ W1), XCD-chunked swizzle ----------
// grid (1252, BT). tl = blockIdx.y selects the time slice. Within a slice the
// 4 nb-blocks of one 32-row A-panel are adjacent in work index -> same XCD.

__global__ __launch_bounds__(256)
void gemm1_swz(const ushort_t* __restrict__ Ah, const ushort_t* __restrict__ Al,
               const ushort_t* __restrict__ Bh, const ushort_t* __restrict__ Bl,
               float* __restrict__ C){
  const int M = N_NODES, K = IN_CH, N = 1024;
  int tl = blockIdx.y;
  const ushort_t* AhT = Ah + (size_t)tl * N_NODES * IN_CH;
  const ushort_t* AlT = Al + (size_t)tl * N_NODES * IN_CH;
  float* CT = C + (size_t)tl * N_NODES * 1024;

  int bid = blockIdx.x;
  int xcd = bid & 7, lk = bid >> 3;
  int wsw = (xcd < 4 ? xcd * 157 : 628 + (xcd - 4) * 156) + lk;
  int mb = wsw >> 2, nbq = wsw & 3;

  int tid = threadIdx.x;
  int w = tid >> 6, lane = tid & 63;
  int m16 = lane & 15, quad = lane >> 4;
  int n0 = (nbq * 4 + w) * 64;
  int m0 = mb * 32;

  f32x4 acc[2][4];
#pragma unroll
  for (int i = 0; i < 2; i++)
#pragma unroll
    for (int j = 0; j < 4; j++) acc[i][j] = (f32x4){0,0,0,0};

  int ar0 = m0 + m16;      if (ar0 >= M) ar0 = M - 1;
  int ar1 = m0 + 16 + m16; if (ar1 >= M) ar1 = M - 1;
  const ushort_t* Ah0 = AhT + (size_t)ar0 * K + quad * 8;
  const ushort_t* Al0 = AlT + (size_t)ar0 * K + quad * 8;
  const ushort_t* Ah1 = AhT + (size_t)ar1 * K + quad * 8;
  const ushort_t* Al1 = AlT + (size_t)ar1 * K + quad * 8;

  for (int k0 = 0; k0 < K; k0 += 32){
    short8 a_h[2], a_l[2];
    a_h[0] = *(const short8*)(Ah0 + k0); a_l[0] = *(const short8*)(Al0 + k0);
    a_h[1] = *(const short8*)(Ah1 + k0); a_l[1] = *(const short8*)(Al1 + k0);
#pragma unroll
    for (int nt = 0; nt < 4; nt++){
      size_t boff = (size_t)(n0 + nt * 16 + m16) * K + k0 + quad * 8;
      short8 b_h = *(const short8*)(Bh + boff);
      short8 b_l = *(const short8*)(Bl + boff);
#pragma unroll
      for (int mt = 0; mt < 2; mt++){
        acc[mt][nt] = __builtin_amdgcn_mfma_f32_16x16x32_bf16(a_h[mt], b_h, acc[mt][nt],0,0,0);
        acc[mt][nt] = __builtin_amdgcn_mfma_f32_16x16x32_bf16(a_h[mt], b_l, acc[mt][nt],0,0,0);
        acc[mt][nt] = __builtin_amdgcn_mfma_f32_16x16x32_bf16(a_l[mt], b_h, acc[mt][nt],0,0,0);
      }
    }
  }
#pragma unroll
  for (int mt = 0; mt < 2; mt++){
    int row = m0 + mt * 16 + quad * 4;
#pragma unroll
    for (int nt = 0; nt < 4; nt++){
      int cc = n0 + nt * 16 + m16;
#pragma unroll
      for (int r4 = 0; r4 < 4; r4++){
        if (row + r4 < M) CT[(size_t)(row + r4) * N + cc] = acc[mt][nt][r4];
      }
    }
  }
}

// ------------- batched GEMM2: h1 @ W2 (K=512, N=128), grid (MB32, BT) ------

__global__ __launch_bounds__(128)
void gemm2_b(const ushort_t* __restrict__ Ah, const ushort_t* __restrict__ Al,
             const ushort_t* __restrict__ Bh, const ushort_t* __restrict__ Bl,
             float* __restrict__ C){
  const int M = N_NODES, K = HC;
  int tl = blockIdx.y;
  const ushort_t* AhT = Ah + (size_t)tl * N_NODES * 512;
  const ushort_t* AlT = Al + (size_t)tl * N_NODES * 512;
  float* CT = C + (size_t)tl * N_NODES * 1024;   // low [N][128] region of slice

  int tid = threadIdx.x;
  int w = tid >> 6, lane = tid & 63;
  int m16 = lane & 15, quad = lane >> 4;
  int n0 = w * 64;
  int m0 = blockIdx.x * 32;

  f32x4 acc[2][4];
#pragma unroll
  for (int i = 0; i < 2; i++)
#pragma unroll
    for (int j = 0; j < 4; j++) acc[i][j] = (f32x4){0,0,0,0};

  int ar0 = m0 + m16;      if (ar0 >= M) ar0 = M - 1;
  int ar1 = m0 + 16 + m16; if (ar1 >= M) ar1 = M - 1;
  const ushort_t* Ah0 = AhT + (size_t)ar0 * K + quad * 8;
  const ushort_t* Al0 = AlT + (size_t)ar0 * K + quad * 8;
  const ushort_t* Ah1 = AhT + (size_t)ar1 * K + quad * 8;
  const ushort_t* Al1 = AlT + (size_t)ar1 * K + quad * 8;

  for (int k0 = 0; k0 < K; k0 += 32){
    short8 a_h[2], a_l[2];
    a_h[0] = *(const short8*)(Ah0 + k0); a_l[0] = *(const short8*)(Al0 + k0);
    a_h[1] = *(const short8*)(Ah1 + k0); a_l[1] = *(const short8*)(Al1 + k0);
#pragma unroll
    for (int nt = 0; nt < 4; nt++){
      size_t boff = (size_t)(n0 + nt * 16 + m16) * K + k0 + quad * 8;
      short8 b_h = *(const short8*)(Bh + boff);
      short8 b_l = *(const short8*)(Bl + boff);
#pragma unroll
      for (int mt = 0; mt < 2; mt++){
        acc[mt][nt] = __builtin_amdgcn_mfma_f32_16x16x32_bf16(a_h[mt], b_h, acc[mt][nt],0,0,0);
        acc[mt][nt] = __builtin_amdgcn_mfma_f32_16x16x32_bf16(a_h[mt], b_l, acc[mt][nt],0,0,0);
        acc[mt][nt] = __builtin_amdgcn_mfma_f32_16x16x32_bf16(a_l[mt], b_h, acc[mt][nt],0,0,0);
      }
    }
  }
#pragma unroll
  for (int mt = 0; mt < 2; mt++){
    int row = m0 + mt * 16 + quad * 4;
#pragma unroll
    for (int nt = 0; nt < 4; nt++){
      int cc = n0 + nt * 16 + m16;
#pragma unroll
      for (int r4 = 0; r4 < 4; r4++){
        if (row + r4 < M) CT[(size_t)(row + r4) * 128 + cc] = acc[mt][nt][r4];
      }
    }
  }
}

// ------------- LDS-staged fused GRU step, both directions (r8 body) --------

struct GruArgs {
  const ushort_t *EtH[2], *EtL[2];     // [N][64]
  const ushort_t *WpH[2], *WpL[2];     // packed [4][10][192][32]
  const float    *BIH[2], *BHH[2];
  const ushort_t *HinH[2],*HinL[2];    // [N][256]
  ushort_t *HoutH[2], *HoutL[2];
  int first;
};

#define GRU_STAGE(BB, AH, AL, ASTRIDE, ACOL, KC)                               \
  {                                                                            \
    _Pragma("unroll")                                                          \
    for (int pass = 0; pass < 2; pass++){                                      \
      int ch = pass * 256 + tid;          /* 0..511 : 128 rows x 4 chunks */   \
      int lch = ch ^ ((ch >> 3) & 7);     /* swizzled logical chunk */         \
      int row = lch >> 2, c = (lch & 3) * 8;                                   \
      int anode = m0 + row; if (anode >= N_NODES) anode = N_NODES - 1;         \
      async_cp16(AH + (size_t)anode * ASTRIDE + (ACOL) + c, &Ah_s[BB][ch * 8]);\
      async_cp16(AL + (size_t)anode * ASTRIDE + (ACOL) + c, &Al_s[BB][ch * 8]);\
    }                                                                          \
    const ushort_t* bh = WpH + ((size_t)jt * 10 + (KC)) * 6144;                \
    const ushort_t* bl = WpL + ((size_t)jt * 10 + (KC)) * 6144;                \
    _Pragma("unroll")                                                          \
    for (int pass = 0; pass < 3; pass++){                                      \
      int ch = pass * 256 + tid;          /* 0..767 : 192 rows x 4 chunks */   \
      int lch = ch ^ ((ch >> 3) & 7);                                          \
      async_cp16(bh + lch * 8, &Bh_s[BB][ch * 8]);                             \
      async_cp16(bl + lch * 8, &Bl_s[BB][ch * 8]);                             \
    }                                                                          \
  }

#define GRU_COMPUTE(BB, NTGT)                                                  \
  {                                                                            \
    short8 a_h[4], a_l[4];                                                     \
    _Pragma("unroll")                                                          \
    for (int mt = 0; mt < 4; mt++){                                            \
      int r = wm * 64 + mt * 16 + m16;                                         \
      int so = ((r * 4 + quad) ^ ((r >> 1) & 7)) * 8;                          \
      a_h[mt] = *(const short8*)&Ah_s[BB][so];                                 \
      a_l[mt] = *(const short8*)&Al_s[BB][so];                                 \
    }                                                                          \
    _Pragma("unroll")                                                          \
    for (int g = 0; g < 3; g++){                                               \
      int tgt = (g < 2) ? g : (NTGT);                                          \
      _Pragma("unroll")                                                        \
      for (int nt = 0; nt < 2; nt++){                                          \
        int r = g * 64 + wn * 32 + nt * 16 + m16;                              \
        int so = ((r * 4 + quad) ^ ((r >> 1) & 7)) * 8;                        \
        short8 b_h = *(const short8*)&Bh_s[BB][so];                            \
        short8 b_l = *(const short8*)&Bl_s[BB][so];                            \
        _Pragma("unroll")                                                      \
        for (int mt = 0; mt < 4; mt++){                                        \
          acc[tgt][mt][nt] = __builtin_amdgcn_mfma_f32_16x16x32_bf16(a_h[mt], b_h, acc[tgt][mt][nt],0,0,0); \
          acc[tgt][mt][nt] = __builtin_amdgcn_mfma_f32_16x16x32_bf16(a_h[mt], b_l, acc[tgt][mt][nt],0,0,0); \
          acc[tgt][mt][nt] = __builtin_amdgcn_mfma_f32_16x16x32_bf16(a_l[mt], b_h, acc[tgt][mt][nt],0,0,0); \
        }                                                                      \
      }                                                                        \
    }                                                                          \
  }

__global__ __launch_bounds__(256, 2)
void gru_step(GruArgs ga){
  int bid = blockIdx.x;
  int wsw = (bid & 7) * 79 + (bid >> 3);
  int m0 = (wsw >> 3) * 128;
  int sub = wsw & 7;
  int jt = sub >> 1;                 // j-tile of 64
  int dir = sub & 1;

  const ushort_t* EtH  = ga.EtH[dir];  const ushort_t* EtL  = ga.EtL[dir];
  const ushort_t* WpH  = ga.WpH[dir];  const ushort_t* WpL  = ga.WpL[dir];
  const float*    BIH  = ga.BIH[dir];  const float*    BHH  = ga.BHH[dir];
  const ushort_t* HinH = ga.HinH[dir]; const ushort_t* HinL = ga.HinL[dir];
  ushort_t* HoutH = ga.HoutH[dir];     ushort_t* HoutL = ga.HoutL[dir];

  __shared__ __align__(16) short Ah_s[2][128 * 32];
  __shared__ __align__(16) short Al_s[2][128 * 32];
  __shared__ __align__(16) short Bh_s[2][192 * 32];
  __shared__ __align__(16) short Bl_s[2][192 * 32];

  int tid = threadIdx.x;
  int w = tid >> 6, lane = tid & 63;
  int wm = w >> 1, wn = w & 1;
  int m16 = lane & 15, quad = lane >> 4;
  int j0 = jt * 64;

  f32x4 acc[4][4][2];                // [r,z,n_in,n_hid][mt][nt]
#pragma unroll
  for (int g = 0; g < 4; g++)
#pragma unroll
    for (int i = 0; i < 4; i++)
#pragma unroll
      for (int j = 0; j < 2; j++) acc[g][i][j] = (f32x4){0,0,0,0};

  GRU_STAGE(0, EtH, EtL, 64, 0, 0)
  __syncthreads();
  GRU_STAGE(1, EtH, EtL, 64, 32, 1)
  GRU_COMPUTE(0, 2)
  __syncthreads();
  if (!ga.first){
    GRU_STAGE(0, HinH, HinL, 256, 0, 2)
    GRU_COMPUTE(1, 2)
    __syncthreads();
    for (int kc = 2; kc < 9; kc++){
      GRU_STAGE((kc + 1) & 1, HinH, HinL, 256, (kc - 1) * 32, kc + 1)
      GRU_COMPUTE(kc & 1, 3)
      __syncthreads();
    }
    GRU_COMPUTE(1, 3)
  } else {
    GRU_COMPUTE(1, 2)
  }

#pragma unroll
  for (int mt = 0; mt < 4; mt++){
    int row = m0 + wm * 64 + mt * 16 + quad * 4;
#pragma unroll
    for (int nt = 0; nt < 2; nt++){
      int j = j0 + wn * 32 + nt * 16 + m16;
      float br  = BIH[j] + BHH[j];
      float bz  = BIH[GRU_H + j] + BHH[GRU_H + j];
      float bni = BIH[2*GRU_H + j];
      float bnh = BHH[2*GRU_H + j];
#pragma unroll
      for (int r4 = 0; r4 < 4; r4++){
        int node = row + r4;
        if (node < N_NODES){
          float rr = 1.f / (1.f + __expf(-(acc[0][mt][nt][r4] + br)));
          float zz = 1.f / (1.f + __expf(-(acc[1][mt][nt][r4] + bz)));
          float nn = tanhf(acc[2][mt][nt][r4] + bni + rr * (acc[3][mt][nt][r4] + bnh));
          size_t hidx = (size_t)node * GRU_H + j;
          float hold = ga.first ? 0.f : (bf2f(HinH[hidx]) + bf2f(HinL[hidx]));
          float hv = (1.f - zz) * nn + zz * hold;
          ushort_t hh = f2bf(hv);
          HoutH[hidx] = hh;
          HoutL[hidx] = f2bf(hv - bf2f(hh));
        }
      }
    }
  }
}

// ---------------- fused GAT layer 1 (batched over tl) ----------------

__device__ __forceinline__ void gat1_half(float4 xl, float4 xr,
                                          float a0, float a1, float a2,
                                          float4 we0, float4 we1, float4 we2,
                                          float4 at, bool valid,
                                          float& den, float4& acc){
  float vx = xl.x + xr.x + a0*we0.x + a1*we1.x + a2*we2.x;
  float vy = xl.y + xr.y + a0*we0.y + a1*we1.y + a2*we2.y;
  float vz = xl.z + xr.z + a0*we0.z + a1*we1.z + a2*we2.z;
  float vw = xl.w + xr.w + a0*we0.w + a1*we1.w + a2*we2.w;
  vx = fmaxf(vx, 0.2f*vx); vy = fmaxf(vy, 0.2f*vy);
  vz = fmaxf(vz, 0.2f*vz); vw = fmaxf(vw, 0.2f*vw);
  float pm = vx*at.x + vy*at.y + vz*at.z + vw*at.w;
  pm += __shfl_xor(pm, 1, 64); pm += __shfl_xor(pm, 2, 64);
  pm += __shfl_xor(pm, 4, 64); pm += __shfl_xor(pm, 8, 64);
  float wgt = valid ? __expf(pm) : 0.f;
  den += wgt;
  acc.x += wgt * xl.x; acc.y += wgt * xl.y;
  acc.z += wgt * xl.z; acc.w += wgt * xl.w;
}

__global__ __launch_bounds__(256)
void gat1_fused(const float* __restrict__ xlrb, const float4* __restrict__ emeta,
                const int* __restrict__ row_ptr, const int* __restrict__ col,
                const float* __restrict__ we, const float* __restrict__ att,
                const float* __restrict__ bias,
                ushort_t* __restrict__ outhb, ushort_t* __restrict__ outlb){
  int tl = blockIdx.y;
  const float* xlr = xlrb + (size_t)tl * N_NODES * 1024;
  ushort_t* outh = outhb + (size_t)tl * N_NODES * 512;
  ushort_t* outl = outlb + (size_t)tl * N_NODES * 512;

  int n = (blockIdx.x * 256 + threadIdx.x) >> 6;
  int lane = threadIdx.x & 63;
  if (n >= N_NODES) return;
  int ch0 = lane * 4;
  int ch1 = 256 + lane * 4;

  float4 att0 = *(const float4*)&att[ch0];
  float4 att1 = *(const float4*)&att[ch1];
  float4 we00 = *(const float4*)&we[ch0],        we01 = *(const float4*)&we[ch1];
  float4 we10 = *(const float4*)&we[512 + ch0],  we11 = *(const float4*)&we[512 + ch1];
  float4 we20 = *(const float4*)&we[1024 + ch0], we21 = *(const float4*)&we[1024 + ch1];
  const float* xrow_n = xlr + (size_t)n * 1024;
  float4 xr0 = *(const float4*)&xrow_n[512 + ch0];
  float4 xr1 = *(const float4*)&xrow_n[512 + ch1];

  float den0 = 0.f, den1 = 0.f;
  float4 acc0 = make_float4(0,0,0,0), acc1 = make_float4(0,0,0,0);
  int beg = row_ptr[n], end = row_ptr[n + 1];

  for (int p = beg - 1; p < end; p += 2){
    int c0 = (p >= beg) ? col[p] : (E_EDGES + n);   // p==beg-1 -> self loop
    bool v1 = (p + 1 < end);
    int c1 = v1 ? col[p + 1] : c0;
    float4 mt0 = emeta[c0];
    float4 mt1 = emeta[c1];
    const float* xp0 = xlr + (size_t)__float_as_int(mt0.w) * 1024;
    const float* xp1 = xlr + (size_t)__float_as_int(mt1.w) * 1024;
    float4 xa0 = *(const float4*)&xp0[ch0];
    float4 xa1 = *(const float4*)&xp0[ch1];
    float4 xb0 = *(const float4*)&xp1[ch0];
    float4 xb1 = *(const float4*)&xp1[ch1];
    gat1_half(xa0, xr0, mt0.x, mt0.y, mt0.z, we00, we10, we20, att0, true, den0, acc0);
    gat1_half(xa1, xr1, mt0.x, mt0.y, mt0.z, we01, we11, we21, att1, true, den1, acc1);
    gat1_half(xb0, xr0, mt1.x, mt1.y, mt1.z, we00, we10, we20, att0, v1, den0, acc0);
    gat1_half(xb1, xr1, mt1.x, mt1.y, mt1.z, we01, we11, we21, att1, v1, den1, acc1);
  }

  float4 b0 = *(const float4*)&bias[ch0];
  float4 b1 = *(const float4*)&bias[ch1];
  float id0 = 1.f / den0, id1 = 1.f / den1;
  float o[8];
  o[0] = acc0.x*id0 + b0.x; o[1] = acc0.y*id0 + b0.y;
  o[2] = acc0.z*id0 + b0.z; o[3] = acc0.w*id0 + b0.w;
  o[4] = acc1.x*id1 + b1.x; o[5] = acc1.y*id1 + b1.y;
  o[6] = acc1.z*id1 + b1.z; o[7] = acc1.w*id1 + b1.w;
  ushort4 h0, h1v, l0, l1v;
  ushort_t* hp0 = (ushort_t*)&h0; ushort_t* hp1 = (ushort_t*)&h1v;
  ushort_t* lp0 = (ushort_t*)&l0; ushort_t* lp1 = (ushort_t*)&l1v;
#pragma unroll
  for (int i = 0; i < 8; i++){
    float v = o[i];
    v = v > 0.f ? v : (__expf(v) - 1.f);
    ushort_t hh = f2bf(v);
    ushort_t ll = f2bf(v - bf2f(hh));
    if (i < 4){ hp0[i] = hh; lp0[i] = ll; } else { hp1[i-4] = hh; lp1[i-4] = ll; }
  }
  *(ushort4*)&outh[(size_t)n * 512 + ch0] = h0;
  *(ushort4*)&outh[(size_t)n * 512 + ch1] = h1v;
  *(ushort4*)&outl[(size_t)n * 512 + ch0] = l0;
  *(ushort4*)&outl[(size_t)n * 512 + ch1] = l1v;
}

// ---------------- fused GAT layer 2 (batched over tl) ----------------

__global__ __launch_bounds__(256)
void gat2_fused(const float* __restrict__ xlrb, const float4* __restrict__ emeta,
                const int* __restrict__ row_ptr, const int* __restrict__ col,
                const float* __restrict__ we, const float* __restrict__ att,
                const float* __restrict__ bias,
                ushort_t* __restrict__ embh, ushort_t* __restrict__ embl, int t0){
  int tl = blockIdx.y;
  const float* xlr = xlrb + (size_t)tl * N_NODES * 1024;   // low [N][128] region
  int t = t0 + tl;

  int n = (blockIdx.x * 256 + threadIdx.x) >> 6;
  int lane = threadIdx.x & 63;
  if (n >= N_NODES) return;
  int g = lane >> 4;
  int c4 = (lane & 15) * 4;

  float4 attq = *(const float4*)&att[c4];
  float4 we0q = *(const float4*)&we[c4];
  float4 we1q = *(const float4*)&we[64 + c4];
  float4 we2q = *(const float4*)&we[128 + c4];
  float4 xr4  = *(const float4*)&xlr[(size_t)n * 128 + 64 + c4];

  float den = 0.f;
  float4 acc = make_float4(0,0,0,0);
  int beg = row_ptr[n], end = row_ptr[n + 1];

  for (int p0 = beg - 1; p0 < end; p0 += 4){
    int pp = p0 + g;
    bool valid = pp < end;
    int s = n; float a0 = 0.f, a1 = 0.f, a2 = 0.f;
    if (valid){
      float4 mt = (pp < beg) ? emeta[E_EDGES + n] : emeta[col[pp]];
      a0 = mt.x; a1 = mt.y; a2 = mt.z; s = __float_as_int(mt.w);
    }
    float4 xl4 = *(const float4*)&xlr[(size_t)s * 128 + c4];
    float vx = xl4.x + xr4.x + a0*we0q.x + a1*we1q.x + a2*we2q.x;
    float vy = xl4.y + xr4.y + a0*we0q.y + a1*we1q.y + a2*we2q.y;
    float vz = xl4.z + xr4.z + a0*we0q.z + a1*we1q.z + a2*we2q.z;
    float vw = xl4.w + xr4.w + a0*we0q.w + a1*we1q.w + a2*we2q.w;
    vx = fmaxf(vx, 0.2f*vx); vy = fmaxf(vy, 0.2f*vy);
    vz = fmaxf(vz, 0.2f*vz); vw = fmaxf(vw, 0.2f*vw);
    float pm = vx*attq.x + vy*attq.y + vz*attq.z + vw*attq.w;
    pm += __shfl_xor(pm, 1, 64); pm += __shfl_xor(pm, 2, 64);
    pm += __shfl_xor(pm, 4, 64); pm += __shfl_xor(pm, 8, 64);
    float wgt = valid ? __expf(pm) : 0.f;
    den += wgt;
    acc.x += wgt * xl4.x; acc.y += wgt * xl4.y;
    acc.z += wgt * xl4.z; acc.w += wgt * xl4.w;
  }
#pragma unroll
  for (int off = 16; off <= 32; off <<= 1){
    den   += __shfl_xor(den, off, 64);
    acc.x += __shfl_xor(acc.x, off, 64);
    acc.y += __shfl_xor(acc.y, off, 64);
    acc.z += __shfl_xor(acc.z, off, 64);
    acc.w += __shfl_xor(acc.w, off, 64);
  }
  if (g == 0){
    float4 bq = *(const float4*)&bias[c4];
    float id = 1.f / den;
    float o[4];
    o[0] = acc.x*id + bq.x; o[1] = acc.y*id + bq.y;
    o[2] = acc.z*id + bq.z; o[3] = acc.w*id + bq.w;
    ushort4 hv, lv;
    ushort_t* hp = (ushort_t*)&hv; ushort_t* lp = (ushort_t*)&lv;
#pragma unroll
    for (int i = 0; i < 4; i++){
      float v = o[i];
      v = v > 0.f ? v : (__expf(v) - 1.f);
      ushort_t hh = f2bf(v);
      hp[i] = hh; lp[i] = f2bf(v - bf2f(hh));
    }
    ushort_t* oh = embh + (size_t)t * N_NODES * HID;
    ushort_t* ol = embl + (size_t)t * N_NODES * HID;
    *(ushort4*)&oh[(size_t)n * 64 + c4] = hv;
    *(ushort4*)&ol[(size_t)n * 64 + c4] = lv;
  }
}

// ---------------- tail ----------------

__global__ __launch_bounds__(256)
void mean_kernel(const ushort_t* __restrict__ hfh, const ushort_t* __restrict__ hfl,
                 const ushort_t* __restrict__ hbh, const ushort_t* __restrict__ hbl,
                 float* __restrict__ g){
  int k = threadIdx.x;
  int n0 = blockIdx.x * 50;
  int n1 = n0 + 50; if (n1 > N_NODES) n1 = N_NODES;
  float sf = 0.f, sb = 0.f;
  for (int n = n0; n < n1; n++){
    size_t i = (size_t)n * GRU_H + k;
    sf += bf2f(hfh[i]) + bf2f(hfl[i]);
    sb += bf2f(hbh[i]) + bf2f(hbl[i]);
  }
  atomicAdd(&g[k], sf);
  atomicAdd(&g[GRU_H + k], sb);
}

__global__ __launch_bounds__(64)
void fc_kernel(const float* __restrict__ g, const float* __restrict__ W,
               const float* __restrict__ b, float* __restrict__ out){
  int j = blockIdx.x;
  int lane = threadIdx.x;
  float s = 0.f;
  for (int k = lane; k < 2 * GRU_H; k += 64) s += g[k] * W[j * (2 * GRU_H) + k];
  s = wave_reduce_sum(s);
  if (lane == 0) out[j] = b[j] + s * (1.0f / N_NODES);
}

// ---------------- launch ----------------

extern "C" void kernel_launch(void* const* d_in, const int* in_sizes, int n_in,
                              void* d_out, int out_size, void* d_ws, size_t ws_size,
                              hipStream_t stream){
  const float* x     = (const float*)d_in[0];
  const float* eattr = (const float*)d_in[1];
  const int*   esrc  = (const int*)  d_in[2];
  const int*   edst  = (const int*)  d_in[3];
  const float* g1_wl = (const float*)d_in[4];
  const float* g1_wr = (const float*)d_in[5];
  const float* g1_we = (const float*)d_in[6];
  const float* g1_att= (const float*)d_in[7];
  const float* g1_b  = (const float*)d_in[8];
  const float* g2_wl = (const float*)d_in[9];
  const float* g2_wr = (const float*)d_in[10];
  const float* g2_we = (const float*)d_in[11];
  const float* g2_att= (const float*)d_in[12];
  const float* g2_b  = (const float*)d_in[13];
  const float* wih_f = (const float*)d_in[14];
  const float* whh_f = (const float*)d_in[15];
  const float* bih_f = (const float*)d_in[16];
  const float* bhh_f = (const float*)d_in[17];
  const float* wih_b = (const float*)d_in[18];
  const float* whh_b = (const float*)d_in[19];
  const float* bih_b = (const float*)d_in[20];
  const float* bhh_b = (const float*)d_in[21];
  const float* fc_w  = (const float*)d_in[22];
  const float* fc_b  = (const float*)d_in[23];
  float* out = (float*)d_out;

  const size_t XTOT = (size_t)T_SEQ * N_NODES * IN_CH;
  const size_t ETOT = (size_t)T_SEQ * N_NODES * HID;
  const size_t HTOT = (size_t)N_NODES * GRU_H;
  const size_t WPK  = 4 * 10 * 192 * 32;

  // pick time-batch factor BT from workspace size (mirror of the alloc list)
  auto plan = [&](int bt) -> size_t {
    size_t t = 0;
    auto add = [&](size_t nf){ t += (nf + 3) & ~(size_t)3; };
    add(XTOT / 2); add(XTOT / 2);
    add((size_t)bt * N_NODES * 1024);
    add((size_t)bt * N_NODES * 512 / 2 + 4);
    add((size_t)bt * N_NODES * 512 / 2 + 4);
    add(ETOT / 2); add(ETOT / 2);
    for (int i = 0; i < 8; i++) add(HTOT / 2 + 4);
    add((size_t)N_NODES * 3); add((size_t)N_NODES * 3); add(512);
    add((size_t)EF * 4);
    add(1024*128/2); add(1024*128/2); add(128*512/2); add(128*512/2);
    for (int i = 0; i < 4; i++) add(WPK / 2);
    add(N_NODES + 4); add(N_NODES + 4); add(N_NODES + 4); add(E_EDGES + 4);
    return t;
  };
  int BT = 8;
  while (BT > 1 && plan(BT) * sizeof(float) > ws_size) BT >>= 1;

  float* ws = (float*)d_ws;
  size_t o = 0;
  auto alloc = [&](size_t nfloats) -> float* {
    float* p = ws + o; o += (nfloats + 3) & ~(size_t)3; return p;
  };
  ushort_t* xh   = (ushort_t*)alloc(XTOT / 2);
  ushort_t* xlo  = (ushort_t*)alloc(XTOT / 2);
  float* xlrb    = alloc((size_t)BT * N_NODES * 1024);
  ushort_t* h1h  = (ushort_t*)alloc((size_t)BT * N_NODES * 512 / 2 + 4);
  ushort_t* h1l  = (ushort_t*)alloc((size_t)BT * N_NODES * 512 / 2 + 4);
  ushort_t* embh = (ushort_t*)alloc(ETOT / 2);
  ushort_t* embl = (ushort_t*)alloc(ETOT / 2);
  ushort_t* hbuf[8];
  for (int i = 0; i < 8; i++) hbuf[i] = (ushort_t*)alloc(HTOT / 2 + 4);
  float* lsum  = alloc((size_t)N_NODES * 3);
  float* lattr = alloc((size_t)N_NODES * 3);
  float* gmean = alloc(512);
  float4* emeta = (float4*)alloc((size_t)EF * 4);
  ushort_t* W1h = (ushort_t*)alloc(1024*128/2);
  ushort_t* W1l = (ushort_t*)alloc(1024*128/2);
  ushort_t* W2h = (ushort_t*)alloc(128*512/2);
  ushort_t* W2l = (ushort_t*)alloc(128*512/2);
  ushort_t* WpFh = (ushort_t*)alloc(WPK/2);
  ushort_t* WpFl = (ushort_t*)alloc(WPK/2);
  ushort_t* WpBh = (ushort_t*)alloc(WPK/2);
  ushort_t* WpBl = (ushort_t*)alloc(WPK/2);
  int* deg     = (int*)alloc(N_NODES + 4);
  int* row_ptr = (int*)alloc(N_NODES + 4);
  int* cursor  = (int*)alloc(N_NODES + 4);
  int* col     = (int*)alloc(E_EDGES + 4);

  hipMemsetAsync(deg,    0, N_NODES * sizeof(int), stream);
  hipMemsetAsync(cursor, 0, N_NODES * sizeof(int), stream);
  hipMemsetAsync(lsum,   0, (size_t)N_NODES * 3 * sizeof(float), stream);
  hipMemsetAsync(gmean,  0, 512 * sizeof(float), stream);
  // no hbuf memsets — gru_step first=1 handles h0 == 0 exactly

  deg_loop_kernel<<<(E_EDGES + 255)/256, 256, 0, stream>>>(edst, eattr, deg, lsum);
  loop_div_kernel<<<(N_NODES + 255)/256, 256, 0, stream>>>(deg, lsum, lattr);
  scan_rowptr_kernel<<<1, 256, 0, stream>>>(deg, row_ptr);
  csr_fill_kernel<<<(E_EDGES + 255)/256, 256, 0, stream>>>(edst, row_ptr, cursor, col);
  build_emeta<<<(EF + 255)/256, 256, 0, stream>>>(eattr, lattr, esrc, emeta);
  split_arr4<<<(int)(XTOT / 4 / 256), 256, 0, stream>>>(
      (const float4*)x, (ushort4*)xh, (ushort4*)xlo, (long)(XTOT / 4));
  split_w_gat1<<<(1024*128 + 255)/256, 256, 0, stream>>>(g1_wl, g1_wr, W1h, W1l);
  split_w_gat2<<<(128*512 + 255)/256, 256, 0, stream>>>(g2_wl, g2_wr, W2h, W2l);
  pack_w_gru<<<(int)((WPK + 255)/256), 256, 0, stream>>>(wih_f, whh_f, WpFh, WpFl);
  pack_w_gru<<<(int)((WPK + 255)/256), 256, 0, stream>>>(wih_b, whh_b, WpBh, WpBl);

  const int MB32 = (N_NODES + 31) / 32;     // 313
  const int NODE_BLOCKS = (N_NODES + 3) / 4;
  for (int t0 = 0; t0 < T_SEQ; t0 += BT){
    const ushort_t* xth = xh  + (size_t)t0 * N_NODES * IN_CH;
    const ushort_t* xtl = xlo + (size_t)t0 * N_NODES * IN_CH;
    gemm1_swz<<<dim3(1252, BT), 256, 0, stream>>>(xth, xtl, W1h, W1l, xlrb);
    gat1_fused<<<dim3(NODE_BLOCKS, BT), 256, 0, stream>>>(
        xlrb, emeta, row_ptr, col, g1_we, g1_att, g1_b, h1h, h1l);
    gemm2_b<<<dim3(MB32, BT), 128, 0, stream>>>(h1h, h1l, W2h, W2l, xlrb);
    gat2_fused<<<dim3(NODE_BLOCKS, BT), 256, 0, stream>>>(
        xlrb, emeta, row_ptr, col, g2_we, g2_att, g2_b, embh, embl, t0);
  }

  // GRU: both directions per launch; fwd ping-pong hbuf[0,1]<->[2,3], bwd [4,5]<->[6,7]
  {
    int fin = 0, bin = 4;
    for (int s = 0; s < T_SEQ; s++){
      int fo = fin ^ 2, bo = bin ^ 2;
      GruArgs ga;
      ga.EtH[0] = embh + (size_t)s * N_NODES * HID;
      ga.EtL[0] = embl + (size_t)s * N_NODES * HID;
      ga.EtH[1] = embh + (size_t)(T_SEQ - 1 - s) * N_NODES * HID;
      ga.EtL[1] = embl + (size_t)(T_SEQ - 1 - s) * N_NODES * HID;
      ga.WpH[0] = WpFh; ga.WpL[0] = WpFl; ga.WpH[1] = WpBh; ga.WpL[1] = WpBl;
      ga.BIH[0] = bih_f; ga.BHH[0] = bhh_f; ga.BIH[1] = bih_b; ga.BHH[1] = bhh_b;
      ga.HinH[0] = hbuf[fin];   ga.HinL[0] = hbuf[fin+1];
      ga.HinH[1] = hbuf[bin];   ga.HinL[1] = hbuf[bin+1];
      ga.HoutH[0] = hbuf[fo];   ga.HoutL[0] = hbuf[fo+1];
      ga.HoutH[1] = hbuf[bo];   ga.HoutL[1] = hbuf[bo+1];
      ga.first = (s == 0) ? 1 : 0;
      gru_step<<<632, 256, 0, stream>>>(ga);
      fin = fo; bin = bo;
    }
  }

  mean_kernel<<<(N_NODES + 49)/50, 256, 0, stream>>>(hbuf[0], hbuf[1], hbuf[4], hbuf[5], gmean);
  fc_kernel<<<33, 64, 0, stream>>>(gmean, fc_w, fc_b, out);
}